// Round 11
// baseline (533.087 us; speedup 1.0000x reference)
//
#include <hip/hip_runtime.h>
#include <hip/hip_bf16.h>
#include <cstdint>
#include <cstddef>

constexpr int NF = 100000;
constexpr int NA = 400;
constexpr int NC = 30;
constexpr int NN = NF + NA + NC;     // 100430
constexpr int D  = 256;
constexpr int DD = D * D;            // 65536
constexpr int E  = 250000;
constexpr int NSL = 128;             // slices for r0/r2 counting sort

typedef __attribute__((ext_vector_type(8))) short bf16x8;
typedef __attribute__((ext_vector_type(4))) float f32x4;
typedef __attribute__((ext_vector_type(8))) ushort u16x8;

__device__ inline ushort f2bf(float f) {
    __hip_bfloat16 h = __float2bfloat16(f);
    return __builtin_bit_cast(ushort, h);
}
__device__ inline float bf2f(ushort u) {
    __hip_bfloat16 h = __builtin_bit_cast(__hip_bfloat16, u);
    return __bfloat162float(h);
}

// async global->LDS, 16B per lane: LDS dest = base + lane*16 (wave-linear)
__device__ inline void gload_lds16(const ushort* g, ushort* l) {
    __builtin_amdgcn_global_load_lds(
        (const __attribute__((address_space(1))) void*)g,
        (__attribute__((address_space(3))) void*)l, 16, 0, 0);
}

// ---------------- per-type encoders: h = relu(x @ W + b), split-bf16 out ----
template<int K, int ROWS>
__global__ __launch_bounds__(256) void encode_kernel(
    const float* __restrict__ x, const float* __restrict__ W,
    const float* __restrict__ b, ushort* __restrict__ hH, ushort* __restrict__ hL,
    int rows, int row_off)
{
    int c = threadIdx.x;
    int base = blockIdx.x * ROWS;
    float wcol[K];
    #pragma unroll
    for (int k = 0; k < K; ++k) wcol[k] = W[k * D + c];
    float bias = b[c];
    for (int i = 0; i < ROWS; ++i) {
        int row = base + i;
        if (row >= rows) return;
        const float* xr = x + (size_t)row * K;
        float acc = bias;
        #pragma unroll
        for (int k = 0; k < K; ++k) acc += xr[k] * wcol[k];
        float v = fmaxf(acc, 0.f);
        ushort hi = f2bf(v);
        size_t o = (size_t)(row_off + row) * D + c;
        hH[o] = hi;
        hL[o] = f2bf(v - bf2f(hi));
    }
}

// ---------------- weight split+transpose: root[k][n] -> WtH/WtL[n][k] -------
__global__ __launch_bounds__(256) void wsplit_kernel(
    const float* __restrict__ root, ushort* __restrict__ WtH, ushort* __restrict__ WtL)
{
    int n = blockIdx.x, k = threadIdx.x;
    float w = root[(size_t)k * D + n];
    ushort hi = f2bf(w);
    WtH[(size_t)n * D + k] = hi;
    WtL[(size_t)n * D + k] = f2bf(w - bf2f(hi));
}

// ---------------- r1/r3 degree count (low contention: 100K dsts) ----------
__global__ __launch_bounds__(256) void deg_count_kernel(
    const int* __restrict__ dst1, const int* __restrict__ dst3,
    int* __restrict__ deg1, int* __restrict__ deg3)
{
    int idx = blockIdx.x * 256 + threadIdx.x;
    if (idx >= 2 * E) return;
    if (idx < E) atomicAdd(&deg1[dst1[idx]], 1);
    else         atomicAdd(&deg3[dst3[idx - E]], 1);
}

// ---------------- r0/r2: per-slice LDS histograms (contention-free) --------
__global__ __launch_bounds__(256) void hist02_kernel(
    const int* __restrict__ dst0, const int* __restrict__ dst2,
    int* __restrict__ bh0, int* __restrict__ bh2)
{
    __shared__ int hist[NA];
    int b = blockIdx.x;                 // 0..2*NSL-1
    bool isR2 = (b >= NSL);
    int sl = isR2 ? b - NSL : b;
    const int* dst = isR2 ? dst2 : dst0;
    int nb = isR2 ? NC : NA;
    for (int i = threadIdx.x; i < nb; i += 256) hist[i] = 0;
    __syncthreads();
    int lo = (int)((long long)E * sl / NSL);
    int hi = (int)((long long)E * (sl + 1) / NSL);
    for (int e = lo + threadIdx.x; e < hi; e += 256)
        atomicAdd(&hist[dst[e]], 1);
    __syncthreads();
    int* bh = isR2 ? (bh2 + sl * NC) : (bh0 + sl * NA);
    for (int i = threadIdx.x; i < nb; i += 256) bh[i] = hist[i];
}

// -------- scan: per-bin over slices + cross-bin; emits rp/inv + abs offsets -
__global__ __launch_bounds__(512) void scan02_kernel(
    int* __restrict__ bh0, int* __restrict__ bh2,
    int* __restrict__ rp0, int* __restrict__ rp2,
    float* __restrict__ inv0, float* __restrict__ inv2)
{
    __shared__ int tot[512];
    __shared__ int exc[512];
    int t = threadIdx.x;
    int cnt = 0;
    if (t < NA) {
        int s = 0;
        for (int sl = 0; sl < NSL; ++sl) {
            int v = bh0[sl * NA + t]; bh0[sl * NA + t] = s; s += v;
        }
        cnt = s;
    } else if (t < NA + NC) {
        int bin = t - NA; int s = 0;
        for (int sl = 0; sl < NSL; ++sl) {
            int v = bh2[sl * NC + bin]; bh2[sl * NC + bin] = s; s += v;
        }
        cnt = s;
    }
    tot[t] = cnt;
    __syncthreads();
    for (int ofs = 1; ofs < 512; ofs <<= 1) {
        int v = (t >= ofs) ? tot[t - ofs] : 0;
        __syncthreads();
        tot[t] += v;
        __syncthreads();
    }
    int ex = tot[t] - cnt;              // exclusive over combined [r0 | r2]
    if (t < NA) {
        exc[t] = ex;
        rp0[t] = ex;
        inv0[t] = 1.0f / (float)(cnt > 1 ? cnt : 1);
        if (t == 0) { rp0[NA] = E; rp2[NC] = E; }
    } else if (t < NA + NC) {
        exc[t] = ex - E;                // r2 csr buffer is its own array
        rp2[t - NA] = ex - E;
        inv2[t - NA] = 1.0f / (float)(cnt > 1 ? cnt : 1);
    } else exc[t] = 0;
    __syncthreads();
    for (int idx = t; idx < NSL * NA; idx += 512) {
        int sl = idx / NA; int bin = idx - sl * NA;
        bh0[idx] += exc[bin];
    }
    for (int idx = t; idx < NSL * NC; idx += 512) {
        int sl = idx / NC; int bin = idx - sl * NC;
        bh2[idx] += exc[NA + bin];
    }
}

// ---------------- r0/r2 CSR fill with LDS cursors --------------------------
__global__ __launch_bounds__(256) void fill02_kernel(
    const int* __restrict__ src0, const int* __restrict__ dst0,
    const int* __restrict__ src2, const int* __restrict__ dst2,
    const int* __restrict__ bh0, const int* __restrict__ bh2,
    int* __restrict__ csr0, int* __restrict__ csr2)
{
    __shared__ int cur[NA];
    int b = blockIdx.x;
    bool isR2 = (b >= NSL);
    int sl = isR2 ? b - NSL : b;
    const int* src = isR2 ? src2 : src0;
    const int* dst = isR2 ? dst2 : dst0;
    const int* bh  = isR2 ? (bh2 + sl * NC) : (bh0 + sl * NA);
    int* csr       = isR2 ? csr2 : csr0;
    int nb = isR2 ? NC : NA;
    for (int i = threadIdx.x; i < nb; i += 256) cur[i] = bh[i];
    __syncthreads();
    int lo = (int)((long long)E * sl / NSL);
    int hi = (int)((long long)E * (sl + 1) / NSL);
    for (int e = lo + threadIdx.x; e < hi; e += 256) {
        int pos = atomicAdd(&cur[dst[e]], 1);
        csr[pos] = src[e];
    }
}

// ---------------- r1/r3 scan chain -----------------------------------------
__global__ __launch_bounds__(1024) void scanA_kernel(
    const int* __restrict__ deg1, const int* __restrict__ deg3, int* __restrict__ bsum)
{
    __shared__ int s[1024];
    int b = blockIdx.x;                    // 0..195
    bool isR3 = (b >= 98);
    const int* deg = isR3 ? deg3 : deg1;
    int chunk = isR3 ? b - 98 : b;
    int i = chunk * 1024 + threadIdx.x;
    int v = (i < NF) ? deg[i] : 0;
    s[threadIdx.x] = v;
    __syncthreads();
    for (int ofs = 512; ofs > 0; ofs >>= 1) {
        if ((int)threadIdx.x < ofs) s[threadIdx.x] += s[threadIdx.x + ofs];
        __syncthreads();
    }
    if (threadIdx.x == 0) bsum[(isR3 ? 128 : 0) + chunk] = s[0];
}

__global__ __launch_bounds__(256) void scanB_kernel(int* __restrict__ bsum)
{
    __shared__ int s[256];
    int t = threadIdx.x;
    int v = ((t & 127) < 98) ? bsum[t] : 0;
    s[t] = v;
    __syncthreads();
    for (int ofs = 1; ofs < 128; ofs <<= 1) {
        int a = ((t & 127) >= ofs) ? s[t - ofs] : 0;
        __syncthreads();
        s[t] += a;
        __syncthreads();
    }
    bsum[t] = s[t] - v;   // exclusive (segmented per 128-half)
}

__global__ __launch_bounds__(1024) void scanC_kernel(
    const int* __restrict__ deg1, const int* __restrict__ deg3,
    const int* __restrict__ bsum,
    int* __restrict__ rp1, int* __restrict__ rp3,
    int* __restrict__ cu1, int* __restrict__ cu3,
    float* __restrict__ inv1, float* __restrict__ inv3)
{
    __shared__ int s[1024];
    int b = blockIdx.x;                    // 0..195
    const int* deg; int* rp; int* cu; float* inv; int chunk; int prefix;
    if (b < 98) { deg = deg1; rp = rp1; cu = cu1; inv = inv1; chunk = b;      prefix = bsum[chunk]; }
    else        { deg = deg3; rp = rp3; cu = cu3; inv = inv3; chunk = b - 98; prefix = bsum[128 + chunk]; }
    int tid = threadIdx.x;
    int i = chunk * 1024 + tid;
    int v = (i < NF) ? deg[i] : 0;
    s[tid] = v;
    __syncthreads();
    for (int ofs = 1; ofs < 1024; ofs <<= 1) {
        int a = (tid >= ofs) ? s[tid - ofs] : 0;
        __syncthreads();
        s[tid] += a;
        __syncthreads();
    }
    int ex = prefix + s[tid] - v;
    if (i < NF) {
        rp[i] = ex;
        cu[i] = ex;
        inv[i] = 1.0f / (float)(v > 1 ? v : 1);
    }
    if (i == 0) rp[NF] = E;
}

__global__ __launch_bounds__(256) void csr_fill13_kernel(
    const int* __restrict__ src1, const int* __restrict__ dst1,
    const int* __restrict__ src3, const int* __restrict__ dst3,
    int* __restrict__ cu1, int* __restrict__ cu3,
    int* __restrict__ csr1, int* __restrict__ csr3)
{
    int idx = blockIdx.x * 256 + threadIdx.x;
    if (idx >= 2 * E) return;
    if (idx < E) {
        int pos = atomicAdd(&cu1[dst1[idx]], 1);
        csr1[pos] = src1[idx];
    } else {
        int e = idx - E;
        int pos = atomicAdd(&cu3[dst3[e]], 1);
        csr3[pos] = src3[e];
    }
}

// ------- y = h[src-type rows] @ Wr (Wr combined from basis on the fly) ------
__global__ __launch_bounds__(256) void y_kernel(
    const ushort* __restrict__ hH, const ushort* __restrict__ hL,
    const float* __restrict__ basis, const float* __restrict__ comp,
    float* __restrict__ y)
{
    int row = blockIdx.x;            // 0..429  (airports then carriers)
    int c = threadIdx.x;
    const ushort* sH = hH + (size_t)(NF + row) * D;
    const ushort* sL = hL + (size_t)(NF + row) * D;
    int rel = (row < NA) ? 1 : 3;
    float c0 = comp[rel * 3 + 0], c1 = comp[rel * 3 + 1], c2 = comp[rel * 3 + 2];
    float acc = 0.f;
    #pragma unroll 4
    for (int k = 0; k < D; ++k) {
        float w = c0 * basis[k * D + c] + c1 * basis[DD + k * D + c]
                + c2 * basis[2 * DD + k * D + c];
        acc += (bf2f(sH[k]) + bf2f(sL[k])) * w;
    }
    y[(size_t)row * D + c] = acc;
}

// ---- pure bf16x3 MFMA GEMM: G = A @ root^T + bias -------------------------
// 2-phase double-buffered staging (T3/T4 minimal): issue tile k+1's
// global_load_lds into buf^1, compute tile k, then vmcnt(0)+raw s_barrier.
// Prefetch latency hides under the MFMA section; loads stay in flight
// during compute. Fragment-major LDS layout (write==read==lane-linear).
__global__ __launch_bounds__(256) void gemm_mfma(
    const ushort* __restrict__ AH, const ushort* __restrict__ AL,
    const ushort* __restrict__ WtH, const ushort* __restrict__ WtL,
    const float* __restrict__ bias,
    ushort* __restrict__ GH, ushort* __restrict__ GL, int nrows)
{
    constexpr int BM = 128, BK = 32;
    constexpr int PLANE = BM * BK;          // 4096 ushorts = 8 KB
    constexpr int BUF = 4 * PLANE;          // 16384 ushorts = 32 KB
    constexpr int LDW = 68;                 // fp32 epilogue scratch stride
    __shared__ __align__(16) ushort lds[2 * BUF];   // 64 KB (epilogue reuses)
    const int t = threadIdx.x;
    const int row0 = blockIdx.x * BM;
    const int col0 = blockIdx.y * BM;
    const int w = t >> 6, lane = t & 63;
    const int wm = w >> 1, wn = w & 1;     // 2x2 wave grid, 64x64 per wave
    const int lr = lane & 15;
    const int lk = lane >> 4;
    f32x4 acc[4][4] = {};

    // staging setup: wave w owns plane w (AH/AL/WtH/WtL)
    const ushort* splane = (w == 0) ? AH : (w == 1) ? AL : (w == 2) ? WtH : WtL;
    int grow[8];
    #pragma unroll
    for (int g = 0; g < 8; ++g) {
        int r = ((w < 2) ? row0 : col0) + g * 16 + lr;
        if (w < 2 && r >= nrows) r = nrows - 1;
        grow[g] = r;
    }
    const int lkk = lk * 8;                // per-lane k offset (ushorts)

    auto stage = [&](int k0, int buf) {
        ushort* ldsbase = lds + buf * BUF + w * PLANE;
        #pragma unroll
        for (int g = 0; g < 8; ++g)
            gload_lds16(splane + (size_t)grow[g] * D + k0 + lkk,
                        ldsbase + g * 512);
    };
    auto compute = [&](int buf) {
        const ushort* base = lds + buf * BUF;
        const ushort* AsH = base;
        const ushort* AsL = base + PLANE;
        const ushort* WsH = base + 2 * PLANE;
        const ushort* WsL = base + 3 * PLANE;
        bf16x8 bh[4], bl[4];
        #pragma unroll
        for (int ni = 0; ni < 4; ++ni) {
            int off = (wn * 4 + ni) * 512 + lane * 8;
            bh[ni] = *(const bf16x8*)(&WsH[off]);
            bl[ni] = *(const bf16x8*)(&WsL[off]);
        }
        #pragma unroll
        for (int mi = 0; mi < 4; ++mi) {
            int off = (wm * 4 + mi) * 512 + lane * 8;
            bf16x8 ah = *(const bf16x8*)(&AsH[off]);
            bf16x8 al = *(const bf16x8*)(&AsL[off]);
            #pragma unroll
            for (int ni = 0; ni < 4; ++ni) {
                acc[mi][ni] = __builtin_amdgcn_mfma_f32_16x16x32_bf16(ah, bh[ni], acc[mi][ni], 0, 0, 0);
                acc[mi][ni] = __builtin_amdgcn_mfma_f32_16x16x32_bf16(ah, bl[ni], acc[mi][ni], 0, 0, 0);
                acc[mi][ni] = __builtin_amdgcn_mfma_f32_16x16x32_bf16(al, bh[ni], acc[mi][ni], 0, 0, 0);
            }
        }
    };

    // prologue: tile 0 -> buf0, full drain
    stage(0, 0);
    asm volatile("s_waitcnt vmcnt(0)" ::: "memory");
    __builtin_amdgcn_s_barrier();
    __builtin_amdgcn_sched_barrier(0);
    // main loop: tiles 0..6 computed with tile k+1 prefetched
    for (int kt = 0; kt < 7; ++kt) {
        stage((kt + 1) * BK, (kt + 1) & 1);
        __builtin_amdgcn_sched_barrier(0);   // keep prefetch issues ahead
        compute(kt & 1);
        asm volatile("s_waitcnt vmcnt(0)" ::: "memory");
        __builtin_amdgcn_s_barrier();
        __builtin_amdgcn_sched_barrier(0);
    }
    compute(1);                              // tile 7 (in buf1), already landed

    // ---- epilogue: stage through LDS for coalesced 16B split-stores ----
    float* S = (float*)lds + (size_t)w * 32 * LDW;   // per-wave 32x68 fp32
    const int rrow = lane >> 3;            // 0..7 read-back row group
    const int grp  = lane & 7;             // col octet
    #pragma unroll
    for (int p = 0; p < 2; ++p) {
        __syncthreads();
        #pragma unroll
        for (int mh = 0; mh < 2; ++mh) {
            int mi = p * 2 + mh;
            #pragma unroll
            for (int ni = 0; ni < 4; ++ni)
                #pragma unroll
                for (int reg = 0; reg < 4; ++reg)
                    S[(mh * 16 + lk * 4 + reg) * LDW + ni * 16 + lr] = acc[mi][ni][reg];
        }
        __syncthreads();
        #pragma unroll
        for (int iter = 0; iter < 4; ++iter) {
            int row_i = rrow + iter * 8;
            int gr = row0 + wm * 64 + p * 32 + row_i;
            int gc = col0 + wn * 64 + grp * 8;
            if (gr >= nrows) continue;
            float4 f0 = *(const float4*)(&S[row_i * LDW + grp * 8]);
            float4 f1 = *(const float4*)(&S[row_i * LDW + grp * 8 + 4]);
            float4 b0 = *(const float4*)(bias + gc);
            float4 b1 = *(const float4*)(bias + gc + 4);
            float v[8] = {f0.x + b0.x, f0.y + b0.y, f0.z + b0.z, f0.w + b0.w,
                          f1.x + b1.x, f1.y + b1.y, f1.z + b1.z, f1.w + b1.w};
            u16x8 hh, ll;
            #pragma unroll
            for (int j = 0; j < 8; ++j) {
                ushort hi = f2bf(v[j]);
                hh[j] = hi;
                ll[j] = f2bf(v[j] - bf2f(hi));
            }
            *(u16x8*)(GH + (size_t)gr * D + gc) = hh;
            *(u16x8*)(GL + (size_t)gr * D + gc) = ll;
        }
    }
}

// ---- layer-0 flight rows: G = relu(G + inv1*Σy1 + inv3*Σy3) in place ------
__global__ __launch_bounds__(256) void msg_relu_kernel(
    ushort* __restrict__ GH, ushort* __restrict__ GL,
    const float* __restrict__ y,
    const int* __restrict__ rp1, const int* __restrict__ csr1, const float* __restrict__ inv1,
    const int* __restrict__ rp3, const int* __restrict__ csr3, const float* __restrict__ inv3)
{
    int row = (blockIdx.x * 256 + threadIdx.x) >> 6;
    if (row >= NF) return;
    int lane = threadIdx.x & 63;
    int c = lane * 4;
    size_t o = (size_t)row * D + c;
    ushort4 gh = *(const ushort4*)(GH + o);
    ushort4 gl = *(const ushort4*)(GL + o);
    float v[4] = {bf2f(gh.x) + bf2f(gl.x), bf2f(gh.y) + bf2f(gl.y),
                  bf2f(gh.z) + bf2f(gl.z), bf2f(gh.w) + bf2f(gl.w)};
    float m[4] = {0, 0, 0, 0};
    int e0 = rp1[row], e1 = rp1[row + 1];
    for (int e = e0; e < e1; ++e) {
        float4 u = *(const float4*)(y + (size_t)csr1[e] * D + c);
        m[0] += u.x; m[1] += u.y; m[2] += u.z; m[3] += u.w;
    }
    float s1 = inv1[row];
    #pragma unroll
    for (int j = 0; j < 4; ++j) v[j] += s1 * m[j];
    m[0] = m[1] = m[2] = m[3] = 0.f;
    e0 = rp3[row]; e1 = rp3[row + 1];
    for (int e = e0; e < e1; ++e) {
        float4 u = *(const float4*)(y + (size_t)(NA + csr3[e]) * D + c);
        m[0] += u.x; m[1] += u.y; m[2] += u.z; m[3] += u.w;
    }
    float s3 = inv3[row];
    ushort4 oh, ol;
    float r0 = fmaxf(v[0] + s3 * m[0], 0.f);
    float r1 = fmaxf(v[1] + s3 * m[1], 0.f);
    float r2 = fmaxf(v[2] + s3 * m[2], 0.f);
    float r3 = fmaxf(v[3] + s3 * m[3], 0.f);
    oh.x = f2bf(r0); ol.x = f2bf(r0 - bf2f(oh.x));
    oh.y = f2bf(r1); ol.y = f2bf(r1 - bf2f(oh.y));
    oh.z = f2bf(r2); ol.z = f2bf(r2 - bf2f(oh.z));
    oh.w = f2bf(r3); ol.w = f2bf(r3 - bf2f(oh.w));
    *(ushort4*)(GH + o) = oh;
    *(ushort4*)(GL + o) = ol;
}

// ---- layer-1: out[f] = relu(G2+msgs) . W_out + b_out (fused readout) -------
__global__ __launch_bounds__(256) void msg_readout_kernel(
    const ushort* __restrict__ GH, const ushort* __restrict__ GL,
    const float* __restrict__ y,
    const int* __restrict__ rp1, const int* __restrict__ csr1, const float* __restrict__ inv1,
    const int* __restrict__ rp3, const int* __restrict__ csr3, const float* __restrict__ inv3,
    const float* __restrict__ wout, const float* __restrict__ bout,
    float* __restrict__ out)
{
    int row = (blockIdx.x * 256 + threadIdx.x) >> 6;
    if (row >= NF) return;
    int lane = threadIdx.x & 63;
    int c = lane * 4;
    size_t o = (size_t)row * D + c;
    ushort4 gh = *(const ushort4*)(GH + o);
    ushort4 gl = *(const ushort4*)(GL + o);
    float v[4] = {bf2f(gh.x) + bf2f(gl.x), bf2f(gh.y) + bf2f(gl.y),
                  bf2f(gh.z) + bf2f(gl.z), bf2f(gh.w) + bf2f(gl.w)};
    float m[4] = {0, 0, 0, 0};
    int e0 = rp1[row], e1 = rp1[row + 1];
    for (int e = e0; e < e1; ++e) {
        float4 u = *(const float4*)(y + (size_t)csr1[e] * D + c);
        m[0] += u.x; m[1] += u.y; m[2] += u.z; m[3] += u.w;
    }
    float s1 = inv1[row];
    #pragma unroll
    for (int j = 0; j < 4; ++j) v[j] += s1 * m[j];
    m[0] = m[1] = m[2] = m[3] = 0.f;
    e0 = rp3[row]; e1 = rp3[row + 1];
    for (int e = e0; e < e1; ++e) {
        float4 u = *(const float4*)(y + (size_t)(NA + csr3[e]) * D + c);
        m[0] += u.x; m[1] += u.y; m[2] += u.z; m[3] += u.w;
    }
    float s3 = inv3[row];
    float4 wv = *(const float4*)(wout + c);
    float pr = fmaxf(v[0] + s3 * m[0], 0.f) * wv.x
             + fmaxf(v[1] + s3 * m[1], 0.f) * wv.y
             + fmaxf(v[2] + s3 * m[2], 0.f) * wv.z
             + fmaxf(v[3] + s3 * m[3], 0.f) * wv.w;
    pr += __shfl_xor(pr, 1);
    pr += __shfl_xor(pr, 2);
    pr += __shfl_xor(pr, 4);
    pr += __shfl_xor(pr, 8);
    pr += __shfl_xor(pr, 16);
    pr += __shfl_xor(pr, 32);
    if (lane == 0) out[row] = pr + bout[0];
}

// ---- r0/r2: agg[dst] += hH[src] — 2 edges per wave, 16B/lane loads ---------
__global__ __launch_bounds__(256) void agg_small_kernel(
    const ushort* __restrict__ hH,
    const int* __restrict__ rp0, const int* __restrict__ csr0,
    const int* __restrict__ rp2, const int* __restrict__ csr2,
    float* __restrict__ agg)
{
    __shared__ float red[4][256];
    int b = blockIdx.x;
    const int* rp; const int* csr; int dstn, chunk, nch; float* arow;
    if (b < NA * 4) { dstn = b >> 2; chunk = b & 3; nch = 4;  rp = rp0; csr = csr0; arow = agg + (size_t)dstn * D; }
    else { int bb = b - NA * 4; dstn = bb >> 6; chunk = bb & 63; nch = 64; rp = rp2; csr = csr2; arow = agg + (size_t)(NA + dstn) * D; }
    int s = rp[dstn], e = rp[dstn + 1];
    int cnt = e - s;
    int lo = s + (int)((long long)cnt * chunk / nch);
    int hi = s + (int)((long long)cnt * (chunk + 1) / nch);
    int w = threadIdx.x >> 6, lane = threadIdx.x & 63;
    int span = hi - lo;
    int wlo = lo + (int)((long long)span * w / 4);
    int whi = lo + (int)((long long)span * (w + 1) / 4);
    int half = lane >> 5;                  // 0: edge p, 1: edge p+1
    int ch8 = (lane & 31) * 8;
    float acc[8] = {};
    int p = wlo;
    for (; p + 1 < whi; p += 2) {
        int r = csr[p + half];
        u16x8 v = *(const u16x8*)(hH + (size_t)r * D + ch8);
        #pragma unroll
        for (int j = 0; j < 8; ++j) acc[j] += bf2f(v[j]);
    }
    if (p < whi && half == 0) {
        int r = csr[p];
        u16x8 v = *(const u16x8*)(hH + (size_t)r * D + ch8);
        #pragma unroll
        for (int j = 0; j < 8; ++j) acc[j] += bf2f(v[j]);
    }
    #pragma unroll
    for (int j = 0; j < 8; ++j) acc[j] += __shfl_xor(acc[j], 32);
    if (lane < 32) {
        #pragma unroll
        for (int j = 0; j < 8; ++j) red[w][ch8 + j] = acc[j];
    }
    __syncthreads();
    int c = threadIdx.x;
    float total = red[0][c] + red[1][c] + red[2][c] + red[3][c];
    atomicAdd(arow + c, total);
}

// -- r0/r2 transform: G = relu(G + inv_deg*(agg @ Wr)) in place, split-store -
__global__ __launch_bounds__(256) void smallT_kernel(
    const float* __restrict__ agg, const float* __restrict__ basis,
    const float* __restrict__ comp,
    const float* __restrict__ inv0, const float* __restrict__ inv2,
    ushort* __restrict__ GH, ushort* __restrict__ GL)
{
    int row = blockIdx.x;            // 0..429
    int c = threadIdx.x;
    const float* a = agg + (size_t)row * D;
    int rel = (row < NA) ? 0 : 2;
    float c0 = comp[rel * 3 + 0], c1 = comp[rel * 3 + 1], c2 = comp[rel * 3 + 2];
    float scale = (row < NA) ? inv0[row] : inv2[row - NA];
    float acc = 0.f;
    #pragma unroll 4
    for (int k = 0; k < D; ++k) {
        float w = c0 * basis[k * D + c] + c1 * basis[DD + k * D + c]
                + c2 * basis[2 * DD + k * D + c];
        acc += a[k] * w;
    }
    size_t o = (size_t)(NF + row) * D + c;
    float v = fmaxf(bf2f(GH[o]) + bf2f(GL[o]) + scale * acc, 0.f);
    ushort hi = f2bf(v);
    GH[o] = hi;
    GL[o] = f2bf(v - bf2f(hi));
}

extern "C" void kernel_launch(void* const* d_in, const int* in_sizes, int n_in,
                              void* d_out, int out_size, void* d_ws, size_t ws_size,
                              hipStream_t stream)
{
    const float* xf = (const float*)d_in[0];
    const float* xa = (const float*)d_in[1];
    const float* xc = (const float*)d_in[2];
    const float* Wf = (const float*)d_in[3];
    const float* bf = (const float*)d_in[4];
    const float* Wa = (const float*)d_in[5];
    const float* ba = (const float*)d_in[6];
    const float* Wc = (const float*)d_in[7];
    const float* bc = (const float*)d_in[8];
    const float* basis0 = (const float*)d_in[9];
    const float* comp0  = (const float*)d_in[10];
    const float* root0  = (const float*)d_in[11];
    const float* bias0  = (const float*)d_in[12];
    const float* basis1 = (const float*)d_in[13];
    const float* comp1  = (const float*)d_in[14];
    const float* root1  = (const float*)d_in[15];
    const float* bias1  = (const float*)d_in[16];
    const float* Wout = (const float*)d_in[17];
    const float* bout = (const float*)d_in[18];
    const int* src0 = (const int*)d_in[19];
    const int* dst0 = (const int*)d_in[20];
    const int* src1 = (const int*)d_in[21];
    const int* dst1 = (const int*)d_in[22];
    const int* src2 = (const int*)d_in[23];
    const int* dst2 = (const int*)d_in[24];
    const int* src3 = (const int*)d_in[25];
    const int* dst3 = (const int*)d_in[26];
    float* out = (float*)d_out;

    char* ws = (char*)d_ws;
    size_t off = 0;
    auto alloc = [&](size_t bytes) -> char* {
        char* p = ws + off;
        off = (off + bytes + 255) & ~(size_t)255;
        return p;
    };
    ushort* hH  = (ushort*)alloc((size_t)NN * D * 2);
    ushort* hL  = (ushort*)alloc((size_t)NN * D * 2);
    ushort* gH  = (ushort*)alloc((size_t)NN * D * 2);
    ushort* gL  = (ushort*)alloc((size_t)NN * D * 2);
    // layer-1 GEMM output reuses hH/hL (dead after layer-0 consumers)
    ushort* g2H = hH;
    ushort* g2L = hL;
    ushort* WtH = (ushort*)alloc((size_t)DD * 2);
    ushort* WtL = (ushort*)alloc((size_t)DD * 2);
    float* ybuf   = (float*)alloc((size_t)(NA + NC) * D * 4);
    float* aggbuf = (float*)alloc((size_t)(NA + NC) * D * 4);
    int*   deg13  = (int*)  alloc((size_t)2 * NF * 4);
    int* deg1 = deg13; int* deg3 = deg13 + NF;
    float* inv1 = (float*)alloc((size_t)NF * 4);
    float* inv3 = (float*)alloc((size_t)NF * 4);
    float* inv0 = (float*)alloc((size_t)NA * 4);
    float* inv2 = (float*)alloc((size_t)NC * 4);
    int* rp0 = (int*)alloc((NA + 1) * 4);
    int* rp1 = (int*)alloc((size_t)(NF + 1) * 4);
    int* rp2 = (int*)alloc((NC + 1) * 4);
    int* rp3 = (int*)alloc((size_t)(NF + 1) * 4);
    int* cu1 = (int*)alloc((size_t)(NF + 1) * 4);
    int* cu3 = (int*)alloc((size_t)(NF + 1) * 4);
    int* csr0 = (int*)alloc((size_t)E * 4);
    int* csr1 = (int*)alloc((size_t)E * 4);
    int* csr2 = (int*)alloc((size_t)E * 4);
    int* csr3 = (int*)alloc((size_t)E * 4);
    int* bsum = (int*)alloc(256 * 4);
    int* bh0  = (int*)alloc((size_t)NSL * NA * 4);
    int* bh2  = (int*)alloc((size_t)NSL * NC * 4);
    (void)ws_size; (void)in_sizes; (void)n_in; (void)out_size;

    // ---- CSR build: r0/r2 via contention-free counting sort
    hist02_kernel<<<2 * NSL, 256, 0, stream>>>(dst0, dst2, bh0, bh2);
    scan02_kernel<<<1, 512, 0, stream>>>(bh0, bh2, rp0, rp2, inv0, inv2);
    fill02_kernel<<<2 * NSL, 256, 0, stream>>>(src0, dst0, src2, dst2, bh0, bh2, csr0, csr2);

    // ---- CSR build: r1/r3 via atomics (100K dsts, avg degree 2.5 — cheap)
    hipMemsetAsync(deg13, 0, (size_t)2 * NF * 4, stream);
    deg_count_kernel<<<(2 * E + 255) / 256, 256, 0, stream>>>(dst1, dst3, deg1, deg3);
    scanA_kernel<<<196, 1024, 0, stream>>>(deg1, deg3, bsum);
    scanB_kernel<<<1, 256, 0, stream>>>(bsum);
    scanC_kernel<<<196, 1024, 0, stream>>>(deg1, deg3, bsum, rp1, rp3, cu1, cu3, inv1, inv3);
    csr_fill13_kernel<<<(2 * E + 255) / 256, 256, 0, stream>>>(
        src1, dst1, src3, dst3, cu1, cu3, csr1, csr3);

    // ---- encoders (split-bf16 output planes)
    encode_kernel<32, 8><<<NF / 8, 256, 0, stream>>>(xf, Wf, bf, hH, hL, NF, 0);
    encode_kernel<16, 8><<<(NA + 7) / 8, 256, 0, stream>>>(xa, Wa, ba, hH, hL, NA, NF);
    encode_kernel<8, 8><<<(NC + 7) / 8, 256, 0, stream>>>(xc, Wc, bc, hH, hL, NC, NF + NA);

    // ---- layer 0: pure MFMA gemm -> G; then per-row-type finishers in place
    wsplit_kernel<<<D, D, 0, stream>>>(root0, WtH, WtL);
    y_kernel<<<NA + NC, 256, 0, stream>>>(hH, hL, basis0, comp0, ybuf);
    gemm_mfma<<<dim3((NN + 127) / 128, 2), 256, 0, stream>>>(
        hH, hL, WtH, WtL, bias0, gH, gL, NN);
    hipMemsetAsync(aggbuf, 0, (size_t)(NA + NC) * D * 4, stream);
    agg_small_kernel<<<NA * 4 + NC * 64, 256, 0, stream>>>(
        hH, rp0, csr0, rp2, csr2, aggbuf);
    smallT_kernel<<<NA + NC, 256, 0, stream>>>(aggbuf, basis0, comp0, inv0, inv2, gH, gL);
    msg_relu_kernel<<<(NF * 64 + 255) / 256, 256, 0, stream>>>(
        gH, gL, ybuf, rp1, csr1, inv1, rp3, csr3, inv3);

    // ---- layer 1 (flights only): pure gemm -> G2 (aliases h); readout -> out
    wsplit_kernel<<<D, D, 0, stream>>>(root1, WtH, WtL);
    y_kernel<<<NA + NC, 256, 0, stream>>>(gH, gL, basis1, comp1, ybuf);
    gemm_mfma<<<dim3((NF + 127) / 128, 2), 256, 0, stream>>>(
        gH, gL, WtH, WtL, bias1, g2H, g2L, NF);
    msg_readout_kernel<<<(NF * 64 + 255) / 256, 256, 0, stream>>>(
        g2H, g2L, ybuf, rp1, csr1, inv1, rp3, csr3, inv3, Wout, bout, out);
}

// Round 12
// 478.467 us; speedup vs baseline: 1.1142x; 1.1142x over previous
//
#include <hip/hip_runtime.h>
#include <hip/hip_bf16.h>
#include <cstdint>
#include <cstddef>

constexpr int NF = 100000;
constexpr int NA = 400;
constexpr int NC = 30;
constexpr int NN = NF + NA + NC;     // 100430
constexpr int D  = 256;
constexpr int DD = D * D;            // 65536
constexpr int E  = 250000;
constexpr int NSL = 128;             // slices for r0/r2 counting sort

typedef __attribute__((ext_vector_type(8))) short bf16x8;
typedef __attribute__((ext_vector_type(4))) float f32x4;
typedef __attribute__((ext_vector_type(8))) ushort u16x8;

__device__ inline ushort f2bf(float f) {
    __hip_bfloat16 h = __float2bfloat16(f);
    return __builtin_bit_cast(ushort, h);
}
__device__ inline float bf2f(ushort u) {
    __hip_bfloat16 h = __builtin_bit_cast(__hip_bfloat16, u);
    return __bfloat162float(h);
}

// async global->LDS, 16B per lane: LDS dest = base + lane*16 (wave-linear)
__device__ inline void gload_lds16(const ushort* g, ushort* l) {
    __builtin_amdgcn_global_load_lds(
        (const __attribute__((address_space(1))) void*)g,
        (__attribute__((address_space(3))) void*)l, 16, 0, 0);
}

// ---------------- per-type encoders: h = relu(x @ W + b) -> bf16 ------------
template<int K, int ROWS>
__global__ __launch_bounds__(256) void encode_kernel(
    const float* __restrict__ x, const float* __restrict__ W,
    const float* __restrict__ b, ushort* __restrict__ hH,
    int rows, int row_off)
{
    int c = threadIdx.x;
    int base = blockIdx.x * ROWS;
    float wcol[K];
    #pragma unroll
    for (int k = 0; k < K; ++k) wcol[k] = W[k * D + c];
    float bias = b[c];
    for (int i = 0; i < ROWS; ++i) {
        int row = base + i;
        if (row >= rows) return;
        const float* xr = x + (size_t)row * K;
        float acc = bias;
        #pragma unroll
        for (int k = 0; k < K; ++k) acc += xr[k] * wcol[k];
        hH[(size_t)(row_off + row) * D + c] = f2bf(fmaxf(acc, 0.f));
    }
}

// ---------------- weight split+transpose: root[k][n] -> WtH/WtL[n][k] -------
__global__ __launch_bounds__(256) void wsplit_kernel(
    const float* __restrict__ root, ushort* __restrict__ WtH, ushort* __restrict__ WtL)
{
    int n = blockIdx.x, k = threadIdx.x;
    float w = root[(size_t)k * D + n];
    ushort hi = f2bf(w);
    WtH[(size_t)n * D + k] = hi;
    WtL[(size_t)n * D + k] = f2bf(w - bf2f(hi));
}

// ---------------- r1/r3 degree count (low contention: 100K dsts) ----------
__global__ __launch_bounds__(256) void deg_count_kernel(
    const int* __restrict__ dst1, const int* __restrict__ dst3,
    int* __restrict__ deg1, int* __restrict__ deg3)
{
    int idx = blockIdx.x * 256 + threadIdx.x;
    if (idx >= 2 * E) return;
    if (idx < E) atomicAdd(&deg1[dst1[idx]], 1);
    else         atomicAdd(&deg3[dst3[idx - E]], 1);
}

// ---------------- r0/r2: per-slice LDS histograms (contention-free) --------
__global__ __launch_bounds__(256) void hist02_kernel(
    const int* __restrict__ dst0, const int* __restrict__ dst2,
    int* __restrict__ bh0, int* __restrict__ bh2)
{
    __shared__ int hist[NA];
    int b = blockIdx.x;                 // 0..2*NSL-1
    bool isR2 = (b >= NSL);
    int sl = isR2 ? b - NSL : b;
    const int* dst = isR2 ? dst2 : dst0;
    int nb = isR2 ? NC : NA;
    for (int i = threadIdx.x; i < nb; i += 256) hist[i] = 0;
    __syncthreads();
    int lo = (int)((long long)E * sl / NSL);
    int hi = (int)((long long)E * (sl + 1) / NSL);
    for (int e = lo + threadIdx.x; e < hi; e += 256)
        atomicAdd(&hist[dst[e]], 1);
    __syncthreads();
    int* bh = isR2 ? (bh2 + sl * NC) : (bh0 + sl * NA);
    for (int i = threadIdx.x; i < nb; i += 256) bh[i] = hist[i];
}

// -------- scan: per-bin over slices + cross-bin; emits rp/inv + abs offsets -
__global__ __launch_bounds__(512) void scan02_kernel(
    int* __restrict__ bh0, int* __restrict__ bh2,
    int* __restrict__ rp0, int* __restrict__ rp2,
    float* __restrict__ inv0, float* __restrict__ inv2)
{
    __shared__ int tot[512];
    __shared__ int exc[512];
    int t = threadIdx.x;
    int cnt = 0;
    if (t < NA) {
        int s = 0;
        for (int sl = 0; sl < NSL; ++sl) {
            int v = bh0[sl * NA + t]; bh0[sl * NA + t] = s; s += v;
        }
        cnt = s;
    } else if (t < NA + NC) {
        int bin = t - NA; int s = 0;
        for (int sl = 0; sl < NSL; ++sl) {
            int v = bh2[sl * NC + bin]; bh2[sl * NC + bin] = s; s += v;
        }
        cnt = s;
    }
    tot[t] = cnt;
    __syncthreads();
    for (int ofs = 1; ofs < 512; ofs <<= 1) {
        int v = (t >= ofs) ? tot[t - ofs] : 0;
        __syncthreads();
        tot[t] += v;
        __syncthreads();
    }
    int ex = tot[t] - cnt;              // exclusive over combined [r0 | r2]
    if (t < NA) {
        exc[t] = ex;
        rp0[t] = ex;
        inv0[t] = 1.0f / (float)(cnt > 1 ? cnt : 1);
        if (t == 0) { rp0[NA] = E; rp2[NC] = E; }
    } else if (t < NA + NC) {
        exc[t] = ex - E;                // r2 csr buffer is its own array
        rp2[t - NA] = ex - E;
        inv2[t - NA] = 1.0f / (float)(cnt > 1 ? cnt : 1);
    } else exc[t] = 0;
    __syncthreads();
    for (int idx = t; idx < NSL * NA; idx += 512) {
        int sl = idx / NA; int bin = idx - sl * NA;
        bh0[idx] += exc[bin];
    }
    for (int idx = t; idx < NSL * NC; idx += 512) {
        int sl = idx / NC; int bin = idx - sl * NC;
        bh2[idx] += exc[NA + bin];
    }
}

// ---------------- r0/r2 CSR fill with LDS cursors --------------------------
__global__ __launch_bounds__(256) void fill02_kernel(
    const int* __restrict__ src0, const int* __restrict__ dst0,
    const int* __restrict__ src2, const int* __restrict__ dst2,
    const int* __restrict__ bh0, const int* __restrict__ bh2,
    int* __restrict__ csr0, int* __restrict__ csr2)
{
    __shared__ int cur[NA];
    int b = blockIdx.x;
    bool isR2 = (b >= NSL);
    int sl = isR2 ? b - NSL : b;
    const int* src = isR2 ? src2 : src0;
    const int* dst = isR2 ? dst2 : dst0;
    const int* bh  = isR2 ? (bh2 + sl * NC) : (bh0 + sl * NA);
    int* csr       = isR2 ? csr2 : csr0;
    int nb = isR2 ? NC : NA;
    for (int i = threadIdx.x; i < nb; i += 256) cur[i] = bh[i];
    __syncthreads();
    int lo = (int)((long long)E * sl / NSL);
    int hi = (int)((long long)E * (sl + 1) / NSL);
    for (int e = lo + threadIdx.x; e < hi; e += 256) {
        int pos = atomicAdd(&cur[dst[e]], 1);
        csr[pos] = src[e];
    }
}

// ---------------- r1/r3 scan chain -----------------------------------------
__global__ __launch_bounds__(1024) void scanA_kernel(
    const int* __restrict__ deg1, const int* __restrict__ deg3, int* __restrict__ bsum)
{
    __shared__ int s[1024];
    int b = blockIdx.x;                    // 0..195
    bool isR3 = (b >= 98);
    const int* deg = isR3 ? deg3 : deg1;
    int chunk = isR3 ? b - 98 : b;
    int i = chunk * 1024 + threadIdx.x;
    int v = (i < NF) ? deg[i] : 0;
    s[threadIdx.x] = v;
    __syncthreads();
    for (int ofs = 512; ofs > 0; ofs >>= 1) {
        if ((int)threadIdx.x < ofs) s[threadIdx.x] += s[threadIdx.x + ofs];
        __syncthreads();
    }
    if (threadIdx.x == 0) bsum[(isR3 ? 128 : 0) + chunk] = s[0];
}

__global__ __launch_bounds__(256) void scanB_kernel(int* __restrict__ bsum)
{
    __shared__ int s[256];
    int t = threadIdx.x;
    int v = ((t & 127) < 98) ? bsum[t] : 0;
    s[t] = v;
    __syncthreads();
    for (int ofs = 1; ofs < 128; ofs <<= 1) {
        int a = ((t & 127) >= ofs) ? s[t - ofs] : 0;
        __syncthreads();
        s[t] += a;
        __syncthreads();
    }
    bsum[t] = s[t] - v;   // exclusive (segmented per 128-half)
}

__global__ __launch_bounds__(1024) void scanC_kernel(
    const int* __restrict__ deg1, const int* __restrict__ deg3,
    const int* __restrict__ bsum,
    int* __restrict__ rp1, int* __restrict__ rp3,
    int* __restrict__ cu1, int* __restrict__ cu3,
    float* __restrict__ inv1, float* __restrict__ inv3)
{
    __shared__ int s[1024];
    int b = blockIdx.x;                    // 0..195
    const int* deg; int* rp; int* cu; float* inv; int chunk; int prefix;
    if (b < 98) { deg = deg1; rp = rp1; cu = cu1; inv = inv1; chunk = b;      prefix = bsum[chunk]; }
    else        { deg = deg3; rp = rp3; cu = cu3; inv = inv3; chunk = b - 98; prefix = bsum[128 + chunk]; }
    int tid = threadIdx.x;
    int i = chunk * 1024 + tid;
    int v = (i < NF) ? deg[i] : 0;
    s[tid] = v;
    __syncthreads();
    for (int ofs = 1; ofs < 1024; ofs <<= 1) {
        int a = (tid >= ofs) ? s[tid - ofs] : 0;
        __syncthreads();
        s[tid] += a;
        __syncthreads();
    }
    int ex = prefix + s[tid] - v;
    if (i < NF) {
        rp[i] = ex;
        cu[i] = ex;
        inv[i] = 1.0f / (float)(v > 1 ? v : 1);
    }
    if (i == 0) rp[NF] = E;
}

__global__ __launch_bounds__(256) void csr_fill13_kernel(
    const int* __restrict__ src1, const int* __restrict__ dst1,
    const int* __restrict__ src3, const int* __restrict__ dst3,
    int* __restrict__ cu1, int* __restrict__ cu3,
    int* __restrict__ csr1, int* __restrict__ csr3)
{
    int idx = blockIdx.x * 256 + threadIdx.x;
    if (idx >= 2 * E) return;
    if (idx < E) {
        int pos = atomicAdd(&cu1[dst1[idx]], 1);
        csr1[pos] = src1[idx];
    } else {
        int e = idx - E;
        int pos = atomicAdd(&cu3[dst3[e]], 1);
        csr3[pos] = src3[e];
    }
}

// ------- y = h[src-type rows] @ Wr (Wr combined from basis on the fly) ------
__global__ __launch_bounds__(256) void y_kernel(
    const ushort* __restrict__ hH,
    const float* __restrict__ basis, const float* __restrict__ comp,
    float* __restrict__ y)
{
    int row = blockIdx.x;            // 0..429  (airports then carriers)
    int c = threadIdx.x;
    const ushort* sH = hH + (size_t)(NF + row) * D;
    int rel = (row < NA) ? 1 : 3;
    float c0 = comp[rel * 3 + 0], c1 = comp[rel * 3 + 1], c2 = comp[rel * 3 + 2];
    float acc = 0.f;
    #pragma unroll 4
    for (int k = 0; k < D; ++k) {
        float w = c0 * basis[k * D + c] + c1 * basis[DD + k * D + c]
                + c2 * basis[2 * DD + k * D + c];
        acc += bf2f(sH[k]) * w;
    }
    y[(size_t)row * D + c] = acc;
}

// ---- bf16 MFMA GEMM: G = A @ root^T + bias (A single-plane, W split) ------
// Fragment-major global_load_lds staging: 3 planes (A, WtH, WtL) x 8 groups
// of 16 rows; lane l's fragment bytes at plane*8KB + g*1KB + l*16.
// Per (mi,ni): 2 MFMA (ah*bh + ah*bl) — A rounding error only (~1e-4 abs).
__global__ __launch_bounds__(256) void gemm_mfma(
    const ushort* __restrict__ A,
    const ushort* __restrict__ WtH, const ushort* __restrict__ WtL,
    const float* __restrict__ bias,
    ushort* __restrict__ G, int nrows)
{
    constexpr int BM = 128, BK = 32;
    constexpr int PLANE = BM * BK;          // 4096 ushorts = 8 KB
    constexpr int LDW = 68;                 // fp32 epilogue scratch stride
    __shared__ __align__(16) ushort lds[17408];   // max(staging 12288, epi 17408)
    const int t = threadIdx.x;
    const int row0 = blockIdx.x * BM;
    const int col0 = blockIdx.y * BM;
    const int w = t >> 6, lane = t & 63;
    const int wm = w >> 1, wn = w & 1;     // 2x2 wave grid, 64x64 per wave
    const int lr = lane & 15;
    const int lk = lane >> 4;
    f32x4 acc[4][4] = {};

    // staging: 24 (plane,group) units, wave w handles 6 consecutive
    const ushort* sp[6];
    ushort* dp[6];
    #pragma unroll
    for (int i = 0; i < 6; ++i) {
        int idx = w * 6 + i;
        int plane = idx >> 3, g = idx & 7;
        const ushort* base = (plane == 0) ? A : (plane == 1) ? WtH : WtL;
        int r = ((plane == 0) ? row0 : col0) + g * 16 + lr;
        if (plane == 0 && r >= nrows) r = nrows - 1;
        sp[i] = base + (size_t)r * D + lk * 8;
        dp[i] = lds + plane * PLANE + g * 512;
    }

    for (int k0 = 0; k0 < D; k0 += BK) {
        #pragma unroll
        for (int i = 0; i < 6; ++i)
            gload_lds16(sp[i] + k0, dp[i]);
        __syncthreads();                   // drains vmcnt -> tiles visible
        const ushort* As  = lds;
        const ushort* WsH = lds + PLANE;
        const ushort* WsL = lds + 2 * PLANE;
        bf16x8 bh[4], bl[4];
        #pragma unroll
        for (int ni = 0; ni < 4; ++ni) {
            int off = (wn * 4 + ni) * 512 + lane * 8;
            bh[ni] = *(const bf16x8*)(&WsH[off]);
            bl[ni] = *(const bf16x8*)(&WsL[off]);
        }
        #pragma unroll
        for (int mi = 0; mi < 4; ++mi) {
            int off = (wm * 4 + mi) * 512 + lane * 8;
            bf16x8 ah = *(const bf16x8*)(&As[off]);
            #pragma unroll
            for (int ni = 0; ni < 4; ++ni) {
                acc[mi][ni] = __builtin_amdgcn_mfma_f32_16x16x32_bf16(ah, bh[ni], acc[mi][ni], 0, 0, 0);
                acc[mi][ni] = __builtin_amdgcn_mfma_f32_16x16x32_bf16(ah, bl[ni], acc[mi][ni], 0, 0, 0);
            }
        }
        __syncthreads();                   // all reads done before overwrite
    }
    // ---- epilogue: stage through LDS for coalesced 16B stores ----
    float* S = (float*)lds + (size_t)w * 32 * LDW;   // per-wave 32x68 fp32
    const int rrow = lane >> 3;            // 0..7 read-back row group
    const int grp  = lane & 7;             // col octet
    #pragma unroll
    for (int p = 0; p < 2; ++p) {
        __syncthreads();
        #pragma unroll
        for (int mh = 0; mh < 2; ++mh) {
            int mi = p * 2 + mh;
            #pragma unroll
            for (int ni = 0; ni < 4; ++ni)
                #pragma unroll
                for (int reg = 0; reg < 4; ++reg)
                    S[(mh * 16 + lk * 4 + reg) * LDW + ni * 16 + lr] = acc[mi][ni][reg];
        }
        __syncthreads();
        #pragma unroll
        for (int iter = 0; iter < 4; ++iter) {
            int row_i = rrow + iter * 8;
            int gr = row0 + wm * 64 + p * 32 + row_i;
            int gc = col0 + wn * 64 + grp * 8;
            if (gr >= nrows) continue;
            float4 f0 = *(const float4*)(&S[row_i * LDW + grp * 8]);
            float4 f1 = *(const float4*)(&S[row_i * LDW + grp * 8 + 4]);
            float4 b0 = *(const float4*)(bias + gc);
            float4 b1 = *(const float4*)(bias + gc + 4);
            float v[8] = {f0.x + b0.x, f0.y + b0.y, f0.z + b0.z, f0.w + b0.w,
                          f1.x + b1.x, f1.y + b1.y, f1.z + b1.z, f1.w + b1.w};
            u16x8 hh;
            #pragma unroll
            for (int j = 0; j < 8; ++j) hh[j] = f2bf(v[j]);
            *(u16x8*)(G + (size_t)gr * D + gc) = hh;
        }
    }
}

// ---- layer-0 flight rows: G = relu(G + inv1*Σy1 + inv3*Σy3) in place ------
__global__ __launch_bounds__(256) void msg_relu_kernel(
    ushort* __restrict__ G,
    const float* __restrict__ y,
    const int* __restrict__ rp1, const int* __restrict__ csr1, const float* __restrict__ inv1,
    const int* __restrict__ rp3, const int* __restrict__ csr3, const float* __restrict__ inv3)
{
    int row = (blockIdx.x * 256 + threadIdx.x) >> 6;
    if (row >= NF) return;
    int lane = threadIdx.x & 63;
    int c = lane * 4;
    size_t o = (size_t)row * D + c;
    ushort4 gh = *(const ushort4*)(G + o);
    float v[4] = {bf2f(gh.x), bf2f(gh.y), bf2f(gh.z), bf2f(gh.w)};
    float m[4] = {0, 0, 0, 0};
    int e0 = rp1[row], e1 = rp1[row + 1];
    for (int e = e0; e < e1; ++e) {
        float4 u = *(const float4*)(y + (size_t)csr1[e] * D + c);
        m[0] += u.x; m[1] += u.y; m[2] += u.z; m[3] += u.w;
    }
    float s1 = inv1[row];
    #pragma unroll
    for (int j = 0; j < 4; ++j) v[j] += s1 * m[j];
    m[0] = m[1] = m[2] = m[3] = 0.f;
    e0 = rp3[row]; e1 = rp3[row + 1];
    for (int e = e0; e < e1; ++e) {
        float4 u = *(const float4*)(y + (size_t)(NA + csr3[e]) * D + c);
        m[0] += u.x; m[1] += u.y; m[2] += u.z; m[3] += u.w;
    }
    float s3 = inv3[row];
    ushort4 oh;
    oh.x = f2bf(fmaxf(v[0] + s3 * m[0], 0.f));
    oh.y = f2bf(fmaxf(v[1] + s3 * m[1], 0.f));
    oh.z = f2bf(fmaxf(v[2] + s3 * m[2], 0.f));
    oh.w = f2bf(fmaxf(v[3] + s3 * m[3], 0.f));
    *(ushort4*)(G + o) = oh;
}

// ---- layer-1: out[f] = relu(G2+msgs) . W_out + b_out (fused readout) -------
__global__ __launch_bounds__(256) void msg_readout_kernel(
    const ushort* __restrict__ G,
    const float* __restrict__ y,
    const int* __restrict__ rp1, const int* __restrict__ csr1, const float* __restrict__ inv1,
    const int* __restrict__ rp3, const int* __restrict__ csr3, const float* __restrict__ inv3,
    const float* __restrict__ wout, const float* __restrict__ bout,
    float* __restrict__ out)
{
    int row = (blockIdx.x * 256 + threadIdx.x) >> 6;
    if (row >= NF) return;
    int lane = threadIdx.x & 63;
    int c = lane * 4;
    size_t o = (size_t)row * D + c;
    ushort4 gh = *(const ushort4*)(G + o);
    float v[4] = {bf2f(gh.x), bf2f(gh.y), bf2f(gh.z), bf2f(gh.w)};
    float m[4] = {0, 0, 0, 0};
    int e0 = rp1[row], e1 = rp1[row + 1];
    for (int e = e0; e < e1; ++e) {
        float4 u = *(const float4*)(y + (size_t)csr1[e] * D + c);
        m[0] += u.x; m[1] += u.y; m[2] += u.z; m[3] += u.w;
    }
    float s1 = inv1[row];
    #pragma unroll
    for (int j = 0; j < 4; ++j) v[j] += s1 * m[j];
    m[0] = m[1] = m[2] = m[3] = 0.f;
    e0 = rp3[row]; e1 = rp3[row + 1];
    for (int e = e0; e < e1; ++e) {
        float4 u = *(const float4*)(y + (size_t)(NA + csr3[e]) * D + c);
        m[0] += u.x; m[1] += u.y; m[2] += u.z; m[3] += u.w;
    }
    float s3 = inv3[row];
    float4 wv = *(const float4*)(wout + c);
    float pr = fmaxf(v[0] + s3 * m[0], 0.f) * wv.x
             + fmaxf(v[1] + s3 * m[1], 0.f) * wv.y
             + fmaxf(v[2] + s3 * m[2], 0.f) * wv.z
             + fmaxf(v[3] + s3 * m[3], 0.f) * wv.w;
    pr += __shfl_xor(pr, 1);
    pr += __shfl_xor(pr, 2);
    pr += __shfl_xor(pr, 4);
    pr += __shfl_xor(pr, 8);
    pr += __shfl_xor(pr, 16);
    pr += __shfl_xor(pr, 32);
    if (lane == 0) out[row] = pr + bout[0];
}

// ---- r0/r2: agg[dst] += hH[src] — 2 edges per wave, 16B/lane loads ---------
__global__ __launch_bounds__(256) void agg_small_kernel(
    const ushort* __restrict__ hH,
    const int* __restrict__ rp0, const int* __restrict__ csr0,
    const int* __restrict__ rp2, const int* __restrict__ csr2,
    float* __restrict__ agg)
{
    __shared__ float red[4][256];
    int b = blockIdx.x;
    const int* rp; const int* csr; int dstn, chunk, nch; float* arow;
    if (b < NA * 4) { dstn = b >> 2; chunk = b & 3; nch = 4;  rp = rp0; csr = csr0; arow = agg + (size_t)dstn * D; }
    else { int bb = b - NA * 4; dstn = bb >> 6; chunk = bb & 63; nch = 64; rp = rp2; csr = csr2; arow = agg + (size_t)(NA + dstn) * D; }
    int s = rp[dstn], e = rp[dstn + 1];
    int cnt = e - s;
    int lo = s + (int)((long long)cnt * chunk / nch);
    int hi = s + (int)((long long)cnt * (chunk + 1) / nch);
    int w = threadIdx.x >> 6, lane = threadIdx.x & 63;
    int span = hi - lo;
    int wlo = lo + (int)((long long)span * w / 4);
    int whi = lo + (int)((long long)span * (w + 1) / 4);
    int half = lane >> 5;                  // 0: edge p, 1: edge p+1
    int ch8 = (lane & 31) * 8;
    float acc[8] = {};
    int p = wlo;
    for (; p + 1 < whi; p += 2) {
        int r = csr[p + half];
        u16x8 v = *(const u16x8*)(hH + (size_t)r * D + ch8);
        #pragma unroll
        for (int j = 0; j < 8; ++j) acc[j] += bf2f(v[j]);
    }
    if (p < whi && half == 0) {
        int r = csr[p];
        u16x8 v = *(const u16x8*)(hH + (size_t)r * D + ch8);
        #pragma unroll
        for (int j = 0; j < 8; ++j) acc[j] += bf2f(v[j]);
    }
    #pragma unroll
    for (int j = 0; j < 8; ++j) acc[j] += __shfl_xor(acc[j], 32);
    if (lane < 32) {
        #pragma unroll
        for (int j = 0; j < 8; ++j) red[w][ch8 + j] = acc[j];
    }
    __syncthreads();
    int c = threadIdx.x;
    float total = red[0][c] + red[1][c] + red[2][c] + red[3][c];
    atomicAdd(arow + c, total);
}

// -- r0/r2 transform: G = relu(G + inv_deg*(agg @ Wr)) in place --------------
__global__ __launch_bounds__(256) void smallT_kernel(
    const float* __restrict__ agg, const float* __restrict__ basis,
    const float* __restrict__ comp,
    const float* __restrict__ inv0, const float* __restrict__ inv2,
    ushort* __restrict__ G)
{
    int row = blockIdx.x;            // 0..429
    int c = threadIdx.x;
    const float* a = agg + (size_t)row * D;
    int rel = (row < NA) ? 0 : 2;
    float c0 = comp[rel * 3 + 0], c1 = comp[rel * 3 + 1], c2 = comp[rel * 3 + 2];
    float scale = (row < NA) ? inv0[row] : inv2[row - NA];
    float acc = 0.f;
    #pragma unroll 4
    for (int k = 0; k < D; ++k) {
        float w = c0 * basis[k * D + c] + c1 * basis[DD + k * D + c]
                + c2 * basis[2 * DD + k * D + c];
        acc += a[k] * w;
    }
    size_t o = (size_t)(NF + row) * D + c;
    G[o] = f2bf(fmaxf(bf2f(G[o]) + scale * acc, 0.f));
}

extern "C" void kernel_launch(void* const* d_in, const int* in_sizes, int n_in,
                              void* d_out, int out_size, void* d_ws, size_t ws_size,
                              hipStream_t stream)
{
    const float* xf = (const float*)d_in[0];
    const float* xa = (const float*)d_in[1];
    const float* xc = (const float*)d_in[2];
    const float* Wf = (const float*)d_in[3];
    const float* bf = (const float*)d_in[4];
    const float* Wa = (const float*)d_in[5];
    const float* ba = (const float*)d_in[6];
    const float* Wc = (const float*)d_in[7];
    const float* bc = (const float*)d_in[8];
    const float* basis0 = (const float*)d_in[9];
    const float* comp0  = (const float*)d_in[10];
    const float* root0  = (const float*)d_in[11];
    const float* bias0  = (const float*)d_in[12];
    const float* basis1 = (const float*)d_in[13];
    const float* comp1  = (const float*)d_in[14];
    const float* root1  = (const float*)d_in[15];
    const float* bias1  = (const float*)d_in[16];
    const float* Wout = (const float*)d_in[17];
    const float* bout = (const float*)d_in[18];
    const int* src0 = (const int*)d_in[19];
    const int* dst0 = (const int*)d_in[20];
    const int* src1 = (const int*)d_in[21];
    const int* dst1 = (const int*)d_in[22];
    const int* src2 = (const int*)d_in[23];
    const int* dst2 = (const int*)d_in[24];
    const int* src3 = (const int*)d_in[25];
    const int* dst3 = (const int*)d_in[26];
    float* out = (float*)d_out;

    char* ws = (char*)d_ws;
    size_t off = 0;
    auto alloc = [&](size_t bytes) -> char* {
        char* p = ws + off;
        off = (off + bytes + 255) & ~(size_t)255;
        return p;
    };
    ushort* hH  = (ushort*)alloc((size_t)NN * D * 2);
    ushort* gH  = (ushort*)alloc((size_t)NN * D * 2);
    // layer-1 GEMM output reuses hH (dead after layer-0 consumers)
    ushort* g2H = hH;
    ushort* WtH = (ushort*)alloc((size_t)DD * 2);
    ushort* WtL = (ushort*)alloc((size_t)DD * 2);
    float* ybuf   = (float*)alloc((size_t)(NA + NC) * D * 4);
    float* aggbuf = (float*)alloc((size_t)(NA + NC) * D * 4);
    int*   deg13  = (int*)  alloc((size_t)2 * NF * 4);
    int* deg1 = deg13; int* deg3 = deg13 + NF;
    float* inv1 = (float*)alloc((size_t)NF * 4);
    float* inv3 = (float*)alloc((size_t)NF * 4);
    float* inv0 = (float*)alloc((size_t)NA * 4);
    float* inv2 = (float*)alloc((size_t)NC * 4);
    int* rp0 = (int*)alloc((NA + 1) * 4);
    int* rp1 = (int*)alloc((size_t)(NF + 1) * 4);
    int* rp2 = (int*)alloc((NC + 1) * 4);
    int* rp3 = (int*)alloc((size_t)(NF + 1) * 4);
    int* cu1 = (int*)alloc((size_t)(NF + 1) * 4);
    int* cu3 = (int*)alloc((size_t)(NF + 1) * 4);
    int* csr0 = (int*)alloc((size_t)E * 4);
    int* csr1 = (int*)alloc((size_t)E * 4);
    int* csr2 = (int*)alloc((size_t)E * 4);
    int* csr3 = (int*)alloc((size_t)E * 4);
    int* bsum = (int*)alloc(256 * 4);
    int* bh0  = (int*)alloc((size_t)NSL * NA * 4);
    int* bh2  = (int*)alloc((size_t)NSL * NC * 4);
    (void)ws_size; (void)in_sizes; (void)n_in; (void)out_size;

    // ---- CSR build: r0/r2 via contention-free counting sort
    hist02_kernel<<<2 * NSL, 256, 0, stream>>>(dst0, dst2, bh0, bh2);
    scan02_kernel<<<1, 512, 0, stream>>>(bh0, bh2, rp0, rp2, inv0, inv2);
    fill02_kernel<<<2 * NSL, 256, 0, stream>>>(src0, dst0, src2, dst2, bh0, bh2, csr0, csr2);

    // ---- CSR build: r1/r3 via atomics (100K dsts, avg degree 2.5 — cheap)
    hipMemsetAsync(deg13, 0, (size_t)2 * NF * 4, stream);
    deg_count_kernel<<<(2 * E + 255) / 256, 256, 0, stream>>>(dst1, dst3, deg1, deg3);
    scanA_kernel<<<196, 1024, 0, stream>>>(deg1, deg3, bsum);
    scanB_kernel<<<1, 256, 0, stream>>>(bsum);
    scanC_kernel<<<196, 1024, 0, stream>>>(deg1, deg3, bsum, rp1, rp3, cu1, cu3, inv1, inv3);
    csr_fill13_kernel<<<(2 * E + 255) / 256, 256, 0, stream>>>(
        src1, dst1, src3, dst3, cu1, cu3, csr1, csr3);

    // ---- encoders (single bf16 plane)
    encode_kernel<32, 8><<<NF / 8, 256, 0, stream>>>(xf, Wf, bf, hH, NF, 0);
    encode_kernel<16, 8><<<(NA + 7) / 8, 256, 0, stream>>>(xa, Wa, ba, hH, NA, NF);
    encode_kernel<8, 8><<<(NC + 7) / 8, 256, 0, stream>>>(xc, Wc, bc, hH, NC, NF + NA);

    // ---- layer 0: pure MFMA gemm -> G; then per-row-type finishers in place
    wsplit_kernel<<<D, D, 0, stream>>>(root0, WtH, WtL);
    y_kernel<<<NA + NC, 256, 0, stream>>>(hH, basis0, comp0, ybuf);
    gemm_mfma<<<dim3((NN + 127) / 128, 2), 256, 0, stream>>>(
        hH, WtH, WtL, bias0, gH, NN);
    hipMemsetAsync(aggbuf, 0, (size_t)(NA + NC) * D * 4, stream);
    agg_small_kernel<<<NA * 4 + NC * 64, 256, 0, stream>>>(
        hH, rp0, csr0, rp2, csr2, aggbuf);
    smallT_kernel<<<NA + NC, 256, 0, stream>>>(aggbuf, basis0, comp0, inv0, inv2, gH);
    msg_relu_kernel<<<(NF * 64 + 255) / 256, 256, 0, stream>>>(
        gH, ybuf, rp1, csr1, inv1, rp3, csr3, inv3);

    // ---- layer 1 (flights only): pure gemm -> G2 (aliases h); readout -> out
    wsplit_kernel<<<D, D, 0, stream>>>(root1, WtH, WtL);
    y_kernel<<<NA + NC, 256, 0, stream>>>(gH, basis1, comp1, ybuf);
    gemm_mfma<<<dim3((NF + 127) / 128, 2), 256, 0, stream>>>(
        gH, WtH, WtL, bias1, g2H, NF);
    msg_readout_kernel<<<(NF * 64 + 255) / 256, 256, 0, stream>>>(
        g2H, ybuf, rp1, csr1, inv1, rp3, csr3, inv3, Wout, bout, out);
}

// Round 13
// 448.202 us; speedup vs baseline: 1.1894x; 1.0675x over previous
//
#include <hip/hip_runtime.h>
#include <hip/hip_bf16.h>
#include <cstdint>
#include <cstddef>

constexpr int NF = 100000;
constexpr int NA = 400;
constexpr int NC = 30;
constexpr int NN = NF + NA + NC;     // 100430
constexpr int D  = 256;
constexpr int DD = D * D;            // 65536
constexpr int E  = 250000;
constexpr int NSL = 128;             // slices for r0/r2 counting sort

typedef __attribute__((ext_vector_type(8))) short bf16x8;
typedef __attribute__((ext_vector_type(4))) float f32x4;
typedef __attribute__((ext_vector_type(8))) ushort u16x8;

__device__ inline ushort f2bf(float f) {
    __hip_bfloat16 h = __float2bfloat16(f);
    return __builtin_bit_cast(ushort, h);
}
__device__ inline float bf2f(ushort u) {
    __hip_bfloat16 h = __builtin_bit_cast(__hip_bfloat16, u);
    return __bfloat162float(h);
}

// async global->LDS, 16B per lane: LDS dest = base + lane*16 (wave-linear)
__device__ inline void gload_lds16(const ushort* g, ushort* l) {
    __builtin_amdgcn_global_load_lds(
        (const __attribute__((address_space(1))) void*)g,
        (__attribute__((address_space(3))) void*)l, 16, 0, 0);
}

// ---------------- per-type encoders: h = relu(x @ W + b) -> bf16 ------------
template<int K, int ROWS>
__global__ __launch_bounds__(256) void encode_kernel(
    const float* __restrict__ x, const float* __restrict__ W,
    const float* __restrict__ b, ushort* __restrict__ hH,
    int rows, int row_off)
{
    int c = threadIdx.x;
    int base = blockIdx.x * ROWS;
    float wcol[K];
    #pragma unroll
    for (int k = 0; k < K; ++k) wcol[k] = W[k * D + c];
    float bias = b[c];
    for (int i = 0; i < ROWS; ++i) {
        int row = base + i;
        if (row >= rows) return;
        const float* xr = x + (size_t)row * K;
        float acc = bias;
        #pragma unroll
        for (int k = 0; k < K; ++k) acc += xr[k] * wcol[k];
        hH[(size_t)(row_off + row) * D + c] = f2bf(fmaxf(acc, 0.f));
    }
}

// ---------------- weight split+transpose: root[k][n] -> WtH/WtL[n][k] -------
__global__ __launch_bounds__(256) void wsplit_kernel(
    const float* __restrict__ root, ushort* __restrict__ WtH, ushort* __restrict__ WtL)
{
    int n = blockIdx.x, k = threadIdx.x;
    float w = root[(size_t)k * D + n];
    ushort hi = f2bf(w);
    WtH[(size_t)n * D + k] = hi;
    WtL[(size_t)n * D + k] = f2bf(w - bf2f(hi));
}

// ---------------- basis combine: Wr[r] = sum_b comp[r,b] * basis[b] ---------
__global__ __launch_bounds__(256) void wr_kernel(
    const float* __restrict__ basis, const float* __restrict__ comp,
    float* __restrict__ wr)
{
    int idx = blockIdx.x * 256 + threadIdx.x;   // < 4*DD
    int r = idx >> 16;
    int io = idx & (DD - 1);
    wr[idx] = comp[r * 3 + 0] * basis[io]
            + comp[r * 3 + 1] * basis[DD + io]
            + comp[r * 3 + 2] * basis[2 * DD + io];
}

// ---------------- r1/r3 degree count (low contention: 100K dsts) ----------
__global__ __launch_bounds__(256) void deg_count_kernel(
    const int* __restrict__ dst1, const int* __restrict__ dst3,
    int* __restrict__ deg1, int* __restrict__ deg3)
{
    int idx = blockIdx.x * 256 + threadIdx.x;
    if (idx >= 2 * E) return;
    if (idx < E) atomicAdd(&deg1[dst1[idx]], 1);
    else         atomicAdd(&deg3[dst3[idx - E]], 1);
}

// ---------------- r0/r2: per-slice LDS histograms (contention-free) --------
__global__ __launch_bounds__(256) void hist02_kernel(
    const int* __restrict__ dst0, const int* __restrict__ dst2,
    int* __restrict__ bh0, int* __restrict__ bh2)
{
    __shared__ int hist[NA];
    int b = blockIdx.x;                 // 0..2*NSL-1
    bool isR2 = (b >= NSL);
    int sl = isR2 ? b - NSL : b;
    const int* dst = isR2 ? dst2 : dst0;
    int nb = isR2 ? NC : NA;
    for (int i = threadIdx.x; i < nb; i += 256) hist[i] = 0;
    __syncthreads();
    int lo = (int)((long long)E * sl / NSL);
    int hi = (int)((long long)E * (sl + 1) / NSL);
    for (int e = lo + threadIdx.x; e < hi; e += 256)
        atomicAdd(&hist[dst[e]], 1);
    __syncthreads();
    int* bh = isR2 ? (bh2 + sl * NC) : (bh0 + sl * NA);
    for (int i = threadIdx.x; i < nb; i += 256) bh[i] = hist[i];
}

// -------- scan: per-bin over slices + cross-bin; emits rp/inv + abs offsets -
__global__ __launch_bounds__(512) void scan02_kernel(
    int* __restrict__ bh0, int* __restrict__ bh2,
    int* __restrict__ rp0, int* __restrict__ rp2,
    float* __restrict__ inv0, float* __restrict__ inv2)
{
    __shared__ int tot[512];
    __shared__ int exc[512];
    int t = threadIdx.x;
    int cnt = 0;
    if (t < NA) {
        int s = 0;
        for (int sl = 0; sl < NSL; ++sl) {
            int v = bh0[sl * NA + t]; bh0[sl * NA + t] = s; s += v;
        }
        cnt = s;
    } else if (t < NA + NC) {
        int bin = t - NA; int s = 0;
        for (int sl = 0; sl < NSL; ++sl) {
            int v = bh2[sl * NC + bin]; bh2[sl * NC + bin] = s; s += v;
        }
        cnt = s;
    }
    tot[t] = cnt;
    __syncthreads();
    for (int ofs = 1; ofs < 512; ofs <<= 1) {
        int v = (t >= ofs) ? tot[t - ofs] : 0;
        __syncthreads();
        tot[t] += v;
        __syncthreads();
    }
    int ex = tot[t] - cnt;              // exclusive over combined [r0 | r2]
    if (t < NA) {
        exc[t] = ex;
        rp0[t] = ex;
        inv0[t] = 1.0f / (float)(cnt > 1 ? cnt : 1);
        if (t == 0) { rp0[NA] = E; rp2[NC] = E; }
    } else if (t < NA + NC) {
        exc[t] = ex - E;                // r2 csr buffer is its own array
        rp2[t - NA] = ex - E;
        inv2[t - NA] = 1.0f / (float)(cnt > 1 ? cnt : 1);
    } else exc[t] = 0;
    __syncthreads();
    for (int idx = t; idx < NSL * NA; idx += 512) {
        int sl = idx / NA; int bin = idx - sl * NA;
        bh0[idx] += exc[bin];
    }
    for (int idx = t; idx < NSL * NC; idx += 512) {
        int sl = idx / NC; int bin = idx - sl * NC;
        bh2[idx] += exc[NA + bin];
    }
}

// ---------------- r0/r2 CSR fill with LDS cursors --------------------------
__global__ __launch_bounds__(256) void fill02_kernel(
    const int* __restrict__ src0, const int* __restrict__ dst0,
    const int* __restrict__ src2, const int* __restrict__ dst2,
    const int* __restrict__ bh0, const int* __restrict__ bh2,
    int* __restrict__ csr0, int* __restrict__ csr2)
{
    __shared__ int cur[NA];
    int b = blockIdx.x;
    bool isR2 = (b >= NSL);
    int sl = isR2 ? b - NSL : b;
    const int* src = isR2 ? src2 : src0;
    const int* dst = isR2 ? dst2 : dst0;
    const int* bh  = isR2 ? (bh2 + sl * NC) : (bh0 + sl * NA);
    int* csr       = isR2 ? csr2 : csr0;
    int nb = isR2 ? NC : NA;
    for (int i = threadIdx.x; i < nb; i += 256) cur[i] = bh[i];
    __syncthreads();
    int lo = (int)((long long)E * sl / NSL);
    int hi = (int)((long long)E * (sl + 1) / NSL);
    for (int e = lo + threadIdx.x; e < hi; e += 256) {
        int pos = atomicAdd(&cur[dst[e]], 1);
        csr[pos] = src[e];
    }
}

// ---------------- r1/r3 scan chain -----------------------------------------
__global__ __launch_bounds__(1024) void scanA_kernel(
    const int* __restrict__ deg1, const int* __restrict__ deg3, int* __restrict__ bsum)
{
    __shared__ int s[1024];
    int b = blockIdx.x;                    // 0..195
    bool isR3 = (b >= 98);
    const int* deg = isR3 ? deg3 : deg1;
    int chunk = isR3 ? b - 98 : b;
    int i = chunk * 1024 + threadIdx.x;
    int v = (i < NF) ? deg[i] : 0;
    s[threadIdx.x] = v;
    __syncthreads();
    for (int ofs = 512; ofs > 0; ofs >>= 1) {
        if ((int)threadIdx.x < ofs) s[threadIdx.x] += s[threadIdx.x + ofs];
        __syncthreads();
    }
    if (threadIdx.x == 0) bsum[(isR3 ? 128 : 0) + chunk] = s[0];
}

__global__ __launch_bounds__(256) void scanB_kernel(int* __restrict__ bsum)
{
    __shared__ int s[256];
    int t = threadIdx.x;
    int v = ((t & 127) < 98) ? bsum[t] : 0;
    s[t] = v;
    __syncthreads();
    for (int ofs = 1; ofs < 128; ofs <<= 1) {
        int a = ((t & 127) >= ofs) ? s[t - ofs] : 0;
        __syncthreads();
        s[t] += a;
        __syncthreads();
    }
    bsum[t] = s[t] - v;   // exclusive (segmented per 128-half)
}

__global__ __launch_bounds__(1024) void scanC_kernel(
    const int* __restrict__ deg1, const int* __restrict__ deg3,
    const int* __restrict__ bsum,
    int* __restrict__ rp1, int* __restrict__ rp3,
    int* __restrict__ cu1, int* __restrict__ cu3,
    float* __restrict__ inv1, float* __restrict__ inv3)
{
    __shared__ int s[1024];
    int b = blockIdx.x;                    // 0..195
    const int* deg; int* rp; int* cu; float* inv; int chunk; int prefix;
    if (b < 98) { deg = deg1; rp = rp1; cu = cu1; inv = inv1; chunk = b;      prefix = bsum[chunk]; }
    else        { deg = deg3; rp = rp3; cu = cu3; inv = inv3; chunk = b - 98; prefix = bsum[128 + chunk]; }
    int tid = threadIdx.x;
    int i = chunk * 1024 + tid;
    int v = (i < NF) ? deg[i] : 0;
    s[tid] = v;
    __syncthreads();
    for (int ofs = 1; ofs < 1024; ofs <<= 1) {
        int a = (tid >= ofs) ? s[tid - ofs] : 0;
        __syncthreads();
        s[tid] += a;
        __syncthreads();
    }
    int ex = prefix + s[tid] - v;
    if (i < NF) {
        rp[i] = ex;
        cu[i] = ex;
        inv[i] = 1.0f / (float)(v > 1 ? v : 1);
    }
    if (i == 0) rp[NF] = E;
}

__global__ __launch_bounds__(256) void csr_fill13_kernel(
    const int* __restrict__ src1, const int* __restrict__ dst1,
    const int* __restrict__ src3, const int* __restrict__ dst3,
    int* __restrict__ cu1, int* __restrict__ cu3,
    int* __restrict__ csr1, int* __restrict__ csr3)
{
    int idx = blockIdx.x * 256 + threadIdx.x;
    if (idx >= 2 * E) return;
    if (idx < E) {
        int pos = atomicAdd(&cu1[dst1[idx]], 1);
        csr1[pos] = src1[idx];
    } else {
        int e = idx - E;
        int pos = atomicAdd(&cu3[dst3[e]], 1);
        csr3[pos] = src3[e];
    }
}

// ------- y = h[src-type rows] @ Wr[rel]  (Wr precomputed) -------------------
__global__ __launch_bounds__(256) void y_kernel(
    const ushort* __restrict__ hH, const float* __restrict__ wr,
    float* __restrict__ y)
{
    int row = blockIdx.x;            // 0..429  (airports then carriers)
    int c = threadIdx.x;
    const ushort* sH = hH + (size_t)(NF + row) * D;
    const float* W = wr + (size_t)((row < NA) ? 1 : 3) * DD;
    float acc = 0.f;
    #pragma unroll 8
    for (int k = 0; k < D; ++k) acc += bf2f(sH[k]) * W[k * D + c];
    y[(size_t)row * D + c] = acc;
}

// ---- bf16 MFMA GEMM: G = A @ root^T + bias (A single-plane, W split) ------
// Fragment-major global_load_lds staging: 3 planes (A, WtH, WtL) x 8 groups
// of 16 rows; lane l's fragment bytes at plane*8KB + g*1KB + l*16.
// Epilogue is 4 passes of 16 rows -> per-wave scratch 4352B, so total LDS
// stays at the staging footprint (24576B) => up to 6 blocks/CU.
__global__ __launch_bounds__(256) void gemm_mfma(
    const ushort* __restrict__ A,
    const ushort* __restrict__ WtH, const ushort* __restrict__ WtL,
    const float* __restrict__ bias,
    ushort* __restrict__ G, int nrows)
{
    constexpr int BM = 128, BK = 32;
    constexpr int PLANE = BM * BK;          // 4096 ushorts = 8 KB
    constexpr int LDW = 68;                 // fp32 epilogue scratch stride
    __shared__ __align__(16) ushort lds[12288];   // 24576 B
    const int t = threadIdx.x;
    const int row0 = blockIdx.x * BM;
    const int col0 = blockIdx.y * BM;
    const int w = t >> 6, lane = t & 63;
    const int wm = w >> 1, wn = w & 1;     // 2x2 wave grid, 64x64 per wave
    const int lr = lane & 15;
    const int lk = lane >> 4;
    f32x4 acc[4][4] = {};

    // staging: 24 (plane,group) units, wave w handles 6 consecutive
    const ushort* sp[6];
    ushort* dp[6];
    #pragma unroll
    for (int i = 0; i < 6; ++i) {
        int idx = w * 6 + i;
        int plane = idx >> 3, g = idx & 7;
        const ushort* base = (plane == 0) ? A : (plane == 1) ? WtH : WtL;
        int r = ((plane == 0) ? row0 : col0) + g * 16 + lr;
        if (plane == 0 && r >= nrows) r = nrows - 1;
        sp[i] = base + (size_t)r * D + lk * 8;
        dp[i] = lds + plane * PLANE + g * 512;
    }

    for (int k0 = 0; k0 < D; k0 += BK) {
        #pragma unroll
        for (int i = 0; i < 6; ++i)
            gload_lds16(sp[i] + k0, dp[i]);
        __syncthreads();                   // drains vmcnt -> tiles visible
        const ushort* As  = lds;
        const ushort* WsH = lds + PLANE;
        const ushort* WsL = lds + 2 * PLANE;
        bf16x8 bh[4], bl[4];
        #pragma unroll
        for (int ni = 0; ni < 4; ++ni) {
            int off = (wn * 4 + ni) * 512 + lane * 8;
            bh[ni] = *(const bf16x8*)(&WsH[off]);
            bl[ni] = *(const bf16x8*)(&WsL[off]);
        }
        #pragma unroll
        for (int mi = 0; mi < 4; ++mi) {
            int off = (wm * 4 + mi) * 512 + lane * 8;
            bf16x8 ah = *(const bf16x8*)(&As[off]);
            #pragma unroll
            for (int ni = 0; ni < 4; ++ni) {
                acc[mi][ni] = __builtin_amdgcn_mfma_f32_16x16x32_bf16(ah, bh[ni], acc[mi][ni], 0, 0, 0);
                acc[mi][ni] = __builtin_amdgcn_mfma_f32_16x16x32_bf16(ah, bl[ni], acc[mi][ni], 0, 0, 0);
            }
        }
        __syncthreads();                   // all reads done before overwrite
    }
    // ---- epilogue: 4 passes of 16 rows through LDS, coalesced 16B stores ---
    float* S = (float*)lds + (size_t)w * 16 * LDW;   // per-wave 16x68 fp32
    const int rrow = lane >> 3;            // 0..7 read-back row group
    const int grp  = lane & 7;             // col octet
    #pragma unroll
    for (int mi = 0; mi < 4; ++mi) {
        __syncthreads();
        #pragma unroll
        for (int ni = 0; ni < 4; ++ni)
            #pragma unroll
            for (int reg = 0; reg < 4; ++reg)
                S[(lk * 4 + reg) * LDW + ni * 16 + lr] = acc[mi][ni][reg];
        __syncthreads();
        #pragma unroll
        for (int iter = 0; iter < 2; ++iter) {
            int row_i = rrow + iter * 8;
            int gr = row0 + wm * 64 + mi * 16 + row_i;
            int gc = col0 + wn * 64 + grp * 8;
            if (gr >= nrows) continue;
            float4 f0 = *(const float4*)(&S[row_i * LDW + grp * 8]);
            float4 f1 = *(const float4*)(&S[row_i * LDW + grp * 8 + 4]);
            float4 b0 = *(const float4*)(bias + gc);
            float4 b1 = *(const float4*)(bias + gc + 4);
            float v[8] = {f0.x + b0.x, f0.y + b0.y, f0.z + b0.z, f0.w + b0.w,
                          f1.x + b1.x, f1.y + b1.y, f1.z + b1.z, f1.w + b1.w};
            u16x8 hh;
            #pragma unroll
            for (int j = 0; j < 8; ++j) hh[j] = f2bf(v[j]);
            *(u16x8*)(G + (size_t)gr * D + gc) = hh;
        }
    }
}

// ---- layer-0 flight rows: G = relu(G + inv1*Σy1 + inv3*Σy3) in place ------
__global__ __launch_bounds__(256) void msg_relu_kernel(
    ushort* __restrict__ G,
    const float* __restrict__ y,
    const int* __restrict__ rp1, const int* __restrict__ csr1, const float* __restrict__ inv1,
    const int* __restrict__ rp3, const int* __restrict__ csr3, const float* __restrict__ inv3)
{
    int row = (blockIdx.x * 256 + threadIdx.x) >> 6;
    if (row >= NF) return;
    int lane = threadIdx.x & 63;
    int c = lane * 4;
    size_t o = (size_t)row * D + c;
    ushort4 gh = *(const ushort4*)(G + o);
    float v[4] = {bf2f(gh.x), bf2f(gh.y), bf2f(gh.z), bf2f(gh.w)};
    float m[4] = {0, 0, 0, 0};
    int e0 = rp1[row], e1 = rp1[row + 1];
    for (int e = e0; e < e1; ++e) {
        float4 u = *(const float4*)(y + (size_t)csr1[e] * D + c);
        m[0] += u.x; m[1] += u.y; m[2] += u.z; m[3] += u.w;
    }
    float s1 = inv1[row];
    #pragma unroll
    for (int j = 0; j < 4; ++j) v[j] += s1 * m[j];
    m[0] = m[1] = m[2] = m[3] = 0.f;
    e0 = rp3[row]; e1 = rp3[row + 1];
    for (int e = e0; e < e1; ++e) {
        float4 u = *(const float4*)(y + (size_t)(NA + csr3[e]) * D + c);
        m[0] += u.x; m[1] += u.y; m[2] += u.z; m[3] += u.w;
    }
    float s3 = inv3[row];
    ushort4 oh;
    oh.x = f2bf(fmaxf(v[0] + s3 * m[0], 0.f));
    oh.y = f2bf(fmaxf(v[1] + s3 * m[1], 0.f));
    oh.z = f2bf(fmaxf(v[2] + s3 * m[2], 0.f));
    oh.w = f2bf(fmaxf(v[3] + s3 * m[3], 0.f));
    *(ushort4*)(G + o) = oh;
}

// ---- layer-1: out[f] = relu(G2+msgs) . W_out + b_out (fused readout) -------
__global__ __launch_bounds__(256) void msg_readout_kernel(
    const ushort* __restrict__ G,
    const float* __restrict__ y,
    const int* __restrict__ rp1, const int* __restrict__ csr1, const float* __restrict__ inv1,
    const int* __restrict__ rp3, const int* __restrict__ csr3, const float* __restrict__ inv3,
    const float* __restrict__ wout, const float* __restrict__ bout,
    float* __restrict__ out)
{
    int row = (blockIdx.x * 256 + threadIdx.x) >> 6;
    if (row >= NF) return;
    int lane = threadIdx.x & 63;
    int c = lane * 4;
    size_t o = (size_t)row * D + c;
    ushort4 gh = *(const ushort4*)(G + o);
    float v[4] = {bf2f(gh.x), bf2f(gh.y), bf2f(gh.z), bf2f(gh.w)};
    float m[4] = {0, 0, 0, 0};
    int e0 = rp1[row], e1 = rp1[row + 1];
    for (int e = e0; e < e1; ++e) {
        float4 u = *(const float4*)(y + (size_t)csr1[e] * D + c);
        m[0] += u.x; m[1] += u.y; m[2] += u.z; m[3] += u.w;
    }
    float s1 = inv1[row];
    #pragma unroll
    for (int j = 0; j < 4; ++j) v[j] += s1 * m[j];
    m[0] = m[1] = m[2] = m[3] = 0.f;
    e0 = rp3[row]; e1 = rp3[row + 1];
    for (int e = e0; e < e1; ++e) {
        float4 u = *(const float4*)(y + (size_t)(NA + csr3[e]) * D + c);
        m[0] += u.x; m[1] += u.y; m[2] += u.z; m[3] += u.w;
    }
    float s3 = inv3[row];
    float4 wv = *(const float4*)(wout + c);
    float pr = fmaxf(v[0] + s3 * m[0], 0.f) * wv.x
             + fmaxf(v[1] + s3 * m[1], 0.f) * wv.y
             + fmaxf(v[2] + s3 * m[2], 0.f) * wv.z
             + fmaxf(v[3] + s3 * m[3], 0.f) * wv.w;
    pr += __shfl_xor(pr, 1);
    pr += __shfl_xor(pr, 2);
    pr += __shfl_xor(pr, 4);
    pr += __shfl_xor(pr, 8);
    pr += __shfl_xor(pr, 16);
    pr += __shfl_xor(pr, 32);
    if (lane == 0) out[row] = pr + bout[0];
}

// ---- r0/r2: agg[dst] += hH[src] — 2 edges per wave, 16B/lane loads ---------
__global__ __launch_bounds__(256) void agg_small_kernel(
    const ushort* __restrict__ hH,
    const int* __restrict__ rp0, const int* __restrict__ csr0,
    const int* __restrict__ rp2, const int* __restrict__ csr2,
    float* __restrict__ agg)
{
    __shared__ float red[4][256];
    int b = blockIdx.x;
    const int* rp; const int* csr; int dstn, chunk, nch; float* arow;
    if (b < NA * 4) { dstn = b >> 2; chunk = b & 3; nch = 4;  rp = rp0; csr = csr0; arow = agg + (size_t)dstn * D; }
    else { int bb = b - NA * 4; dstn = bb >> 6; chunk = bb & 63; nch = 64; rp = rp2; csr = csr2; arow = agg + (size_t)(NA + dstn) * D; }
    int s = rp[dstn], e = rp[dstn + 1];
    int cnt = e - s;
    int lo = s + (int)((long long)cnt * chunk / nch);
    int hi = s + (int)((long long)cnt * (chunk + 1) / nch);
    int w = threadIdx.x >> 6, lane = threadIdx.x & 63;
    int span = hi - lo;
    int wlo = lo + (int)((long long)span * w / 4);
    int whi = lo + (int)((long long)span * (w + 1) / 4);
    int half = lane >> 5;                  // 0: edge p, 1: edge p+1
    int ch8 = (lane & 31) * 8;
    float acc[8] = {};
    int p = wlo;
    for (; p + 1 < whi; p += 2) {
        int r = csr[p + half];
        u16x8 v = *(const u16x8*)(hH + (size_t)r * D + ch8);
        #pragma unroll
        for (int j = 0; j < 8; ++j) acc[j] += bf2f(v[j]);
    }
    if (p < whi && half == 0) {
        int r = csr[p];
        u16x8 v = *(const u16x8*)(hH + (size_t)r * D + ch8);
        #pragma unroll
        for (int j = 0; j < 8; ++j) acc[j] += bf2f(v[j]);
    }
    #pragma unroll
    for (int j = 0; j < 8; ++j) acc[j] += __shfl_xor(acc[j], 32);
    if (lane < 32) {
        #pragma unroll
        for (int j = 0; j < 8; ++j) red[w][ch8 + j] = acc[j];
    }
    __syncthreads();
    int c = threadIdx.x;
    float total = red[0][c] + red[1][c] + red[2][c] + red[3][c];
    atomicAdd(arow + c, total);
}

// -- r0/r2 transform: G = relu(G + inv_deg*(agg @ Wr[rel])) in place ---------
__global__ __launch_bounds__(256) void smallT_kernel(
    const float* __restrict__ agg, const float* __restrict__ wr,
    const float* __restrict__ inv0, const float* __restrict__ inv2,
    ushort* __restrict__ G)
{
    int row = blockIdx.x;            // 0..429
    int c = threadIdx.x;
    const float* a = agg + (size_t)row * D;
    const float* W = wr + (size_t)((row < NA) ? 0 : 2) * DD;
    float scale = (row < NA) ? inv0[row] : inv2[row - NA];
    float acc = 0.f;
    #pragma unroll 8
    for (int k = 0; k < D; ++k) acc += a[k] * W[k * D + c];
    size_t o = (size_t)(NF + row) * D + c;
    G[o] = f2bf(fmaxf(bf2f(G[o]) + scale * acc, 0.f));
}

extern "C" void kernel_launch(void* const* d_in, const int* in_sizes, int n_in,
                              void* d_out, int out_size, void* d_ws, size_t ws_size,
                              hipStream_t stream)
{
    const float* xf = (const float*)d_in[0];
    const float* xa = (const float*)d_in[1];
    const float* xc = (const float*)d_in[2];
    const float* Wf = (const float*)d_in[3];
    const float* bf = (const float*)d_in[4];
    const float* Wa = (const float*)d_in[5];
    const float* ba = (const float*)d_in[6];
    const float* Wc = (const float*)d_in[7];
    const float* bc = (const float*)d_in[8];
    const float* basis0 = (const float*)d_in[9];
    const float* comp0  = (const float*)d_in[10];
    const float* root0  = (const float*)d_in[11];
    const float* bias0  = (const float*)d_in[12];
    const float* basis1 = (const float*)d_in[13];
    const float* comp1  = (const float*)d_in[14];
    const float* root1  = (const float*)d_in[15];
    const float* bias1  = (const float*)d_in[16];
    const float* Wout = (const float*)d_in[17];
    const float* bout = (const float*)d_in[18];
    const int* src0 = (const int*)d_in[19];
    const int* dst0 = (const int*)d_in[20];
    const int* src1 = (const int*)d_in[21];
    const int* dst1 = (const int*)d_in[22];
    const int* src2 = (const int*)d_in[23];
    const int* dst2 = (const int*)d_in[24];
    const int* src3 = (const int*)d_in[25];
    const int* dst3 = (const int*)d_in[26];
    float* out = (float*)d_out;

    char* ws = (char*)d_ws;
    size_t off = 0;
    auto alloc = [&](size_t bytes) -> char* {
        char* p = ws + off;
        off = (off + bytes + 255) & ~(size_t)255;
        return p;
    };
    ushort* hH  = (ushort*)alloc((size_t)NN * D * 2);
    ushort* gH  = (ushort*)alloc((size_t)NN * D * 2);
    // layer-1 GEMM output reuses hH (dead after layer-0 consumers)
    ushort* g2H = hH;
    ushort* WtH = (ushort*)alloc((size_t)DD * 2);
    ushort* WtL = (ushort*)alloc((size_t)DD * 2);
    float* wrbuf  = (float*)alloc((size_t)4 * DD * 4);
    float* ybuf   = (float*)alloc((size_t)(NA + NC) * D * 4);
    float* aggbuf = (float*)alloc((size_t)(NA + NC) * D * 4);
    int*   deg13  = (int*)  alloc((size_t)2 * NF * 4);
    int* deg1 = deg13; int* deg3 = deg13 + NF;
    float* inv1 = (float*)alloc((size_t)NF * 4);
    float* inv3 = (float*)alloc((size_t)NF * 4);
    float* inv0 = (float*)alloc((size_t)NA * 4);
    float* inv2 = (float*)alloc((size_t)NC * 4);
    int* rp0 = (int*)alloc((NA + 1) * 4);
    int* rp1 = (int*)alloc((size_t)(NF + 1) * 4);
    int* rp2 = (int*)alloc((NC + 1) * 4);
    int* rp3 = (int*)alloc((size_t)(NF + 1) * 4);
    int* cu1 = (int*)alloc((size_t)(NF + 1) * 4);
    int* cu3 = (int*)alloc((size_t)(NF + 1) * 4);
    int* csr0 = (int*)alloc((size_t)E * 4);
    int* csr1 = (int*)alloc((size_t)E * 4);
    int* csr2 = (int*)alloc((size_t)E * 4);
    int* csr3 = (int*)alloc((size_t)E * 4);
    int* bsum = (int*)alloc(256 * 4);
    int* bh0  = (int*)alloc((size_t)NSL * NA * 4);
    int* bh2  = (int*)alloc((size_t)NSL * NC * 4);
    (void)ws_size; (void)in_sizes; (void)n_in; (void)out_size;

    // ---- CSR build: r0/r2 via contention-free counting sort
    hist02_kernel<<<2 * NSL, 256, 0, stream>>>(dst0, dst2, bh0, bh2);
    scan02_kernel<<<1, 512, 0, stream>>>(bh0, bh2, rp0, rp2, inv0, inv2);
    fill02_kernel<<<2 * NSL, 256, 0, stream>>>(src0, dst0, src2, dst2, bh0, bh2, csr0, csr2);

    // ---- CSR build: r1/r3 via atomics (100K dsts, avg degree 2.5 — cheap)
    hipMemsetAsync(deg13, 0, (size_t)2 * NF * 4, stream);
    deg_count_kernel<<<(2 * E + 255) / 256, 256, 0, stream>>>(dst1, dst3, deg1, deg3);
    scanA_kernel<<<196, 1024, 0, stream>>>(deg1, deg3, bsum);
    scanB_kernel<<<1, 256, 0, stream>>>(bsum);
    scanC_kernel<<<196, 1024, 0, stream>>>(deg1, deg3, bsum, rp1, rp3, cu1, cu3, inv1, inv3);
    csr_fill13_kernel<<<(2 * E + 255) / 256, 256, 0, stream>>>(
        src1, dst1, src3, dst3, cu1, cu3, csr1, csr3);

    // ---- encoders (single bf16 plane)
    encode_kernel<32, 8><<<NF / 8, 256, 0, stream>>>(xf, Wf, bf, hH, NF, 0);
    encode_kernel<16, 8><<<(NA + 7) / 8, 256, 0, stream>>>(xa, Wa, ba, hH, NA, NF);
    encode_kernel<8, 8><<<(NC + 7) / 8, 256, 0, stream>>>(xc, Wc, bc, hH, NC, NF + NA);

    // ---- layer 0: pure MFMA gemm -> G; then per-row-type finishers in place
    wsplit_kernel<<<D, D, 0, stream>>>(root0, WtH, WtL);
    wr_kernel<<<4 * DD / 256, 256, 0, stream>>>(basis0, comp0, wrbuf);
    y_kernel<<<NA + NC, 256, 0, stream>>>(hH, wrbuf, ybuf);
    gemm_mfma<<<dim3((NN + 127) / 128, 2), 256, 0, stream>>>(
        hH, WtH, WtL, bias0, gH, NN);
    hipMemsetAsync(aggbuf, 0, (size_t)(NA + NC) * D * 4, stream);
    agg_small_kernel<<<NA * 4 + NC * 64, 256, 0, stream>>>(
        hH, rp0, csr0, rp2, csr2, aggbuf);
    smallT_kernel<<<NA + NC, 256, 0, stream>>>(aggbuf, wrbuf, inv0, inv2, gH);
    msg_relu_kernel<<<(NF * 64 + 255) / 256, 256, 0, stream>>>(
        gH, ybuf, rp1, csr1, inv1, rp3, csr3, inv3);

    // ---- layer 1 (flights only): pure gemm -> G2 (aliases h); readout -> out
    wsplit_kernel<<<D, D, 0, stream>>>(root1, WtH, WtL);
    wr_kernel<<<4 * DD / 256, 256, 0, stream>>>(basis1, comp1, wrbuf);
    y_kernel<<<NA + NC, 256, 0, stream>>>(gH, wrbuf, ybuf);
    gemm_mfma<<<dim3((NF + 127) / 128, 2), 256, 0, stream>>>(
        gH, WtH, WtL, bias1, g2H, NF);
    msg_readout_kernel<<<(NF * 64 + 255) / 256, 256, 0, stream>>>(
        g2H, ybuf, rp1, csr1, inv1, rp3, csr3, inv3, Wout, bout, out);
}

// Round 14
// 440.783 us; speedup vs baseline: 1.2094x; 1.0168x over previous
//
#include <hip/hip_runtime.h>
#include <hip/hip_bf16.h>
#include <cstdint>
#include <cstddef>

constexpr int NF = 100000;
constexpr int NA = 400;
constexpr int NC = 30;
constexpr int NN = NF + NA + NC;     // 100430
constexpr int D  = 256;
constexpr int DD = D * D;            // 65536
constexpr int E  = 250000;
constexpr int NSL = 128;             // slices for r0/r2 counting sort

typedef __attribute__((ext_vector_type(8))) short bf16x8;
typedef __attribute__((ext_vector_type(4))) float f32x4;
typedef __attribute__((ext_vector_type(8))) ushort u16x8;

__device__ inline ushort f2bf(float f) {
    __hip_bfloat16 h = __float2bfloat16(f);
    return __builtin_bit_cast(ushort, h);
}
__device__ inline float bf2f(ushort u) {
    __hip_bfloat16 h = __builtin_bit_cast(__hip_bfloat16, u);
    return __bfloat162float(h);
}

// async global->LDS, 16B per lane: LDS dest = base + lane*16 (wave-linear)
__device__ inline void gload_lds16(const ushort* g, ushort* l) {
    __builtin_amdgcn_global_load_lds(
        (const __attribute__((address_space(1))) void*)g,
        (__attribute__((address_space(3))) void*)l, 16, 0, 0);
}

// ---------------- per-type encoders: h = relu(x @ W + b) -> bf16 ------------
template<int K, int ROWS>
__global__ __launch_bounds__(256) void encode_kernel(
    const float* __restrict__ x, const float* __restrict__ W,
    const float* __restrict__ b, ushort* __restrict__ hH,
    int rows, int row_off)
{
    int c = threadIdx.x;
    int base = blockIdx.x * ROWS;
    float wcol[K];
    #pragma unroll
    for (int k = 0; k < K; ++k) wcol[k] = W[k * D + c];
    float bias = b[c];
    for (int i = 0; i < ROWS; ++i) {
        int row = base + i;
        if (row >= rows) return;
        const float* xr = x + (size_t)row * K;
        float acc = bias;
        #pragma unroll
        for (int k = 0; k < K; ++k) acc += xr[k] * wcol[k];
        hH[(size_t)(row_off + row) * D + c] = f2bf(fmaxf(acc, 0.f));
    }
}

// ---------------- weight split+transpose: root[k][n] -> WtH/WtL[n][k] -------
__global__ __launch_bounds__(256) void wsplit_kernel(
    const float* __restrict__ root, ushort* __restrict__ WtH, ushort* __restrict__ WtL)
{
    int n = blockIdx.x, k = threadIdx.x;
    float w = root[(size_t)k * D + n];
    ushort hi = f2bf(w);
    WtH[(size_t)n * D + k] = hi;
    WtL[(size_t)n * D + k] = f2bf(w - bf2f(hi));
}

// ---------------- basis combine: Wr[r] = sum_b comp[r,b] * basis[b] ---------
__global__ __launch_bounds__(256) void wr_kernel(
    const float* __restrict__ basis, const float* __restrict__ comp,
    float* __restrict__ wr)
{
    int idx = blockIdx.x * 256 + threadIdx.x;   // < 4*DD
    int r = idx >> 16;
    int io = idx & (DD - 1);
    wr[idx] = comp[r * 3 + 0] * basis[io]
            + comp[r * 3 + 1] * basis[DD + io]
            + comp[r * 3 + 2] * basis[2 * DD + io];
}

// ---------------- r1/r3 degree count (low contention: 100K dsts) ----------
__global__ __launch_bounds__(256) void deg_count_kernel(
    const int* __restrict__ dst1, const int* __restrict__ dst3,
    int* __restrict__ deg1, int* __restrict__ deg3)
{
    int idx = blockIdx.x * 256 + threadIdx.x;
    if (idx >= 2 * E) return;
    if (idx < E) atomicAdd(&deg1[dst1[idx]], 1);
    else         atomicAdd(&deg3[dst3[idx - E]], 1);
}

// ---------------- r0/r2: per-slice LDS histograms (contention-free) --------
__global__ __launch_bounds__(256) void hist02_kernel(
    const int* __restrict__ dst0, const int* __restrict__ dst2,
    int* __restrict__ bh0, int* __restrict__ bh2)
{
    __shared__ int hist[NA];
    int b = blockIdx.x;                 // 0..2*NSL-1
    bool isR2 = (b >= NSL);
    int sl = isR2 ? b - NSL : b;
    const int* dst = isR2 ? dst2 : dst0;
    int nb = isR2 ? NC : NA;
    for (int i = threadIdx.x; i < nb; i += 256) hist[i] = 0;
    __syncthreads();
    int lo = (int)((long long)E * sl / NSL);
    int hi = (int)((long long)E * (sl + 1) / NSL);
    for (int e = lo + threadIdx.x; e < hi; e += 256)
        atomicAdd(&hist[dst[e]], 1);
    __syncthreads();
    int* bh = isR2 ? (bh2 + sl * NC) : (bh0 + sl * NA);
    for (int i = threadIdx.x; i < nb; i += 256) bh[i] = hist[i];
}

// -------- scan: per-bin over slices + cross-bin; emits rp/inv + abs offsets -
__global__ __launch_bounds__(512) void scan02_kernel(
    int* __restrict__ bh0, int* __restrict__ bh2,
    int* __restrict__ rp0, int* __restrict__ rp2,
    float* __restrict__ inv0, float* __restrict__ inv2)
{
    __shared__ int tot[512];
    __shared__ int exc[512];
    int t = threadIdx.x;
    int cnt = 0;
    if (t < NA) {
        int s = 0;
        for (int sl = 0; sl < NSL; ++sl) {
            int v = bh0[sl * NA + t]; bh0[sl * NA + t] = s; s += v;
        }
        cnt = s;
    } else if (t < NA + NC) {
        int bin = t - NA; int s = 0;
        for (int sl = 0; sl < NSL; ++sl) {
            int v = bh2[sl * NC + bin]; bh2[sl * NC + bin] = s; s += v;
        }
        cnt = s;
    }
    tot[t] = cnt;
    __syncthreads();
    for (int ofs = 1; ofs < 512; ofs <<= 1) {
        int v = (t >= ofs) ? tot[t - ofs] : 0;
        __syncthreads();
        tot[t] += v;
        __syncthreads();
    }
    int ex = tot[t] - cnt;              // exclusive over combined [r0 | r2]
    if (t < NA) {
        exc[t] = ex;
        rp0[t] = ex;
        inv0[t] = 1.0f / (float)(cnt > 1 ? cnt : 1);
        if (t == 0) { rp0[NA] = E; rp2[NC] = E; }
    } else if (t < NA + NC) {
        exc[t] = ex - E;                // r2 csr buffer is its own array
        rp2[t - NA] = ex - E;
        inv2[t - NA] = 1.0f / (float)(cnt > 1 ? cnt : 1);
    } else exc[t] = 0;
    __syncthreads();
    for (int idx = t; idx < NSL * NA; idx += 512) {
        int sl = idx / NA; int bin = idx - sl * NA;
        bh0[idx] += exc[bin];
    }
    for (int idx = t; idx < NSL * NC; idx += 512) {
        int sl = idx / NC; int bin = idx - sl * NC;
        bh2[idx] += exc[NA + bin];
    }
}

// ---------------- r0/r2 CSR fill with LDS cursors --------------------------
__global__ __launch_bounds__(256) void fill02_kernel(
    const int* __restrict__ src0, const int* __restrict__ dst0,
    const int* __restrict__ src2, const int* __restrict__ dst2,
    const int* __restrict__ bh0, const int* __restrict__ bh2,
    int* __restrict__ csr0, int* __restrict__ csr2)
{
    __shared__ int cur[NA];
    int b = blockIdx.x;
    bool isR2 = (b >= NSL);
    int sl = isR2 ? b - NSL : b;
    const int* src = isR2 ? src2 : src0;
    const int* dst = isR2 ? dst2 : dst0;
    const int* bh  = isR2 ? (bh2 + sl * NC) : (bh0 + sl * NA);
    int* csr       = isR2 ? csr2 : csr0;
    int nb = isR2 ? NC : NA;
    for (int i = threadIdx.x; i < nb; i += 256) cur[i] = bh[i];
    __syncthreads();
    int lo = (int)((long long)E * sl / NSL);
    int hi = (int)((long long)E * (sl + 1) / NSL);
    for (int e = lo + threadIdx.x; e < hi; e += 256) {
        int pos = atomicAdd(&cur[dst[e]], 1);
        csr[pos] = src[e];
    }
}

// ---------------- r1/r3 scan chain -----------------------------------------
__global__ __launch_bounds__(1024) void scanA_kernel(
    const int* __restrict__ deg1, const int* __restrict__ deg3, int* __restrict__ bsum)
{
    __shared__ int s[1024];
    int b = blockIdx.x;                    // 0..195
    bool isR3 = (b >= 98);
    const int* deg = isR3 ? deg3 : deg1;
    int chunk = isR3 ? b - 98 : b;
    int i = chunk * 1024 + threadIdx.x;
    int v = (i < NF) ? deg[i] : 0;
    s[threadIdx.x] = v;
    __syncthreads();
    for (int ofs = 512; ofs > 0; ofs >>= 1) {
        if ((int)threadIdx.x < ofs) s[threadIdx.x] += s[threadIdx.x + ofs];
        __syncthreads();
    }
    if (threadIdx.x == 0) bsum[(isR3 ? 128 : 0) + chunk] = s[0];
}

__global__ __launch_bounds__(256) void scanB_kernel(int* __restrict__ bsum)
{
    __shared__ int s[256];
    int t = threadIdx.x;
    int v = ((t & 127) < 98) ? bsum[t] : 0;
    s[t] = v;
    __syncthreads();
    for (int ofs = 1; ofs < 128; ofs <<= 1) {
        int a = ((t & 127) >= ofs) ? s[t - ofs] : 0;
        __syncthreads();
        s[t] += a;
        __syncthreads();
    }
    bsum[t] = s[t] - v;   // exclusive (segmented per 128-half)
}

__global__ __launch_bounds__(1024) void scanC_kernel(
    const int* __restrict__ deg1, const int* __restrict__ deg3,
    const int* __restrict__ bsum,
    int* __restrict__ rp1, int* __restrict__ rp3,
    int* __restrict__ cu1, int* __restrict__ cu3,
    float* __restrict__ inv1, float* __restrict__ inv3)
{
    __shared__ int s[1024];
    int b = blockIdx.x;                    // 0..195
    const int* deg; int* rp; int* cu; float* inv; int chunk; int prefix;
    if (b < 98) { deg = deg1; rp = rp1; cu = cu1; inv = inv1; chunk = b;      prefix = bsum[chunk]; }
    else        { deg = deg3; rp = rp3; cu = cu3; inv = inv3; chunk = b - 98; prefix = bsum[128 + chunk]; }
    int tid = threadIdx.x;
    int i = chunk * 1024 + tid;
    int v = (i < NF) ? deg[i] : 0;
    s[tid] = v;
    __syncthreads();
    for (int ofs = 1; ofs < 1024; ofs <<= 1) {
        int a = (tid >= ofs) ? s[tid - ofs] : 0;
        __syncthreads();
        s[tid] += a;
        __syncthreads();
    }
    int ex = prefix + s[tid] - v;
    if (i < NF) {
        rp[i] = ex;
        cu[i] = ex;
        inv[i] = 1.0f / (float)(v > 1 ? v : 1);
    }
    if (i == 0) rp[NF] = E;
}

__global__ __launch_bounds__(256) void csr_fill13_kernel(
    const int* __restrict__ src1, const int* __restrict__ dst1,
    const int* __restrict__ src3, const int* __restrict__ dst3,
    int* __restrict__ cu1, int* __restrict__ cu3,
    int* __restrict__ csr1, int* __restrict__ csr3)
{
    int idx = blockIdx.x * 256 + threadIdx.x;
    if (idx >= 2 * E) return;
    if (idx < E) {
        int pos = atomicAdd(&cu1[dst1[idx]], 1);
        csr1[pos] = src1[idx];
    } else {
        int e = idx - E;
        int pos = atomicAdd(&cu3[dst3[e]], 1);
        csr3[pos] = src3[e];
    }
}

// ------- y = h[src-type rows] @ Wr[rel]  (Wr precomputed) -------------------
__global__ __launch_bounds__(256) void y_kernel(
    const ushort* __restrict__ hH, const float* __restrict__ wr,
    float* __restrict__ y)
{
    int row = blockIdx.x;            // 0..429  (airports then carriers)
    int c = threadIdx.x;
    const ushort* sH = hH + (size_t)(NF + row) * D;
    const float* W = wr + (size_t)((row < NA) ? 1 : 3) * DD;
    float acc = 0.f;
    #pragma unroll 8
    for (int k = 0; k < D; ++k) acc += bf2f(sH[k]) * W[k * D + c];
    y[(size_t)row * D + c] = acc;
}

// ---- bf16 MFMA GEMM: G = A @ root^T + bias (A single-plane, W split) ------
// 8 waves (512 thr), each owning a 64x32 sub-tile: acc = 8 f32x4 = 32 AGPR,
// total regs < 128 -> 16 waves/CU residency (2 blocks). Fragment-major
// global_load_lds staging: 3 planes x 8 groups of 16 rows, 3 units/wave.
__global__ __launch_bounds__(512) void gemm_mfma(
    const ushort* __restrict__ A,
    const ushort* __restrict__ WtH, const ushort* __restrict__ WtL,
    const float* __restrict__ bias,
    ushort* __restrict__ G, int nrows)
{
    constexpr int BM = 128, BK = 32;
    constexpr int PLANE = BM * BK;          // 4096 ushorts = 8 KB
    constexpr int LDW = 36;                 // fp32 epilogue scratch stride
    __shared__ __align__(16) ushort lds[12288];   // 24576 B
    const int t = threadIdx.x;
    const int row0 = blockIdx.x * BM;
    const int col0 = blockIdx.y * BM;
    const int w = t >> 6, lane = t & 63;    // 8 waves
    const int wm = w >> 2, wn = w & 3;      // 2x4 wave grid, 64x32 per wave
    const int lr = lane & 15;
    const int lk = lane >> 4;
    f32x4 acc[4][2] = {};

    // staging: 24 (plane,group) units, wave w handles 3 consecutive
    const ushort* sp[3];
    ushort* dp[3];
    #pragma unroll
    for (int i = 0; i < 3; ++i) {
        int idx = w * 3 + i;
        int plane = idx >> 3, g = idx & 7;
        const ushort* base = (plane == 0) ? A : (plane == 1) ? WtH : WtL;
        int r = ((plane == 0) ? row0 : col0) + g * 16 + lr;
        if (plane == 0 && r >= nrows) r = nrows - 1;
        sp[i] = base + (size_t)r * D + lk * 8;
        dp[i] = lds + plane * PLANE + g * 512;
    }

    for (int k0 = 0; k0 < D; k0 += BK) {
        #pragma unroll
        for (int i = 0; i < 3; ++i)
            gload_lds16(sp[i] + k0, dp[i]);
        __syncthreads();                   // drains vmcnt -> tiles visible
        const ushort* As  = lds;
        const ushort* WsH = lds + PLANE;
        const ushort* WsL = lds + 2 * PLANE;
        bf16x8 bh[2], bl[2];
        #pragma unroll
        for (int ni = 0; ni < 2; ++ni) {
            int off = (wn * 2 + ni) * 512 + lane * 8;
            bh[ni] = *(const bf16x8*)(&WsH[off]);
            bl[ni] = *(const bf16x8*)(&WsL[off]);
        }
        #pragma unroll
        for (int mi = 0; mi < 4; ++mi) {
            int off = (wm * 4 + mi) * 512 + lane * 8;
            bf16x8 ah = *(const bf16x8*)(&As[off]);
            #pragma unroll
            for (int ni = 0; ni < 2; ++ni) {
                acc[mi][ni] = __builtin_amdgcn_mfma_f32_16x16x32_bf16(ah, bh[ni], acc[mi][ni], 0, 0, 0);
                acc[mi][ni] = __builtin_amdgcn_mfma_f32_16x16x32_bf16(ah, bl[ni], acc[mi][ni], 0, 0, 0);
            }
        }
        __syncthreads();                   // all reads done before overwrite
    }
    // ---- epilogue: per-mi 16x32 pass through LDS, coalesced 16B stores -----
    float* S = (float*)lds + (size_t)w * 16 * LDW;   // per-wave 16x36 fp32
    const int rrow = lane >> 2;            // 0..15 read-back row
    const int grp  = lane & 3;             // col octet (8 bf16)
    #pragma unroll
    for (int mi = 0; mi < 4; ++mi) {
        __syncthreads();
        #pragma unroll
        for (int ni = 0; ni < 2; ++ni)
            #pragma unroll
            for (int reg = 0; reg < 4; ++reg)
                S[(lk * 4 + reg) * LDW + ni * 16 + lr] = acc[mi][ni][reg];
        __syncthreads();
        int gr = row0 + wm * 64 + mi * 16 + rrow;
        int gc = col0 + wn * 32 + grp * 8;
        if (gr >= nrows) continue;
        float4 f0 = *(const float4*)(&S[rrow * LDW + grp * 8]);
        float4 f1 = *(const float4*)(&S[rrow * LDW + grp * 8 + 4]);
        float4 b0 = *(const float4*)(bias + gc);
        float4 b1 = *(const float4*)(bias + gc + 4);
        float v[8] = {f0.x + b0.x, f0.y + b0.y, f0.z + b0.z, f0.w + b0.w,
                      f1.x + b1.x, f1.y + b1.y, f1.z + b1.z, f1.w + b1.w};
        u16x8 hh;
        #pragma unroll
        for (int j = 0; j < 8; ++j) hh[j] = f2bf(v[j]);
        *(u16x8*)(G + (size_t)gr * D + gc) = hh;
    }
}

// ---- layer-0 flight rows: G = relu(G + inv1*Σy1 + inv3*Σy3) in place ------
__global__ __launch_bounds__(256) void msg_relu_kernel(
    ushort* __restrict__ G,
    const float* __restrict__ y,
    const int* __restrict__ rp1, const int* __restrict__ csr1, const float* __restrict__ inv1,
    const int* __restrict__ rp3, const int* __restrict__ csr3, const float* __restrict__ inv3)
{
    int row = (blockIdx.x * 256 + threadIdx.x) >> 6;
    if (row >= NF) return;
    int lane = threadIdx.x & 63;
    int c = lane * 4;
    size_t o = (size_t)row * D + c;
    ushort4 gh = *(const ushort4*)(G + o);
    float v[4] = {bf2f(gh.x), bf2f(gh.y), bf2f(gh.z), bf2f(gh.w)};
    float m[4] = {0, 0, 0, 0};
    int e0 = rp1[row], e1 = rp1[row + 1];
    for (int e = e0; e < e1; ++e) {
        float4 u = *(const float4*)(y + (size_t)csr1[e] * D + c);
        m[0] += u.x; m[1] += u.y; m[2] += u.z; m[3] += u.w;
    }
    float s1 = inv1[row];
    #pragma unroll
    for (int j = 0; j < 4; ++j) v[j] += s1 * m[j];
    m[0] = m[1] = m[2] = m[3] = 0.f;
    e0 = rp3[row]; e1 = rp3[row + 1];
    for (int e = e0; e < e1; ++e) {
        float4 u = *(const float4*)(y + (size_t)(NA + csr3[e]) * D + c);
        m[0] += u.x; m[1] += u.y; m[2] += u.z; m[3] += u.w;
    }
    float s3 = inv3[row];
    ushort4 oh;
    oh.x = f2bf(fmaxf(v[0] + s3 * m[0], 0.f));
    oh.y = f2bf(fmaxf(v[1] + s3 * m[1], 0.f));
    oh.z = f2bf(fmaxf(v[2] + s3 * m[2], 0.f));
    oh.w = f2bf(fmaxf(v[3] + s3 * m[3], 0.f));
    *(ushort4*)(G + o) = oh;
}

// ---- layer-1: out[f] = relu(G2+msgs) . W_out + b_out (fused readout) -------
__global__ __launch_bounds__(256) void msg_readout_kernel(
    const ushort* __restrict__ G,
    const float* __restrict__ y,
    const int* __restrict__ rp1, const int* __restrict__ csr1, const float* __restrict__ inv1,
    const int* __restrict__ rp3, const int* __restrict__ csr3, const float* __restrict__ inv3,
    const float* __restrict__ wout, const float* __restrict__ bout,
    float* __restrict__ out)
{
    int row = (blockIdx.x * 256 + threadIdx.x) >> 6;
    if (row >= NF) return;
    int lane = threadIdx.x & 63;
    int c = lane * 4;
    size_t o = (size_t)row * D + c;
    ushort4 gh = *(const ushort4*)(G + o);
    float v[4] = {bf2f(gh.x), bf2f(gh.y), bf2f(gh.z), bf2f(gh.w)};
    float m[4] = {0, 0, 0, 0};
    int e0 = rp1[row], e1 = rp1[row + 1];
    for (int e = e0; e < e1; ++e) {
        float4 u = *(const float4*)(y + (size_t)csr1[e] * D + c);
        m[0] += u.x; m[1] += u.y; m[2] += u.z; m[3] += u.w;
    }
    float s1 = inv1[row];
    #pragma unroll
    for (int j = 0; j < 4; ++j) v[j] += s1 * m[j];
    m[0] = m[1] = m[2] = m[3] = 0.f;
    e0 = rp3[row]; e1 = rp3[row + 1];
    for (int e = e0; e < e1; ++e) {
        float4 u = *(const float4*)(y + (size_t)(NA + csr3[e]) * D + c);
        m[0] += u.x; m[1] += u.y; m[2] += u.z; m[3] += u.w;
    }
    float s3 = inv3[row];
    float4 wv = *(const float4*)(wout + c);
    float pr = fmaxf(v[0] + s3 * m[0], 0.f) * wv.x
             + fmaxf(v[1] + s3 * m[1], 0.f) * wv.y
             + fmaxf(v[2] + s3 * m[2], 0.f) * wv.z
             + fmaxf(v[3] + s3 * m[3], 0.f) * wv.w;
    pr += __shfl_xor(pr, 1);
    pr += __shfl_xor(pr, 2);
    pr += __shfl_xor(pr, 4);
    pr += __shfl_xor(pr, 8);
    pr += __shfl_xor(pr, 16);
    pr += __shfl_xor(pr, 32);
    if (lane == 0) out[row] = pr + bout[0];
}

// ---- r0/r2: agg[dst] += hH[src] — 2 edges per wave, 16B/lane loads ---------
__global__ __launch_bounds__(256) void agg_small_kernel(
    const ushort* __restrict__ hH,
    const int* __restrict__ rp0, const int* __restrict__ csr0,
    const int* __restrict__ rp2, const int* __restrict__ csr2,
    float* __restrict__ agg)
{
    __shared__ float red[4][256];
    int b = blockIdx.x;
    const int* rp; const int* csr; int dstn, chunk, nch; float* arow;
    if (b < NA * 4) { dstn = b >> 2; chunk = b & 3; nch = 4;  rp = rp0; csr = csr0; arow = agg + (size_t)dstn * D; }
    else { int bb = b - NA * 4; dstn = bb >> 6; chunk = bb & 63; nch = 64; rp = rp2; csr = csr2; arow = agg + (size_t)(NA + dstn) * D; }
    int s = rp[dstn], e = rp[dstn + 1];
    int cnt = e - s;
    int lo = s + (int)((long long)cnt * chunk / nch);
    int hi = s + (int)((long long)cnt * (chunk + 1) / nch);
    int w = threadIdx.x >> 6, lane = threadIdx.x & 63;
    int span = hi - lo;
    int wlo = lo + (int)((long long)span * w / 4);
    int whi = lo + (int)((long long)span * (w + 1) / 4);
    int half = lane >> 5;                  // 0: edge p, 1: edge p+1
    int ch8 = (lane & 31) * 8;
    float acc[8] = {};
    int p = wlo;
    for (; p + 1 < whi; p += 2) {
        int r = csr[p + half];
        u16x8 v = *(const u16x8*)(hH + (size_t)r * D + ch8);
        #pragma unroll
        for (int j = 0; j < 8; ++j) acc[j] += bf2f(v[j]);
    }
    if (p < whi && half == 0) {
        int r = csr[p];
        u16x8 v = *(const u16x8*)(hH + (size_t)r * D + ch8);
        #pragma unroll
        for (int j = 0; j < 8; ++j) acc[j] += bf2f(v[j]);
    }
    #pragma unroll
    for (int j = 0; j < 8; ++j) acc[j] += __shfl_xor(acc[j], 32);
    if (lane < 32) {
        #pragma unroll
        for (int j = 0; j < 8; ++j) red[w][ch8 + j] = acc[j];
    }
    __syncthreads();
    int c = threadIdx.x;
    float total = red[0][c] + red[1][c] + red[2][c] + red[3][c];
    atomicAdd(arow + c, total);
}

// -- r0/r2 transform: G = relu(G + inv_deg*(agg @ Wr[rel])) in place ---------
__global__ __launch_bounds__(256) void smallT_kernel(
    const float* __restrict__ agg, const float* __restrict__ wr,
    const float* __restrict__ inv0, const float* __restrict__ inv2,
    ushort* __restrict__ G)
{
    int row = blockIdx.x;            // 0..429
    int c = threadIdx.x;
    const float* a = agg + (size_t)row * D;
    const float* W = wr + (size_t)((row < NA) ? 0 : 2) * DD;
    float scale = (row < NA) ? inv0[row] : inv2[row - NA];
    float acc = 0.f;
    #pragma unroll 8
    for (int k = 0; k < D; ++k) acc += a[k] * W[k * D + c];
    size_t o = (size_t)(NF + row) * D + c;
    G[o] = f2bf(fmaxf(bf2f(G[o]) + scale * acc, 0.f));
}

extern "C" void kernel_launch(void* const* d_in, const int* in_sizes, int n_in,
                              void* d_out, int out_size, void* d_ws, size_t ws_size,
                              hipStream_t stream)
{
    const float* xf = (const float*)d_in[0];
    const float* xa = (const float*)d_in[1];
    const float* xc = (const float*)d_in[2];
    const float* Wf = (const float*)d_in[3];
    const float* bf = (const float*)d_in[4];
    const float* Wa = (const float*)d_in[5];
    const float* ba = (const float*)d_in[6];
    const float* Wc = (const float*)d_in[7];
    const float* bc = (const float*)d_in[8];
    const float* basis0 = (const float*)d_in[9];
    const float* comp0  = (const float*)d_in[10];
    const float* root0  = (const float*)d_in[11];
    const float* bias0  = (const float*)d_in[12];
    const float* basis1 = (const float*)d_in[13];
    const float* comp1  = (const float*)d_in[14];
    const float* root1  = (const float*)d_in[15];
    const float* bias1  = (const float*)d_in[16];
    const float* Wout = (const float*)d_in[17];
    const float* bout = (const float*)d_in[18];
    const int* src0 = (const int*)d_in[19];
    const int* dst0 = (const int*)d_in[20];
    const int* src1 = (const int*)d_in[21];
    const int* dst1 = (const int*)d_in[22];
    const int* src2 = (const int*)d_in[23];
    const int* dst2 = (const int*)d_in[24];
    const int* src3 = (const int*)d_in[25];
    const int* dst3 = (const int*)d_in[26];
    float* out = (float*)d_out;

    char* ws = (char*)d_ws;
    size_t off = 0;
    auto alloc = [&](size_t bytes) -> char* {
        char* p = ws + off;
        off = (off + bytes + 255) & ~(size_t)255;
        return p;
    };
    ushort* hH  = (ushort*)alloc((size_t)NN * D * 2);
    ushort* gH  = (ushort*)alloc((size_t)NN * D * 2);
    // layer-1 GEMM output reuses hH (dead after layer-0 consumers)
    ushort* g2H = hH;
    ushort* WtH = (ushort*)alloc((size_t)DD * 2);
    ushort* WtL = (ushort*)alloc((size_t)DD * 2);
    float* wrbuf  = (float*)alloc((size_t)4 * DD * 4);
    float* ybuf   = (float*)alloc((size_t)(NA + NC) * D * 4);
    float* aggbuf = (float*)alloc((size_t)(NA + NC) * D * 4);
    int*   deg13  = (int*)  alloc((size_t)2 * NF * 4);
    int* deg1 = deg13; int* deg3 = deg13 + NF;
    float* inv1 = (float*)alloc((size_t)NF * 4);
    float* inv3 = (float*)alloc((size_t)NF * 4);
    float* inv0 = (float*)alloc((size_t)NA * 4);
    float* inv2 = (float*)alloc((size_t)NC * 4);
    int* rp0 = (int*)alloc((NA + 1) * 4);
    int* rp1 = (int*)alloc((size_t)(NF + 1) * 4);
    int* rp2 = (int*)alloc((NC + 1) * 4);
    int* rp3 = (int*)alloc((size_t)(NF + 1) * 4);
    int* cu1 = (int*)alloc((size_t)(NF + 1) * 4);
    int* cu3 = (int*)alloc((size_t)(NF + 1) * 4);
    int* csr0 = (int*)alloc((size_t)E * 4);
    int* csr1 = (int*)alloc((size_t)E * 4);
    int* csr2 = (int*)alloc((size_t)E * 4);
    int* csr3 = (int*)alloc((size_t)E * 4);
    int* bsum = (int*)alloc(256 * 4);
    int* bh0  = (int*)alloc((size_t)NSL * NA * 4);
    int* bh2  = (int*)alloc((size_t)NSL * NC * 4);
    (void)ws_size; (void)in_sizes; (void)n_in; (void)out_size;

    // ---- CSR build: r0/r2 via contention-free counting sort
    hist02_kernel<<<2 * NSL, 256, 0, stream>>>(dst0, dst2, bh0, bh2);
    scan02_kernel<<<1, 512, 0, stream>>>(bh0, bh2, rp0, rp2, inv0, inv2);
    fill02_kernel<<<2 * NSL, 256, 0, stream>>>(src0, dst0, src2, dst2, bh0, bh2, csr0, csr2);

    // ---- CSR build: r1/r3 via atomics (100K dsts, avg degree 2.5 — cheap)
    hipMemsetAsync(deg13, 0, (size_t)2 * NF * 4, stream);
    deg_count_kernel<<<(2 * E + 255) / 256, 256, 0, stream>>>(dst1, dst3, deg1, deg3);
    scanA_kernel<<<196, 1024, 0, stream>>>(deg1, deg3, bsum);
    scanB_kernel<<<1, 256, 0, stream>>>(bsum);
    scanC_kernel<<<196, 1024, 0, stream>>>(deg1, deg3, bsum, rp1, rp3, cu1, cu3, inv1, inv3);
    csr_fill13_kernel<<<(2 * E + 255) / 256, 256, 0, stream>>>(
        src1, dst1, src3, dst3, cu1, cu3, csr1, csr3);

    // ---- encoders (single bf16 plane)
    encode_kernel<32, 8><<<NF / 8, 256, 0, stream>>>(xf, Wf, bf, hH, NF, 0);
    encode_kernel<16, 8><<<(NA + 7) / 8, 256, 0, stream>>>(xa, Wa, ba, hH, NA, NF);
    encode_kernel<8, 8><<<(NC + 7) / 8, 256, 0, stream>>>(xc, Wc, bc, hH, NC, NF + NA);

    // ---- layer 0: pure MFMA gemm -> G; then per-row-type finishers in place
    wsplit_kernel<<<D, D, 0, stream>>>(root0, WtH, WtL);
    wr_kernel<<<4 * DD / 256, 256, 0, stream>>>(basis0, comp0, wrbuf);
    y_kernel<<<NA + NC, 256, 0, stream>>>(hH, wrbuf, ybuf);
    gemm_mfma<<<dim3((NN + 127) / 128, 2), 512, 0, stream>>>(
        hH, WtH, WtL, bias0, gH, NN);
    hipMemsetAsync(aggbuf, 0, (size_t)(NA + NC) * D * 4, stream);
    agg_small_kernel<<<NA * 4 + NC * 64, 256, 0, stream>>>(
        hH, rp0, csr0, rp2, csr2, aggbuf);
    smallT_kernel<<<NA + NC, 256, 0, stream>>>(aggbuf, wrbuf, inv0, inv2, gH);
    msg_relu_kernel<<<(NF * 64 + 255) / 256, 256, 0, stream>>>(
        gH, ybuf, rp1, csr1, inv1, rp3, csr3, inv3);

    // ---- layer 1 (flights only): pure gemm -> G2 (aliases h); readout -> out
    wsplit_kernel<<<D, D, 0, stream>>>(root1, WtH, WtL);
    wr_kernel<<<4 * DD / 256, 256, 0, stream>>>(basis1, comp1, wrbuf);
    y_kernel<<<NA + NC, 256, 0, stream>>>(gH, wrbuf, ybuf);
    gemm_mfma<<<dim3((NF + 127) / 128, 2), 512, 0, stream>>>(
        gH, WtH, WtL, bias1, g2H, NF);
    msg_readout_kernel<<<(NF * 64 + 255) / 256, 256, 0, stream>>>(
        g2H, ybuf, rp1, csr1, inv1, rp3, csr3, inv3, Wout, bout, out);
}

// Round 15
// 406.588 us; speedup vs baseline: 1.3111x; 1.0841x over previous
//
#include <hip/hip_runtime.h>
#include <hip/hip_bf16.h>
#include <cstdint>
#include <cstddef>

constexpr int NF = 100000;
constexpr int NA = 400;
constexpr int NC = 30;
constexpr int NN = NF + NA + NC;     // 100430
constexpr int D  = 256;
constexpr int DD = D * D;            // 65536
constexpr int E  = 250000;
constexpr int NSL = 128;             // slices for r0/r2 counting sort

typedef __attribute__((ext_vector_type(8))) short bf16x8;
typedef __attribute__((ext_vector_type(4))) float f32x4;
typedef __attribute__((ext_vector_type(8))) ushort u16x8;

__device__ inline ushort f2bf(float f) {
    __hip_bfloat16 h = __float2bfloat16(f);
    return __builtin_bit_cast(ushort, h);
}
__device__ inline float bf2f(ushort u) {
    __hip_bfloat16 h = __builtin_bit_cast(__hip_bfloat16, u);
    return __bfloat162float(h);
}

// async global->LDS, 16B per lane: LDS dest = base + lane*16 (wave-linear)
__device__ inline void gload_lds16(const ushort* g, ushort* l) {
    __builtin_amdgcn_global_load_lds(
        (const __attribute__((address_space(1))) void*)g,
        (__attribute__((address_space(3))) void*)l, 16, 0, 0);
}

// ---------------- per-type encoders: h = relu(x @ W + b) -> bf16 ------------
template<int K, int ROWS>
__global__ __launch_bounds__(256) void encode_kernel(
    const float* __restrict__ x, const float* __restrict__ W,
    const float* __restrict__ b, ushort* __restrict__ hH,
    int rows, int row_off)
{
    int c = threadIdx.x;
    int base = blockIdx.x * ROWS;
    float wcol[K];
    #pragma unroll
    for (int k = 0; k < K; ++k) wcol[k] = W[k * D + c];
    float bias = b[c];
    for (int i = 0; i < ROWS; ++i) {
        int row = base + i;
        if (row >= rows) return;
        const float* xr = x + (size_t)row * K;
        float acc = bias;
        #pragma unroll
        for (int k = 0; k < K; ++k) acc += xr[k] * wcol[k];
        hH[(size_t)(row_off + row) * D + c] = f2bf(fmaxf(acc, 0.f));
    }
}

// ---------------- weight split+transpose: root[k][n] -> WtH/WtL[n][k] -------
__global__ __launch_bounds__(256) void wsplit_kernel(
    const float* __restrict__ root, ushort* __restrict__ WtH, ushort* __restrict__ WtL)
{
    int n = blockIdx.x, k = threadIdx.x;
    float w = root[(size_t)k * D + n];
    ushort hi = f2bf(w);
    WtH[(size_t)n * D + k] = hi;
    WtL[(size_t)n * D + k] = f2bf(w - bf2f(hi));
}

// ---------------- basis combine: Wr[r] = sum_b comp[r,b] * basis[b] ---------
__global__ __launch_bounds__(256) void wr_kernel(
    const float* __restrict__ basis, const float* __restrict__ comp,
    float* __restrict__ wr)
{
    int idx = blockIdx.x * 256 + threadIdx.x;   // < 4*DD
    int r = idx >> 16;
    int io = idx & (DD - 1);
    wr[idx] = comp[r * 3 + 0] * basis[io]
            + comp[r * 3 + 1] * basis[DD + io]
            + comp[r * 3 + 2] * basis[2 * DD + io];
}

// ---------------- r1/r3 degree count (low contention: 100K dsts) ----------
__global__ __launch_bounds__(256) void deg_count_kernel(
    const int* __restrict__ dst1, const int* __restrict__ dst3,
    int* __restrict__ deg1, int* __restrict__ deg3)
{
    int idx = blockIdx.x * 256 + threadIdx.x;
    if (idx >= 2 * E) return;
    if (idx < E) atomicAdd(&deg1[dst1[idx]], 1);
    else         atomicAdd(&deg3[dst3[idx - E]], 1);
}

// ---------------- r0/r2: per-slice LDS histograms (contention-free) --------
__global__ __launch_bounds__(256) void hist02_kernel(
    const int* __restrict__ dst0, const int* __restrict__ dst2,
    int* __restrict__ bh0, int* __restrict__ bh2)
{
    __shared__ int hist[NA];
    int b = blockIdx.x;                 // 0..2*NSL-1
    bool isR2 = (b >= NSL);
    int sl = isR2 ? b - NSL : b;
    const int* dst = isR2 ? dst2 : dst0;
    int nb = isR2 ? NC : NA;
    for (int i = threadIdx.x; i < nb; i += 256) hist[i] = 0;
    __syncthreads();
    int lo = (int)((long long)E * sl / NSL);
    int hi = (int)((long long)E * (sl + 1) / NSL);
    for (int e = lo + threadIdx.x; e < hi; e += 256)
        atomicAdd(&hist[dst[e]], 1);
    __syncthreads();
    int* bh = isR2 ? (bh2 + sl * NC) : (bh0 + sl * NA);
    for (int i = threadIdx.x; i < nb; i += 256) bh[i] = hist[i];
}

// -------- scan: per-bin over slices + cross-bin; emits rp/inv + abs offsets -
__global__ __launch_bounds__(512) void scan02_kernel(
    int* __restrict__ bh0, int* __restrict__ bh2,
    int* __restrict__ rp0, int* __restrict__ rp2,
    float* __restrict__ inv0, float* __restrict__ inv2)
{
    __shared__ int tot[512];
    __shared__ int exc[512];
    int t = threadIdx.x;
    int cnt = 0;
    if (t < NA) {
        int s = 0;
        for (int sl = 0; sl < NSL; ++sl) {
            int v = bh0[sl * NA + t]; bh0[sl * NA + t] = s; s += v;
        }
        cnt = s;
    } else if (t < NA + NC) {
        int bin = t - NA; int s = 0;
        for (int sl = 0; sl < NSL; ++sl) {
            int v = bh2[sl * NC + bin]; bh2[sl * NC + bin] = s; s += v;
        }
        cnt = s;
    }
    tot[t] = cnt;
    __syncthreads();
    for (int ofs = 1; ofs < 512; ofs <<= 1) {
        int v = (t >= ofs) ? tot[t - ofs] : 0;
        __syncthreads();
        tot[t] += v;
        __syncthreads();
    }
    int ex = tot[t] - cnt;              // exclusive over combined [r0 | r2]
    if (t < NA) {
        exc[t] = ex;
        rp0[t] = ex;
        inv0[t] = 1.0f / (float)(cnt > 1 ? cnt : 1);
        if (t == 0) { rp0[NA] = E; rp2[NC] = E; }
    } else if (t < NA + NC) {
        exc[t] = ex - E;                // r2 csr buffer is its own array
        rp2[t - NA] = ex - E;
        inv2[t - NA] = 1.0f / (float)(cnt > 1 ? cnt : 1);
    } else exc[t] = 0;
    __syncthreads();
    for (int idx = t; idx < NSL * NA; idx += 512) {
        int sl = idx / NA; int bin = idx - sl * NA;
        bh0[idx] += exc[bin];
    }
    for (int idx = t; idx < NSL * NC; idx += 512) {
        int sl = idx / NC; int bin = idx - sl * NC;
        bh2[idx] += exc[NA + bin];
    }
}

// ---------------- r0/r2 CSR fill with LDS cursors --------------------------
__global__ __launch_bounds__(256) void fill02_kernel(
    const int* __restrict__ src0, const int* __restrict__ dst0,
    const int* __restrict__ src2, const int* __restrict__ dst2,
    const int* __restrict__ bh0, const int* __restrict__ bh2,
    int* __restrict__ csr0, int* __restrict__ csr2)
{
    __shared__ int cur[NA];
    int b = blockIdx.x;
    bool isR2 = (b >= NSL);
    int sl = isR2 ? b - NSL : b;
    const int* src = isR2 ? src2 : src0;
    const int* dst = isR2 ? dst2 : dst0;
    const int* bh  = isR2 ? (bh2 + sl * NC) : (bh0 + sl * NA);
    int* csr       = isR2 ? csr2 : csr0;
    int nb = isR2 ? NC : NA;
    for (int i = threadIdx.x; i < nb; i += 256) cur[i] = bh[i];
    __syncthreads();
    int lo = (int)((long long)E * sl / NSL);
    int hi = (int)((long long)E * (sl + 1) / NSL);
    for (int e = lo + threadIdx.x; e < hi; e += 256) {
        int pos = atomicAdd(&cur[dst[e]], 1);
        csr[pos] = src[e];
    }
}

// ---------------- r1/r3 scan chain -----------------------------------------
__global__ __launch_bounds__(1024) void scanA_kernel(
    const int* __restrict__ deg1, const int* __restrict__ deg3, int* __restrict__ bsum)
{
    __shared__ int s[1024];
    int b = blockIdx.x;                    // 0..195
    bool isR3 = (b >= 98);
    const int* deg = isR3 ? deg3 : deg1;
    int chunk = isR3 ? b - 98 : b;
    int i = chunk * 1024 + threadIdx.x;
    int v = (i < NF) ? deg[i] : 0;
    s[threadIdx.x] = v;
    __syncthreads();
    for (int ofs = 512; ofs > 0; ofs >>= 1) {
        if ((int)threadIdx.x < ofs) s[threadIdx.x] += s[threadIdx.x + ofs];
        __syncthreads();
    }
    if (threadIdx.x == 0) bsum[(isR3 ? 128 : 0) + chunk] = s[0];
}

__global__ __launch_bounds__(256) void scanB_kernel(int* __restrict__ bsum)
{
    __shared__ int s[256];
    int t = threadIdx.x;
    int v = ((t & 127) < 98) ? bsum[t] : 0;
    s[t] = v;
    __syncthreads();
    for (int ofs = 1; ofs < 128; ofs <<= 1) {
        int a = ((t & 127) >= ofs) ? s[t - ofs] : 0;
        __syncthreads();
        s[t] += a;
        __syncthreads();
    }
    bsum[t] = s[t] - v;   // exclusive (segmented per 128-half)
}

__global__ __launch_bounds__(1024) void scanC_kernel(
    const int* __restrict__ deg1, const int* __restrict__ deg3,
    const int* __restrict__ bsum,
    int* __restrict__ rp1, int* __restrict__ rp3,
    int* __restrict__ cu1, int* __restrict__ cu3,
    float* __restrict__ inv1, float* __restrict__ inv3)
{
    __shared__ int s[1024];
    int b = blockIdx.x;                    // 0..195
    const int* deg; int* rp; int* cu; float* inv; int chunk; int prefix;
    if (b < 98) { deg = deg1; rp = rp1; cu = cu1; inv = inv1; chunk = b;      prefix = bsum[chunk]; }
    else        { deg = deg3; rp = rp3; cu = cu3; inv = inv3; chunk = b - 98; prefix = bsum[128 + chunk]; }
    int tid = threadIdx.x;
    int i = chunk * 1024 + tid;
    int v = (i < NF) ? deg[i] : 0;
    s[tid] = v;
    __syncthreads();
    for (int ofs = 1; ofs < 1024; ofs <<= 1) {
        int a = (tid >= ofs) ? s[tid - ofs] : 0;
        __syncthreads();
        s[tid] += a;
        __syncthreads();
    }
    int ex = prefix + s[tid] - v;
    if (i < NF) {
        rp[i] = ex;
        cu[i] = ex;
        inv[i] = 1.0f / (float)(v > 1 ? v : 1);
    }
    if (i == 0) rp[NF] = E;
}

__global__ __launch_bounds__(256) void csr_fill13_kernel(
    const int* __restrict__ src1, const int* __restrict__ dst1,
    const int* __restrict__ src3, const int* __restrict__ dst3,
    int* __restrict__ cu1, int* __restrict__ cu3,
    int* __restrict__ csr1, int* __restrict__ csr3)
{
    int idx = blockIdx.x * 256 + threadIdx.x;
    if (idx >= 2 * E) return;
    if (idx < E) {
        int pos = atomicAdd(&cu1[dst1[idx]], 1);
        csr1[pos] = src1[idx];
    } else {
        int e = idx - E;
        int pos = atomicAdd(&cu3[dst3[e]], 1);
        csr3[pos] = src3[e];
    }
}

// ------- y = h[src-type rows] @ Wr[rel]  (Wr precomputed) -------------------
__global__ __launch_bounds__(256) void y_kernel(
    const ushort* __restrict__ hH, const float* __restrict__ wr,
    float* __restrict__ y)
{
    int row = blockIdx.x;            // 0..429  (airports then carriers)
    int c = threadIdx.x;
    const ushort* sH = hH + (size_t)(NF + row) * D;
    const float* W = wr + (size_t)((row < NA) ? 1 : 3) * DD;
    float acc = 0.f;
    #pragma unroll 8
    for (int k = 0; k < D; ++k) acc += bf2f(sH[k]) * W[k * D + c];
    y[(size_t)row * D + c] = acc;
}

// ---- bf16 MFMA GEMM: G = A @ root^T + bias (A single-plane, W split) ------
// 8 waves (512 thr), each owning a 64x32 sub-tile: acc = 8 f32x4 = 32 AGPR,
// total regs < 128 -> 16 waves/CU residency (2 blocks). Fragment-major
// global_load_lds staging: 3 planes x 8 groups of 16 rows, 3 units/wave.
__global__ __launch_bounds__(512) void gemm_mfma(
    const ushort* __restrict__ A,
    const ushort* __restrict__ WtH, const ushort* __restrict__ WtL,
    const float* __restrict__ bias,
    ushort* __restrict__ G, int nrows)
{
    constexpr int BM = 128, BK = 32;
    constexpr int PLANE = BM * BK;          // 4096 ushorts = 8 KB
    constexpr int LDW = 36;                 // fp32 epilogue scratch stride
    __shared__ __align__(16) ushort lds[12288];   // 24576 B
    const int t = threadIdx.x;
    const int row0 = blockIdx.x * BM;
    const int col0 = blockIdx.y * BM;
    const int w = t >> 6, lane = t & 63;    // 8 waves
    const int wm = w >> 2, wn = w & 3;      // 2x4 wave grid, 64x32 per wave
    const int lr = lane & 15;
    const int lk = lane >> 4;
    f32x4 acc[4][2] = {};

    // staging: 24 (plane,group) units, wave w handles 3 consecutive
    const ushort* sp[3];
    ushort* dp[3];
    #pragma unroll
    for (int i = 0; i < 3; ++i) {
        int idx = w * 3 + i;
        int plane = idx >> 3, g = idx & 7;
        const ushort* base = (plane == 0) ? A : (plane == 1) ? WtH : WtL;
        int r = ((plane == 0) ? row0 : col0) + g * 16 + lr;
        if (plane == 0 && r >= nrows) r = nrows - 1;
        sp[i] = base + (size_t)r * D + lk * 8;
        dp[i] = lds + plane * PLANE + g * 512;
    }

    for (int k0 = 0; k0 < D; k0 += BK) {
        #pragma unroll
        for (int i = 0; i < 3; ++i)
            gload_lds16(sp[i] + k0, dp[i]);
        __syncthreads();                   // drains vmcnt -> tiles visible
        const ushort* As  = lds;
        const ushort* WsH = lds + PLANE;
        const ushort* WsL = lds + 2 * PLANE;
        bf16x8 bh[2], bl[2];
        #pragma unroll
        for (int ni = 0; ni < 2; ++ni) {
            int off = (wn * 2 + ni) * 512 + lane * 8;
            bh[ni] = *(const bf16x8*)(&WsH[off]);
            bl[ni] = *(const bf16x8*)(&WsL[off]);
        }
        #pragma unroll
        for (int mi = 0; mi < 4; ++mi) {
            int off = (wm * 4 + mi) * 512 + lane * 8;
            bf16x8 ah = *(const bf16x8*)(&As[off]);
            #pragma unroll
            for (int ni = 0; ni < 2; ++ni) {
                acc[mi][ni] = __builtin_amdgcn_mfma_f32_16x16x32_bf16(ah, bh[ni], acc[mi][ni], 0, 0, 0);
                acc[mi][ni] = __builtin_amdgcn_mfma_f32_16x16x32_bf16(ah, bl[ni], acc[mi][ni], 0, 0, 0);
            }
        }
        __syncthreads();                   // all reads done before overwrite
    }
    // ---- epilogue: per-mi 16x32 pass through LDS, coalesced 16B stores -----
    float* S = (float*)lds + (size_t)w * 16 * LDW;   // per-wave 16x36 fp32
    const int rrow = lane >> 2;            // 0..15 read-back row
    const int grp  = lane & 3;             // col octet (8 bf16)
    #pragma unroll
    for (int mi = 0; mi < 4; ++mi) {
        __syncthreads();
        #pragma unroll
        for (int ni = 0; ni < 2; ++ni)
            #pragma unroll
            for (int reg = 0; reg < 4; ++reg)
                S[(lk * 4 + reg) * LDW + ni * 16 + lr] = acc[mi][ni][reg];
        __syncthreads();
        int gr = row0 + wm * 64 + mi * 16 + rrow;
        int gc = col0 + wn * 32 + grp * 8;
        if (gr >= nrows) continue;
        float4 f0 = *(const float4*)(&S[rrow * LDW + grp * 8]);
        float4 f1 = *(const float4*)(&S[rrow * LDW + grp * 8 + 4]);
        float4 b0 = *(const float4*)(bias + gc);
        float4 b1 = *(const float4*)(bias + gc + 4);
        float v[8] = {f0.x + b0.x, f0.y + b0.y, f0.z + b0.z, f0.w + b0.w,
                      f1.x + b1.x, f1.y + b1.y, f1.z + b1.z, f1.w + b1.w};
        u16x8 hh;
        #pragma unroll
        for (int j = 0; j < 8; ++j) hh[j] = f2bf(v[j]);
        *(u16x8*)(G + (size_t)gr * D + gc) = hh;
    }
}

// ---- layer-0 flight rows: G = relu(G + inv1*Σy1 + inv3*Σy3) in place ------
// 2 rows per wave: lanes 0-31 row 2w, lanes 32-63 row 2w+1; 8 ch/lane.
// Two independent edge-walk chains interleave -> 2x memory-level parallelism.
__global__ __launch_bounds__(256) void msg_relu_kernel(
    ushort* __restrict__ G,
    const float* __restrict__ y,
    const int* __restrict__ rp1, const int* __restrict__ csr1, const float* __restrict__ inv1,
    const int* __restrict__ rp3, const int* __restrict__ csr3, const float* __restrict__ inv3)
{
    int wid = (blockIdx.x * 256 + threadIdx.x) >> 6;
    int lane = threadIdx.x & 63;
    int row = wid * 2 + (lane >> 5);
    if (row >= NF) return;
    int c = (lane & 31) * 8;
    size_t o = (size_t)row * D + c;
    u16x8 gh = *(const u16x8*)(G + o);
    float v[8];
    #pragma unroll
    for (int j = 0; j < 8; ++j) v[j] = bf2f(gh[j]);
    float m[8] = {};
    int e0 = rp1[row], e1 = rp1[row + 1];
    for (int e = e0; e < e1; ++e) {
        const float* yr = y + (size_t)csr1[e] * D + c;
        float4 u0 = *(const float4*)yr;
        float4 u1 = *(const float4*)(yr + 4);
        m[0] += u0.x; m[1] += u0.y; m[2] += u0.z; m[3] += u0.w;
        m[4] += u1.x; m[5] += u1.y; m[6] += u1.z; m[7] += u1.w;
    }
    float s1 = inv1[row];
    #pragma unroll
    for (int j = 0; j < 8; ++j) { v[j] += s1 * m[j]; m[j] = 0.f; }
    e0 = rp3[row]; e1 = rp3[row + 1];
    for (int e = e0; e < e1; ++e) {
        const float* yr = y + (size_t)(NA + csr3[e]) * D + c;
        float4 u0 = *(const float4*)yr;
        float4 u1 = *(const float4*)(yr + 4);
        m[0] += u0.x; m[1] += u0.y; m[2] += u0.z; m[3] += u0.w;
        m[4] += u1.x; m[5] += u1.y; m[6] += u1.z; m[7] += u1.w;
    }
    float s3 = inv3[row];
    u16x8 oh;
    #pragma unroll
    for (int j = 0; j < 8; ++j) oh[j] = f2bf(fmaxf(v[j] + s3 * m[j], 0.f));
    *(u16x8*)(G + o) = oh;
}

// ---- layer-1: out[f] = relu(G2+msgs) . W_out + b_out (fused readout) -------
// Same 2-rows-per-wave layout; dot reduction is 5 shfl within each half.
__global__ __launch_bounds__(256) void msg_readout_kernel(
    const ushort* __restrict__ G,
    const float* __restrict__ y,
    const int* __restrict__ rp1, const int* __restrict__ csr1, const float* __restrict__ inv1,
    const int* __restrict__ rp3, const int* __restrict__ csr3, const float* __restrict__ inv3,
    const float* __restrict__ wout, const float* __restrict__ bout,
    float* __restrict__ out)
{
    int wid = (blockIdx.x * 256 + threadIdx.x) >> 6;
    int lane = threadIdx.x & 63;
    int row = wid * 2 + (lane >> 5);
    if (row >= NF) return;
    int c = (lane & 31) * 8;
    size_t o = (size_t)row * D + c;
    u16x8 gh = *(const u16x8*)(G + o);
    float v[8];
    #pragma unroll
    for (int j = 0; j < 8; ++j) v[j] = bf2f(gh[j]);
    float m[8] = {};
    int e0 = rp1[row], e1 = rp1[row + 1];
    for (int e = e0; e < e1; ++e) {
        const float* yr = y + (size_t)csr1[e] * D + c;
        float4 u0 = *(const float4*)yr;
        float4 u1 = *(const float4*)(yr + 4);
        m[0] += u0.x; m[1] += u0.y; m[2] += u0.z; m[3] += u0.w;
        m[4] += u1.x; m[5] += u1.y; m[6] += u1.z; m[7] += u1.w;
    }
    float s1 = inv1[row];
    #pragma unroll
    for (int j = 0; j < 8; ++j) { v[j] += s1 * m[j]; m[j] = 0.f; }
    e0 = rp3[row]; e1 = rp3[row + 1];
    for (int e = e0; e < e1; ++e) {
        const float* yr = y + (size_t)(NA + csr3[e]) * D + c;
        float4 u0 = *(const float4*)yr;
        float4 u1 = *(const float4*)(yr + 4);
        m[0] += u0.x; m[1] += u0.y; m[2] += u0.z; m[3] += u0.w;
        m[4] += u1.x; m[5] += u1.y; m[6] += u1.z; m[7] += u1.w;
    }
    float s3 = inv3[row];
    float4 w0 = *(const float4*)(wout + c);
    float4 w1 = *(const float4*)(wout + c + 4);
    float wv[8] = {w0.x, w0.y, w0.z, w0.w, w1.x, w1.y, w1.z, w1.w};
    float pr = 0.f;
    #pragma unroll
    for (int j = 0; j < 8; ++j) pr += fmaxf(v[j] + s3 * m[j], 0.f) * wv[j];
    pr += __shfl_xor(pr, 1);
    pr += __shfl_xor(pr, 2);
    pr += __shfl_xor(pr, 4);
    pr += __shfl_xor(pr, 8);
    pr += __shfl_xor(pr, 16);
    if ((lane & 31) == 0) out[row] = pr + bout[0];
}

// ---- r0/r2: agg[dst] += hH[src] — 2 edges per wave, 16B/lane loads ---------
__global__ __launch_bounds__(256) void agg_small_kernel(
    const ushort* __restrict__ hH,
    const int* __restrict__ rp0, const int* __restrict__ csr0,
    const int* __restrict__ rp2, const int* __restrict__ csr2,
    float* __restrict__ agg)
{
    __shared__ float red[4][256];
    int b = blockIdx.x;
    const int* rp; const int* csr; int dstn, chunk, nch; float* arow;
    if (b < NA * 4) { dstn = b >> 2; chunk = b & 3; nch = 4;  rp = rp0; csr = csr0; arow = agg + (size_t)dstn * D; }
    else { int bb = b - NA * 4; dstn = bb >> 6; chunk = bb & 63; nch = 64; rp = rp2; csr = csr2; arow = agg + (size_t)(NA + dstn) * D; }
    int s = rp[dstn], e = rp[dstn + 1];
    int cnt = e - s;
    int lo = s + (int)((long long)cnt * chunk / nch);
    int hi = s + (int)((long long)cnt * (chunk + 1) / nch);
    int w = threadIdx.x >> 6, lane = threadIdx.x & 63;
    int span = hi - lo;
    int wlo = lo + (int)((long long)span * w / 4);
    int whi = lo + (int)((long long)span * (w + 1) / 4);
    int half = lane >> 5;                  // 0: edge p, 1: edge p+1
    int ch8 = (lane & 31) * 8;
    float acc[8] = {};
    int p = wlo;
    for (; p + 1 < whi; p += 2) {
        int r = csr[p + half];
        u16x8 v = *(const u16x8*)(hH + (size_t)r * D + ch8);
        #pragma unroll
        for (int j = 0; j < 8; ++j) acc[j] += bf2f(v[j]);
    }
    if (p < whi && half == 0) {
        int r = csr[p];
        u16x8 v = *(const u16x8*)(hH + (size_t)r * D + ch8);
        #pragma unroll
        for (int j = 0; j < 8; ++j) acc[j] += bf2f(v[j]);
    }
    #pragma unroll
    for (int j = 0; j < 8; ++j) acc[j] += __shfl_xor(acc[j], 32);
    if (lane < 32) {
        #pragma unroll
        for (int j = 0; j < 8; ++j) red[w][ch8 + j] = acc[j];
    }
    __syncthreads();
    int c = threadIdx.x;
    float total = red[0][c] + red[1][c] + red[2][c] + red[3][c];
    atomicAdd(arow + c, total);
}

// -- r0/r2 transform: G = relu(G + inv_deg*(agg @ Wr[rel])) in place ---------
__global__ __launch_bounds__(256) void smallT_kernel(
    const float* __restrict__ agg, const float* __restrict__ wr,
    const float* __restrict__ inv0, const float* __restrict__ inv2,
    ushort* __restrict__ G)
{
    int row = blockIdx.x;            // 0..429
    int c = threadIdx.x;
    const float* a = agg + (size_t)row * D;
    const float* W = wr + (size_t)((row < NA) ? 0 : 2) * DD;
    float scale = (row < NA) ? inv0[row] : inv2[row - NA];
    float acc = 0.f;
    #pragma unroll 8
    for (int k = 0; k < D; ++k) acc += a[k] * W[k * D + c];
    size_t o = (size_t)(NF + row) * D + c;
    G[o] = f2bf(fmaxf(bf2f(G[o]) + scale * acc, 0.f));
}

extern "C" void kernel_launch(void* const* d_in, const int* in_sizes, int n_in,
                              void* d_out, int out_size, void* d_ws, size_t ws_size,
                              hipStream_t stream)
{
    const float* xf = (const float*)d_in[0];
    const float* xa = (const float*)d_in[1];
    const float* xc = (const float*)d_in[2];
    const float* Wf = (const float*)d_in[3];
    const float* bf = (const float*)d_in[4];
    const float* Wa = (const float*)d_in[5];
    const float* ba = (const float*)d_in[6];
    const float* Wc = (const float*)d_in[7];
    const float* bc = (const float*)d_in[8];
    const float* basis0 = (const float*)d_in[9];
    const float* comp0  = (const float*)d_in[10];
    const float* root0  = (const float*)d_in[11];
    const float* bias0  = (const float*)d_in[12];
    const float* basis1 = (const float*)d_in[13];
    const float* comp1  = (const float*)d_in[14];
    const float* root1  = (const float*)d_in[15];
    const float* bias1  = (const float*)d_in[16];
    const float* Wout = (const float*)d_in[17];
    const float* bout = (const float*)d_in[18];
    const int* src0 = (const int*)d_in[19];
    const int* dst0 = (const int*)d_in[20];
    const int* src1 = (const int*)d_in[21];
    const int* dst1 = (const int*)d_in[22];
    const int* src2 = (const int*)d_in[23];
    const int* dst2 = (const int*)d_in[24];
    const int* src3 = (const int*)d_in[25];
    const int* dst3 = (const int*)d_in[26];
    float* out = (float*)d_out;

    char* ws = (char*)d_ws;
    size_t off = 0;
    auto alloc = [&](size_t bytes) -> char* {
        char* p = ws + off;
        off = (off + bytes + 255) & ~(size_t)255;
        return p;
    };
    ushort* hH  = (ushort*)alloc((size_t)NN * D * 2);
    ushort* gH  = (ushort*)alloc((size_t)NN * D * 2);
    // layer-1 GEMM output reuses hH (dead after layer-0 consumers)
    ushort* g2H = hH;
    ushort* WtH = (ushort*)alloc((size_t)DD * 2);
    ushort* WtL = (ushort*)alloc((size_t)DD * 2);
    float* wrbuf  = (float*)alloc((size_t)4 * DD * 4);
    float* ybuf   = (float*)alloc((size_t)(NA + NC) * D * 4);
    float* aggbuf = (float*)alloc((size_t)(NA + NC) * D * 4);
    int*   deg13  = (int*)  alloc((size_t)2 * NF * 4);
    int* deg1 = deg13; int* deg3 = deg13 + NF;
    float* inv1 = (float*)alloc((size_t)NF * 4);
    float* inv3 = (float*)alloc((size_t)NF * 4);
    float* inv0 = (float*)alloc((size_t)NA * 4);
    float* inv2 = (float*)alloc((size_t)NC * 4);
    int* rp0 = (int*)alloc((NA + 1) * 4);
    int* rp1 = (int*)alloc((size_t)(NF + 1) * 4);
    int* rp2 = (int*)alloc((NC + 1) * 4);
    int* rp3 = (int*)alloc((size_t)(NF + 1) * 4);
    int* cu1 = (int*)alloc((size_t)(NF + 1) * 4);
    int* cu3 = (int*)alloc((size_t)(NF + 1) * 4);
    int* csr0 = (int*)alloc((size_t)E * 4);
    int* csr1 = (int*)alloc((size_t)E * 4);
    int* csr2 = (int*)alloc((size_t)E * 4);
    int* csr3 = (int*)alloc((size_t)E * 4);
    int* bsum = (int*)alloc(256 * 4);
    int* bh0  = (int*)alloc((size_t)NSL * NA * 4);
    int* bh2  = (int*)alloc((size_t)NSL * NC * 4);
    (void)ws_size; (void)in_sizes; (void)n_in; (void)out_size;

    // ---- CSR build: r0/r2 via contention-free counting sort
    hist02_kernel<<<2 * NSL, 256, 0, stream>>>(dst0, dst2, bh0, bh2);
    scan02_kernel<<<1, 512, 0, stream>>>(bh0, bh2, rp0, rp2, inv0, inv2);
    fill02_kernel<<<2 * NSL, 256, 0, stream>>>(src0, dst0, src2, dst2, bh0, bh2, csr0, csr2);

    // ---- CSR build: r1/r3 via atomics (100K dsts, avg degree 2.5 — cheap)
    hipMemsetAsync(deg13, 0, (size_t)2 * NF * 4, stream);
    deg_count_kernel<<<(2 * E + 255) / 256, 256, 0, stream>>>(dst1, dst3, deg1, deg3);
    scanA_kernel<<<196, 1024, 0, stream>>>(deg1, deg3, bsum);
    scanB_kernel<<<1, 256, 0, stream>>>(bsum);
    scanC_kernel<<<196, 1024, 0, stream>>>(deg1, deg3, bsum, rp1, rp3, cu1, cu3, inv1, inv3);
    csr_fill13_kernel<<<(2 * E + 255) / 256, 256, 0, stream>>>(
        src1, dst1, src3, dst3, cu1, cu3, csr1, csr3);

    // ---- encoders (single bf16 plane)
    encode_kernel<32, 8><<<NF / 8, 256, 0, stream>>>(xf, Wf, bf, hH, NF, 0);
    encode_kernel<16, 8><<<(NA + 7) / 8, 256, 0, stream>>>(xa, Wa, ba, hH, NA, NF);
    encode_kernel<8, 8><<<(NC + 7) / 8, 256, 0, stream>>>(xc, Wc, bc, hH, NC, NF + NA);

    // ---- layer 0: pure MFMA gemm -> G; then per-row-type finishers in place
    wsplit_kernel<<<D, D, 0, stream>>>(root0, WtH, WtL);
    wr_kernel<<<4 * DD / 256, 256, 0, stream>>>(basis0, comp0, wrbuf);
    y_kernel<<<NA + NC, 256, 0, stream>>>(hH, wrbuf, ybuf);
    gemm_mfma<<<dim3((NN + 127) / 128, 2), 512, 0, stream>>>(
        hH, WtH, WtL, bias0, gH, NN);
    hipMemsetAsync(aggbuf, 0, (size_t)(NA + NC) * D * 4, stream);
    agg_small_kernel<<<NA * 4 + NC * 64, 256, 0, stream>>>(
        hH, rp0, csr0, rp2, csr2, aggbuf);
    smallT_kernel<<<NA + NC, 256, 0, stream>>>(aggbuf, wrbuf, inv0, inv2, gH);
    msg_relu_kernel<<<(NF / 2 * 64 + 255) / 256, 256, 0, stream>>>(
        gH, ybuf, rp1, csr1, inv1, rp3, csr3, inv3);

    // ---- layer 1 (flights only): pure gemm -> G2 (aliases h); readout -> out
    wsplit_kernel<<<D, D, 0, stream>>>(root1, WtH, WtL);
    wr_kernel<<<4 * DD / 256, 256, 0, stream>>>(basis1, comp1, wrbuf);
    y_kernel<<<NA + NC, 256, 0, stream>>>(gH, wrbuf, ybuf);
    gemm_mfma<<<dim3((NF + 127) / 128, 2), 512, 0, stream>>>(
        gH, WtH, WtL, bias1, g2H, NF);
    msg_readout_kernel<<<(NF / 2 * 64 + 255) / 256, 256, 0, stream>>>(
        g2H, ybuf, rp1, csr1, inv1, rp3, csr3, inv3, Wout, bout, out);
}

// Round 16
// 402.917 us; speedup vs baseline: 1.3231x; 1.0091x over previous
//
#include <hip/hip_runtime.h>
#include <hip/hip_bf16.h>
#include <cstdint>
#include <cstddef>

constexpr int NF = 100000;
constexpr int NA = 400;
constexpr int NC = 30;
constexpr int NN = NF + NA + NC;     // 100430
constexpr int D  = 256;
constexpr int DD = D * D;            // 65536
constexpr int E  = 250000;
constexpr int NSL = 128;             // slices for r0/r2 counting sort

typedef __attribute__((ext_vector_type(8))) short bf16x8;
typedef __attribute__((ext_vector_type(4))) float f32x4;
typedef __attribute__((ext_vector_type(8))) ushort u16x8;

__device__ inline ushort f2bf(float f) {
    __hip_bfloat16 h = __float2bfloat16(f);
    return __builtin_bit_cast(ushort, h);
}
__device__ inline float bf2f(ushort u) {
    __hip_bfloat16 h = __builtin_bit_cast(__hip_bfloat16, u);
    return __bfloat162float(h);
}

// async global->LDS, 16B per lane: LDS dest = base + lane*16 (wave-linear)
__device__ inline void gload_lds16(const ushort* g, ushort* l) {
    __builtin_amdgcn_global_load_lds(
        (const __attribute__((address_space(1))) void*)g,
        (__attribute__((address_space(3))) void*)l, 16, 0, 0);
}

// ---------------- per-type encoders: h = relu(x @ W + b) -> bf16 ------------
template<int K, int ROWS>
__global__ __launch_bounds__(256) void encode_kernel(
    const float* __restrict__ x, const float* __restrict__ W,
    const float* __restrict__ b, ushort* __restrict__ hH,
    int rows, int row_off)
{
    int c = threadIdx.x;
    int base = blockIdx.x * ROWS;
    float wcol[K];
    #pragma unroll
    for (int k = 0; k < K; ++k) wcol[k] = W[k * D + c];
    float bias = b[c];
    for (int i = 0; i < ROWS; ++i) {
        int row = base + i;
        if (row >= rows) return;
        const float* xr = x + (size_t)row * K;
        float acc = bias;
        #pragma unroll
        for (int k = 0; k < K; ++k) acc += xr[k] * wcol[k];
        hH[(size_t)(row_off + row) * D + c] = f2bf(fmaxf(acc, 0.f));
    }
}

// ---------------- weight split+transpose: root[k][n] -> WtH/WtL[n][k] -------
__global__ __launch_bounds__(256) void wsplit_kernel(
    const float* __restrict__ root, ushort* __restrict__ WtH, ushort* __restrict__ WtL)
{
    int n = blockIdx.x, k = threadIdx.x;
    float w = root[(size_t)k * D + n];
    ushort hi = f2bf(w);
    WtH[(size_t)n * D + k] = hi;
    WtL[(size_t)n * D + k] = f2bf(w - bf2f(hi));
}

// ---------------- basis combine: Wr[r] = sum_b comp[r,b] * basis[b] ---------
__global__ __launch_bounds__(256) void wr_kernel(
    const float* __restrict__ basis, const float* __restrict__ comp,
    float* __restrict__ wr)
{
    int idx = blockIdx.x * 256 + threadIdx.x;   // < 4*DD
    int r = idx >> 16;
    int io = idx & (DD - 1);
    wr[idx] = comp[r * 3 + 0] * basis[io]
            + comp[r * 3 + 1] * basis[DD + io]
            + comp[r * 3 + 2] * basis[2 * DD + io];
}

// ---------------- r1/r3 degree count (low contention: 100K dsts) ----------
__global__ __launch_bounds__(256) void deg_count_kernel(
    const int* __restrict__ dst1, const int* __restrict__ dst3,
    int* __restrict__ deg1, int* __restrict__ deg3)
{
    int idx = blockIdx.x * 256 + threadIdx.x;
    if (idx >= 2 * E) return;
    if (idx < E) atomicAdd(&deg1[dst1[idx]], 1);
    else         atomicAdd(&deg3[dst3[idx - E]], 1);
}

// ---------------- r0/r2: per-slice LDS histograms (contention-free) --------
__global__ __launch_bounds__(256) void hist02_kernel(
    const int* __restrict__ dst0, const int* __restrict__ dst2,
    int* __restrict__ bh0, int* __restrict__ bh2)
{
    __shared__ int hist[NA];
    int b = blockIdx.x;                 // 0..2*NSL-1
    bool isR2 = (b >= NSL);
    int sl = isR2 ? b - NSL : b;
    const int* dst = isR2 ? dst2 : dst0;
    int nb = isR2 ? NC : NA;
    for (int i = threadIdx.x; i < nb; i += 256) hist[i] = 0;
    __syncthreads();
    int lo = (int)((long long)E * sl / NSL);
    int hi = (int)((long long)E * (sl + 1) / NSL);
    for (int e = lo + threadIdx.x; e < hi; e += 256)
        atomicAdd(&hist[dst[e]], 1);
    __syncthreads();
    int* bh = isR2 ? (bh2 + sl * NC) : (bh0 + sl * NA);
    for (int i = threadIdx.x; i < nb; i += 256) bh[i] = hist[i];
}

// -------- scan: per-bin over slices + cross-bin; emits rp/inv + abs offsets -
__global__ __launch_bounds__(512) void scan02_kernel(
    int* __restrict__ bh0, int* __restrict__ bh2,
    int* __restrict__ rp0, int* __restrict__ rp2,
    float* __restrict__ inv0, float* __restrict__ inv2)
{
    __shared__ int tot[512];
    __shared__ int exc[512];
    int t = threadIdx.x;
    int cnt = 0;
    if (t < NA) {
        int s = 0;
        for (int sl = 0; sl < NSL; ++sl) {
            int v = bh0[sl * NA + t]; bh0[sl * NA + t] = s; s += v;
        }
        cnt = s;
    } else if (t < NA + NC) {
        int bin = t - NA; int s = 0;
        for (int sl = 0; sl < NSL; ++sl) {
            int v = bh2[sl * NC + bin]; bh2[sl * NC + bin] = s; s += v;
        }
        cnt = s;
    }
    tot[t] = cnt;
    __syncthreads();
    for (int ofs = 1; ofs < 512; ofs <<= 1) {
        int v = (t >= ofs) ? tot[t - ofs] : 0;
        __syncthreads();
        tot[t] += v;
        __syncthreads();
    }
    int ex = tot[t] - cnt;              // exclusive over combined [r0 | r2]
    if (t < NA) {
        exc[t] = ex;
        rp0[t] = ex;
        inv0[t] = 1.0f / (float)(cnt > 1 ? cnt : 1);
        if (t == 0) { rp0[NA] = E; rp2[NC] = E; }
    } else if (t < NA + NC) {
        exc[t] = ex - E;                // r2 csr buffer is its own array
        rp2[t - NA] = ex - E;
        inv2[t - NA] = 1.0f / (float)(cnt > 1 ? cnt : 1);
    } else exc[t] = 0;
    __syncthreads();
    for (int idx = t; idx < NSL * NA; idx += 512) {
        int sl = idx / NA; int bin = idx - sl * NA;
        bh0[idx] += exc[bin];
    }
    for (int idx = t; idx < NSL * NC; idx += 512) {
        int sl = idx / NC; int bin = idx - sl * NC;
        bh2[idx] += exc[NA + bin];
    }
}

// ---------------- r0/r2 CSR fill with LDS cursors --------------------------
__global__ __launch_bounds__(256) void fill02_kernel(
    const int* __restrict__ src0, const int* __restrict__ dst0,
    const int* __restrict__ src2, const int* __restrict__ dst2,
    const int* __restrict__ bh0, const int* __restrict__ bh2,
    int* __restrict__ csr0, int* __restrict__ csr2)
{
    __shared__ int cur[NA];
    int b = blockIdx.x;
    bool isR2 = (b >= NSL);
    int sl = isR2 ? b - NSL : b;
    const int* src = isR2 ? src2 : src0;
    const int* dst = isR2 ? dst2 : dst0;
    const int* bh  = isR2 ? (bh2 + sl * NC) : (bh0 + sl * NA);
    int* csr       = isR2 ? csr2 : csr0;
    int nb = isR2 ? NC : NA;
    for (int i = threadIdx.x; i < nb; i += 256) cur[i] = bh[i];
    __syncthreads();
    int lo = (int)((long long)E * sl / NSL);
    int hi = (int)((long long)E * (sl + 1) / NSL);
    for (int e = lo + threadIdx.x; e < hi; e += 256) {
        int pos = atomicAdd(&cur[dst[e]], 1);
        csr[pos] = src[e];
    }
}

// ---------------- r1/r3 scan chain -----------------------------------------
__global__ __launch_bounds__(1024) void scanA_kernel(
    const int* __restrict__ deg1, const int* __restrict__ deg3, int* __restrict__ bsum)
{
    __shared__ int s[1024];
    int b = blockIdx.x;                    // 0..195
    bool isR3 = (b >= 98);
    const int* deg = isR3 ? deg3 : deg1;
    int chunk = isR3 ? b - 98 : b;
    int i = chunk * 1024 + threadIdx.x;
    int v = (i < NF) ? deg[i] : 0;
    s[threadIdx.x] = v;
    __syncthreads();
    for (int ofs = 512; ofs > 0; ofs >>= 1) {
        if ((int)threadIdx.x < ofs) s[threadIdx.x] += s[threadIdx.x + ofs];
        __syncthreads();
    }
    if (threadIdx.x == 0) bsum[(isR3 ? 128 : 0) + chunk] = s[0];
}

__global__ __launch_bounds__(256) void scanB_kernel(int* __restrict__ bsum)
{
    __shared__ int s[256];
    int t = threadIdx.x;
    int v = ((t & 127) < 98) ? bsum[t] : 0;
    s[t] = v;
    __syncthreads();
    for (int ofs = 1; ofs < 128; ofs <<= 1) {
        int a = ((t & 127) >= ofs) ? s[t - ofs] : 0;
        __syncthreads();
        s[t] += a;
        __syncthreads();
    }
    bsum[t] = s[t] - v;   // exclusive (segmented per 128-half)
}

__global__ __launch_bounds__(1024) void scanC_kernel(
    const int* __restrict__ deg1, const int* __restrict__ deg3,
    const int* __restrict__ bsum,
    int* __restrict__ rp1, int* __restrict__ rp3,
    int* __restrict__ cu1, int* __restrict__ cu3,
    float* __restrict__ inv1, float* __restrict__ inv3)
{
    __shared__ int s[1024];
    int b = blockIdx.x;                    // 0..195
    const int* deg; int* rp; int* cu; float* inv; int chunk; int prefix;
    if (b < 98) { deg = deg1; rp = rp1; cu = cu1; inv = inv1; chunk = b;      prefix = bsum[chunk]; }
    else        { deg = deg3; rp = rp3; cu = cu3; inv = inv3; chunk = b - 98; prefix = bsum[128 + chunk]; }
    int tid = threadIdx.x;
    int i = chunk * 1024 + tid;
    int v = (i < NF) ? deg[i] : 0;
    s[tid] = v;
    __syncthreads();
    for (int ofs = 1; ofs < 1024; ofs <<= 1) {
        int a = (tid >= ofs) ? s[tid - ofs] : 0;
        __syncthreads();
        s[tid] += a;
        __syncthreads();
    }
    int ex = prefix + s[tid] - v;
    if (i < NF) {
        rp[i] = ex;
        cu[i] = ex;
        inv[i] = 1.0f / (float)(v > 1 ? v : 1);
    }
    if (i == 0) rp[NF] = E;
}

__global__ __launch_bounds__(256) void csr_fill13_kernel(
    const int* __restrict__ src1, const int* __restrict__ dst1,
    const int* __restrict__ src3, const int* __restrict__ dst3,
    int* __restrict__ cu1, int* __restrict__ cu3,
    int* __restrict__ csr1, int* __restrict__ csr3)
{
    int idx = blockIdx.x * 256 + threadIdx.x;
    if (idx >= 2 * E) return;
    if (idx < E) {
        int pos = atomicAdd(&cu1[dst1[idx]], 1);
        csr1[pos] = src1[idx];
    } else {
        int e = idx - E;
        int pos = atomicAdd(&cu3[dst3[e]], 1);
        csr3[pos] = src3[e];
    }
}

// ------- y = h[src-type rows] @ Wr[rel]  (Wr precomputed) -------------------
__global__ __launch_bounds__(256) void y_kernel(
    const ushort* __restrict__ hH, const float* __restrict__ wr,
    float* __restrict__ y)
{
    int row = blockIdx.x;            // 0..429  (airports then carriers)
    int c = threadIdx.x;
    const ushort* sH = hH + (size_t)(NF + row) * D;
    const float* W = wr + (size_t)((row < NA) ? 1 : 3) * DD;
    float acc = 0.f;
    #pragma unroll 8
    for (int k = 0; k < D; ++k) acc += bf2f(sH[k]) * W[k * D + c];
    y[(size_t)row * D + c] = acc;
}

// ---- bf16 MFMA GEMM: G = A @ root^T + bias (A single-plane, W split) ------
// 8 waves, 64x32 sub-tiles, fragment-major global_load_lds staging, now with
// 2-phase double-buffered LDS: stage tile k+1 into buf^1, compute tile k,
// then vmcnt(0)+s_barrier. Prefetch latency hides under the MFMA section.
// LDS 2x24576=49152 B -> 3 blocks/CU ceiling (above measured residency).
__global__ __launch_bounds__(512) void gemm_mfma(
    const ushort* __restrict__ A,
    const ushort* __restrict__ WtH, const ushort* __restrict__ WtL,
    const float* __restrict__ bias,
    ushort* __restrict__ G, int nrows)
{
    constexpr int BM = 128, BK = 32;
    constexpr int PLANE = BM * BK;          // 4096 ushorts = 8 KB
    constexpr int BUF = 3 * PLANE;          // 12288 ushorts = 24 KB
    constexpr int LDW = 36;                 // fp32 epilogue scratch stride
    __shared__ __align__(16) ushort lds[2 * BUF];   // 49152 B
    const int t = threadIdx.x;
    const int row0 = blockIdx.x * BM;
    const int col0 = blockIdx.y * BM;
    const int w = t >> 6, lane = t & 63;    // 8 waves
    const int wm = w >> 2, wn = w & 3;      // 2x4 wave grid, 64x32 per wave
    const int lr = lane & 15;
    const int lk = lane >> 4;
    f32x4 acc[4][2] = {};

    // staging: 24 (plane,group) units, wave w handles 3 consecutive
    const ushort* sp[3];
    int dofs[3];
    #pragma unroll
    for (int i = 0; i < 3; ++i) {
        int idx = w * 3 + i;
        int plane = idx >> 3, g = idx & 7;
        const ushort* base = (plane == 0) ? A : (plane == 1) ? WtH : WtL;
        int r = ((plane == 0) ? row0 : col0) + g * 16 + lr;
        if (plane == 0 && r >= nrows) r = nrows - 1;
        sp[i] = base + (size_t)r * D + lk * 8;
        dofs[i] = plane * PLANE + g * 512;
    }

    auto stage = [&](int k0, int buf) {
        ushort* bb = lds + buf * BUF;
        #pragma unroll
        for (int i = 0; i < 3; ++i)
            gload_lds16(sp[i] + k0, bb + dofs[i]);
    };
    auto compute = [&](int buf) {
        const ushort* base = lds + buf * BUF;
        const ushort* As  = base;
        const ushort* WsH = base + PLANE;
        const ushort* WsL = base + 2 * PLANE;
        bf16x8 bh[2], bl[2];
        #pragma unroll
        for (int ni = 0; ni < 2; ++ni) {
            int off = (wn * 2 + ni) * 512 + lane * 8;
            bh[ni] = *(const bf16x8*)(&WsH[off]);
            bl[ni] = *(const bf16x8*)(&WsL[off]);
        }
        #pragma unroll
        for (int mi = 0; mi < 4; ++mi) {
            int off = (wm * 4 + mi) * 512 + lane * 8;
            bf16x8 ah = *(const bf16x8*)(&As[off]);
            #pragma unroll
            for (int ni = 0; ni < 2; ++ni) {
                acc[mi][ni] = __builtin_amdgcn_mfma_f32_16x16x32_bf16(ah, bh[ni], acc[mi][ni], 0, 0, 0);
                acc[mi][ni] = __builtin_amdgcn_mfma_f32_16x16x32_bf16(ah, bl[ni], acc[mi][ni], 0, 0, 0);
            }
        }
    };

    // prologue: tile 0 -> buf0, full drain
    stage(0, 0);
    asm volatile("s_waitcnt vmcnt(0)" ::: "memory");
    __builtin_amdgcn_s_barrier();
    __builtin_amdgcn_sched_barrier(0);
    // main loop: compute tile kt while tile kt+1 streams into the other buf
    for (int kt = 0; kt < 7; ++kt) {
        stage((kt + 1) * BK, (kt + 1) & 1);
        __builtin_amdgcn_sched_barrier(0);   // keep prefetch issues ahead
        compute(kt & 1);
        asm volatile("s_waitcnt vmcnt(0)" ::: "memory");
        __builtin_amdgcn_s_barrier();
        __builtin_amdgcn_sched_barrier(0);
    }
    compute(1);                              // tile 7 already landed in buf1

    // ---- epilogue: per-mi 16x32 pass through LDS, coalesced 16B stores -----
    __syncthreads();                         // everyone done with buffers
    float* S = (float*)lds + (size_t)w * 16 * LDW;   // per-wave 16x36 fp32
    const int rrow = lane >> 2;            // 0..15 read-back row
    const int grp  = lane & 3;             // col octet (8 bf16)
    #pragma unroll
    for (int mi = 0; mi < 4; ++mi) {
        __syncthreads();
        #pragma unroll
        for (int ni = 0; ni < 2; ++ni)
            #pragma unroll
            for (int reg = 0; reg < 4; ++reg)
                S[(lk * 4 + reg) * LDW + ni * 16 + lr] = acc[mi][ni][reg];
        __syncthreads();
        int gr = row0 + wm * 64 + mi * 16 + rrow;
        int gc = col0 + wn * 32 + grp * 8;
        if (gr >= nrows) continue;
        float4 f0 = *(const float4*)(&S[rrow * LDW + grp * 8]);
        float4 f1 = *(const float4*)(&S[rrow * LDW + grp * 8 + 4]);
        float4 b0 = *(const float4*)(bias + gc);
        float4 b1 = *(const float4*)(bias + gc + 4);
        float v[8] = {f0.x + b0.x, f0.y + b0.y, f0.z + b0.z, f0.w + b0.w,
                      f1.x + b1.x, f1.y + b1.y, f1.z + b1.z, f1.w + b1.w};
        u16x8 hh;
        #pragma unroll
        for (int j = 0; j < 8; ++j) hh[j] = f2bf(v[j]);
        *(u16x8*)(G + (size_t)gr * D + gc) = hh;
    }
}

// ---- layer-0 flight rows: G = relu(G + inv1*Σy1 + inv3*Σy3) in place ------
// 2 rows per wave: lanes 0-31 row 2w, lanes 32-63 row 2w+1; 8 ch/lane.
__global__ __launch_bounds__(256) void msg_relu_kernel(
    ushort* __restrict__ G,
    const float* __restrict__ y,
    const int* __restrict__ rp1, const int* __restrict__ csr1, const float* __restrict__ inv1,
    const int* __restrict__ rp3, const int* __restrict__ csr3, const float* __restrict__ inv3)
{
    int wid = (blockIdx.x * 256 + threadIdx.x) >> 6;
    int lane = threadIdx.x & 63;
    int row = wid * 2 + (lane >> 5);
    if (row >= NF) return;
    int c = (lane & 31) * 8;
    size_t o = (size_t)row * D + c;
    u16x8 gh = *(const u16x8*)(G + o);
    float v[8];
    #pragma unroll
    for (int j = 0; j < 8; ++j) v[j] = bf2f(gh[j]);
    float m[8] = {};
    int e0 = rp1[row], e1 = rp1[row + 1];
    for (int e = e0; e < e1; ++e) {
        const float* yr = y + (size_t)csr1[e] * D + c;
        float4 u0 = *(const float4*)yr;
        float4 u1 = *(const float4*)(yr + 4);
        m[0] += u0.x; m[1] += u0.y; m[2] += u0.z; m[3] += u0.w;
        m[4] += u1.x; m[5] += u1.y; m[6] += u1.z; m[7] += u1.w;
    }
    float s1 = inv1[row];
    #pragma unroll
    for (int j = 0; j < 8; ++j) { v[j] += s1 * m[j]; m[j] = 0.f; }
    e0 = rp3[row]; e1 = rp3[row + 1];
    for (int e = e0; e < e1; ++e) {
        const float* yr = y + (size_t)(NA + csr3[e]) * D + c;
        float4 u0 = *(const float4*)yr;
        float4 u1 = *(const float4*)(yr + 4);
        m[0] += u0.x; m[1] += u0.y; m[2] += u0.z; m[3] += u0.w;
        m[4] += u1.x; m[5] += u1.y; m[6] += u1.z; m[7] += u1.w;
    }
    float s3 = inv3[row];
    u16x8 oh;
    #pragma unroll
    for (int j = 0; j < 8; ++j) oh[j] = f2bf(fmaxf(v[j] + s3 * m[j], 0.f));
    *(u16x8*)(G + o) = oh;
}

// ---- layer-1: out[f] = relu(G2+msgs) . W_out + b_out (fused readout) -------
__global__ __launch_bounds__(256) void msg_readout_kernel(
    const ushort* __restrict__ G,
    const float* __restrict__ y,
    const int* __restrict__ rp1, const int* __restrict__ csr1, const float* __restrict__ inv1,
    const int* __restrict__ rp3, const int* __restrict__ csr3, const float* __restrict__ inv3,
    const float* __restrict__ wout, const float* __restrict__ bout,
    float* __restrict__ out)
{
    int wid = (blockIdx.x * 256 + threadIdx.x) >> 6;
    int lane = threadIdx.x & 63;
    int row = wid * 2 + (lane >> 5);
    if (row >= NF) return;
    int c = (lane & 31) * 8;
    size_t o = (size_t)row * D + c;
    u16x8 gh = *(const u16x8*)(G + o);
    float v[8];
    #pragma unroll
    for (int j = 0; j < 8; ++j) v[j] = bf2f(gh[j]);
    float m[8] = {};
    int e0 = rp1[row], e1 = rp1[row + 1];
    for (int e = e0; e < e1; ++e) {
        const float* yr = y + (size_t)csr1[e] * D + c;
        float4 u0 = *(const float4*)yr;
        float4 u1 = *(const float4*)(yr + 4);
        m[0] += u0.x; m[1] += u0.y; m[2] += u0.z; m[3] += u0.w;
        m[4] += u1.x; m[5] += u1.y; m[6] += u1.z; m[7] += u1.w;
    }
    float s1 = inv1[row];
    #pragma unroll
    for (int j = 0; j < 8; ++j) { v[j] += s1 * m[j]; m[j] = 0.f; }
    e0 = rp3[row]; e1 = rp3[row + 1];
    for (int e = e0; e < e1; ++e) {
        const float* yr = y + (size_t)(NA + csr3[e]) * D + c;
        float4 u0 = *(const float4*)yr;
        float4 u1 = *(const float4*)(yr + 4);
        m[0] += u0.x; m[1] += u0.y; m[2] += u0.z; m[3] += u0.w;
        m[4] += u1.x; m[5] += u1.y; m[6] += u1.z; m[7] += u1.w;
    }
    float s3 = inv3[row];
    float4 w0 = *(const float4*)(wout + c);
    float4 w1 = *(const float4*)(wout + c + 4);
    float wv[8] = {w0.x, w0.y, w0.z, w0.w, w1.x, w1.y, w1.z, w1.w};
    float pr = 0.f;
    #pragma unroll
    for (int j = 0; j < 8; ++j) pr += fmaxf(v[j] + s3 * m[j], 0.f) * wv[j];
    pr += __shfl_xor(pr, 1);
    pr += __shfl_xor(pr, 2);
    pr += __shfl_xor(pr, 4);
    pr += __shfl_xor(pr, 8);
    pr += __shfl_xor(pr, 16);
    if ((lane & 31) == 0) out[row] = pr + bout[0];
}

// ---- r0/r2: agg[dst] += hH[src] — 2 edges per wave, 16B/lane loads ---------
__global__ __launch_bounds__(256) void agg_small_kernel(
    const ushort* __restrict__ hH,
    const int* __restrict__ rp0, const int* __restrict__ csr0,
    const int* __restrict__ rp2, const int* __restrict__ csr2,
    float* __restrict__ agg)
{
    __shared__ float red[4][256];
    int b = blockIdx.x;
    const int* rp; const int* csr; int dstn, chunk, nch; float* arow;
    if (b < NA * 4) { dstn = b >> 2; chunk = b & 3; nch = 4;  rp = rp0; csr = csr0; arow = agg + (size_t)dstn * D; }
    else { int bb = b - NA * 4; dstn = bb >> 6; chunk = bb & 63; nch = 64; rp = rp2; csr = csr2; arow = agg + (size_t)(NA + dstn) * D; }
    int s = rp[dstn], e = rp[dstn + 1];
    int cnt = e - s;
    int lo = s + (int)((long long)cnt * chunk / nch);
    int hi = s + (int)((long long)cnt * (chunk + 1) / nch);
    int w = threadIdx.x >> 6, lane = threadIdx.x & 63;
    int span = hi - lo;
    int wlo = lo + (int)((long long)span * w / 4);
    int whi = lo + (int)((long long)span * (w + 1) / 4);
    int half = lane >> 5;                  // 0: edge p, 1: edge p+1
    int ch8 = (lane & 31) * 8;
    float acc[8] = {};
    int p = wlo;
    for (; p + 1 < whi; p += 2) {
        int r = csr[p + half];
        u16x8 v = *(const u16x8*)(hH + (size_t)r * D + ch8);
        #pragma unroll
        for (int j = 0; j < 8; ++j) acc[j] += bf2f(v[j]);
    }
    if (p < whi && half == 0) {
        int r = csr[p];
        u16x8 v = *(const u16x8*)(hH + (size_t)r * D + ch8);
        #pragma unroll
        for (int j = 0; j < 8; ++j) acc[j] += bf2f(v[j]);
    }
    #pragma unroll
    for (int j = 0; j < 8; ++j) acc[j] += __shfl_xor(acc[j], 32);
    if (lane < 32) {
        #pragma unroll
        for (int j = 0; j < 8; ++j) red[w][ch8 + j] = acc[j];
    }
    __syncthreads();
    int c = threadIdx.x;
    float total = red[0][c] + red[1][c] + red[2][c] + red[3][c];
    atomicAdd(arow + c, total);
}

// -- r0/r2 transform: G = relu(G + inv_deg*(agg @ Wr[rel])) in place ---------
__global__ __launch_bounds__(256) void smallT_kernel(
    const float* __restrict__ agg, const float* __restrict__ wr,
    const float* __restrict__ inv0, const float* __restrict__ inv2,
    ushort* __restrict__ G)
{
    int row = blockIdx.x;            // 0..429
    int c = threadIdx.x;
    const float* a = agg + (size_t)row * D;
    const float* W = wr + (size_t)((row < NA) ? 0 : 2) * DD;
    float scale = (row < NA) ? inv0[row] : inv2[row - NA];
    float acc = 0.f;
    #pragma unroll 8
    for (int k = 0; k < D; ++k) acc += a[k] * W[k * D + c];
    size_t o = (size_t)(NF + row) * D + c;
    G[o] = f2bf(fmaxf(bf2f(G[o]) + scale * acc, 0.f));
}

extern "C" void kernel_launch(void* const* d_in, const int* in_sizes, int n_in,
                              void* d_out, int out_size, void* d_ws, size_t ws_size,
                              hipStream_t stream)
{
    const float* xf = (const float*)d_in[0];
    const float* xa = (const float*)d_in[1];
    const float* xc = (const float*)d_in[2];
    const float* Wf = (const float*)d_in[3];
    const float* bf = (const float*)d_in[4];
    const float* Wa = (const float*)d_in[5];
    const float* ba = (const float*)d_in[6];
    const float* Wc = (const float*)d_in[7];
    const float* bc = (const float*)d_in[8];
    const float* basis0 = (const float*)d_in[9];
    const float* comp0  = (const float*)d_in[10];
    const float* root0  = (const float*)d_in[11];
    const float* bias0  = (const float*)d_in[12];
    const float* basis1 = (const float*)d_in[13];
    const float* comp1  = (const float*)d_in[14];
    const float* root1  = (const float*)d_in[15];
    const float* bias1  = (const float*)d_in[16];
    const float* Wout = (const float*)d_in[17];
    const float* bout = (const float*)d_in[18];
    const int* src0 = (const int*)d_in[19];
    const int* dst0 = (const int*)d_in[20];
    const int* src1 = (const int*)d_in[21];
    const int* dst1 = (const int*)d_in[22];
    const int* src2 = (const int*)d_in[23];
    const int* dst2 = (const int*)d_in[24];
    const int* src3 = (const int*)d_in[25];
    const int* dst3 = (const int*)d_in[26];
    float* out = (float*)d_out;

    char* ws = (char*)d_ws;
    size_t off = 0;
    auto alloc = [&](size_t bytes) -> char* {
        char* p = ws + off;
        off = (off + bytes + 255) & ~(size_t)255;
        return p;
    };
    ushort* hH  = (ushort*)alloc((size_t)NN * D * 2);
    ushort* gH  = (ushort*)alloc((size_t)NN * D * 2);
    // layer-1 GEMM output reuses hH (dead after layer-0 consumers)
    ushort* g2H = hH;
    ushort* WtH = (ushort*)alloc((size_t)DD * 2);
    ushort* WtL = (ushort*)alloc((size_t)DD * 2);
    float* wrbuf  = (float*)alloc((size_t)4 * DD * 4);
    float* ybuf   = (float*)alloc((size_t)(NA + NC) * D * 4);
    float* aggbuf = (float*)alloc((size_t)(NA + NC) * D * 4);
    int*   deg13  = (int*)  alloc((size_t)2 * NF * 4);
    int* deg1 = deg13; int* deg3 = deg13 + NF;
    float* inv1 = (float*)alloc((size_t)NF * 4);
    float* inv3 = (float*)alloc((size_t)NF * 4);
    float* inv0 = (float*)alloc((size_t)NA * 4);
    float* inv2 = (float*)alloc((size_t)NC * 4);
    int* rp0 = (int*)alloc((NA + 1) * 4);
    int* rp1 = (int*)alloc((size_t)(NF + 1) * 4);
    int* rp2 = (int*)alloc((NC + 1) * 4);
    int* rp3 = (int*)alloc((size_t)(NF + 1) * 4);
    int* cu1 = (int*)alloc((size_t)(NF + 1) * 4);
    int* cu3 = (int*)alloc((size_t)(NF + 1) * 4);
    int* csr0 = (int*)alloc((size_t)E * 4);
    int* csr1 = (int*)alloc((size_t)E * 4);
    int* csr2 = (int*)alloc((size_t)E * 4);
    int* csr3 = (int*)alloc((size_t)E * 4);
    int* bsum = (int*)alloc(256 * 4);
    int* bh0  = (int*)alloc((size_t)NSL * NA * 4);
    int* bh2  = (int*)alloc((size_t)NSL * NC * 4);
    (void)ws_size; (void)in_sizes; (void)n_in; (void)out_size;

    // ---- CSR build: r0/r2 via contention-free counting sort
    hist02_kernel<<<2 * NSL, 256, 0, stream>>>(dst0, dst2, bh0, bh2);
    scan02_kernel<<<1, 512, 0, stream>>>(bh0, bh2, rp0, rp2, inv0, inv2);
    fill02_kernel<<<2 * NSL, 256, 0, stream>>>(src0, dst0, src2, dst2, bh0, bh2, csr0, csr2);

    // ---- CSR build: r1/r3 via atomics (100K dsts, avg degree 2.5 — cheap)
    hipMemsetAsync(deg13, 0, (size_t)2 * NF * 4, stream);
    deg_count_kernel<<<(2 * E + 255) / 256, 256, 0, stream>>>(dst1, dst3, deg1, deg3);
    scanA_kernel<<<196, 1024, 0, stream>>>(deg1, deg3, bsum);
    scanB_kernel<<<1, 256, 0, stream>>>(bsum);
    scanC_kernel<<<196, 1024, 0, stream>>>(deg1, deg3, bsum, rp1, rp3, cu1, cu3, inv1, inv3);
    csr_fill13_kernel<<<(2 * E + 255) / 256, 256, 0, stream>>>(
        src1, dst1, src3, dst3, cu1, cu3, csr1, csr3);

    // ---- encoders (single bf16 plane)
    encode_kernel<32, 8><<<NF / 8, 256, 0, stream>>>(xf, Wf, bf, hH, NF, 0);
    encode_kernel<16, 8><<<(NA + 7) / 8, 256, 0, stream>>>(xa, Wa, ba, hH, NA, NF);
    encode_kernel<8, 8><<<(NC + 7) / 8, 256, 0, stream>>>(xc, Wc, bc, hH, NC, NF + NA);

    // ---- layer 0: pure MFMA gemm -> G; then per-row-type finishers in place
    wsplit_kernel<<<D, D, 0, stream>>>(root0, WtH, WtL);
    wr_kernel<<<4 * DD / 256, 256, 0, stream>>>(basis0, comp0, wrbuf);
    y_kernel<<<NA + NC, 256, 0, stream>>>(hH, wrbuf, ybuf);
    gemm_mfma<<<dim3((NN + 127) / 128, 2), 512, 0, stream>>>(
        hH, WtH, WtL, bias0, gH, NN);
    hipMemsetAsync(aggbuf, 0, (size_t)(NA + NC) * D * 4, stream);
    agg_small_kernel<<<NA * 4 + NC * 64, 256, 0, stream>>>(
        hH, rp0, csr0, rp2, csr2, aggbuf);
    smallT_kernel<<<NA + NC, 256, 0, stream>>>(aggbuf, wrbuf, inv0, inv2, gH);
    msg_relu_kernel<<<(NF / 2 * 64 + 255) / 256, 256, 0, stream>>>(
        gH, ybuf, rp1, csr1, inv1, rp3, csr3, inv3);

    // ---- layer 1 (flights only): pure gemm -> G2 (aliases h); readout -> out
    wsplit_kernel<<<D, D, 0, stream>>>(root1, WtH, WtL);
    wr_kernel<<<4 * DD / 256, 256, 0, stream>>>(basis1, comp1, wrbuf);
    y_kernel<<<NA + NC, 256, 0, stream>>>(gH, wrbuf, ybuf);
    gemm_mfma<<<dim3((NF + 127) / 128, 2), 512, 0, stream>>>(
        gH, WtH, WtL, bias1, g2H, NF);
    msg_readout_kernel<<<(NF / 2 * 64 + 255) / 256, 256, 0, stream>>>(
        g2H, ybuf, rp1, csr1, inv1, rp3, csr3, inv3, Wout, bout, out);
}